// Round 1
// baseline (1149.228 us; speedup 1.0000x reference)
//
#include <hip/hip_runtime.h>
#include <math.h>

#define THREADS 256

// ---------------- degree / normalization ----------------

__global__ __launch_bounds__(THREADS) void init_cnt_kernel(int* __restrict__ cnt, int n) {
    int i = blockIdx.x * blockDim.x + threadIdx.x;
    if (i < n) cnt[i] = 1;  // self-loop
}

__global__ __launch_bounds__(THREADS) void count_kernel(const int* __restrict__ dst,
                                                        int* __restrict__ cnt, int e) {
    int i = blockIdx.x * blockDim.x + threadIdx.x;
    if (i < e) atomicAdd(&cnt[dst[i]], 1);
}

__global__ __launch_bounds__(THREADS) void dis_kernel(const int* __restrict__ cnt,
                                                      float* __restrict__ dis, int n) {
    int i = blockIdx.x * blockDim.x + threadIdx.x;
    if (i < n) dis[i] = rsqrtf((float)cnt[i]);
}

// ---------------- fused GEMM ----------------
// Computes, per row r:
//   xrow = PRE ? swish(X[r]*dis[r] + bin) : X[r]
//   v    = (xrow @ W) * dis[r]
//   hs[r] = v;  agg[r] = v;   (agg init == self-loop contribution)
// Safe to run with agg == X in-place when KTOT == OUT == stride (each block
// writes exactly the rows it read, after all its reads complete).
template <int KTOT, int OUT, bool PRE>
__global__ __launch_bounds__(THREADS) void gemm_kernel(
    const float* __restrict__ X, const float* __restrict__ W,
    const float* __restrict__ bin, const float* __restrict__ dis,
    float* __restrict__ hs, float* __restrict__ agg, int n)
{
    constexpr int KC   = 64;
    constexpr int RPT  = (OUT == 64) ? 4 : 2;   // rows per thread
    constexpr int OPT  = (OUT == 64) ? 4 : 5;   // outs per thread
    constexpr int ROWG = 64 / RPT;

    __shared__ float Xs[64][KC + 1];   // +1 pad: conflict-free column reads
    __shared__ float Ws[KC * OUT];

    const int tid  = threadIdx.x;
    const int row0 = blockIdx.x * 64;
    const int rg   = (tid % ROWG) * RPT;
    const int og   = (tid / ROWG) * OPT;

    float acc[RPT][OPT];
#pragma unroll
    for (int i = 0; i < RPT; ++i)
#pragma unroll
        for (int j = 0; j < OPT; ++j) acc[i][j] = 0.f;

    for (int kc = 0; kc < KTOT; kc += KC) {
        // stage W chunk [KC][OUT]
        const float4* W4 = (const float4*)(W + (size_t)kc * OUT);
        for (int i = tid; i < KC * OUT / 4; i += THREADS)
            ((float4*)Ws)[i] = W4[i];
        // stage X tile [64][KC] (+ fused pre-activation)
        for (int i = tid; i < 64 * KC / 4; i += THREADS) {
            int r   = i >> 4;      // KC/4 == 16 float4 per row
            int c4  = i & 15;
            int row = row0 + r;
            float4 v = make_float4(0.f, 0.f, 0.f, 0.f);
            if (row < n) {
                v = *(const float4*)(X + (size_t)row * KTOT + kc + c4 * 4);
                if (PRE) {
                    float dd = dis[row];
                    int   cb = kc + c4 * 4;
                    float h;
                    h = v.x * dd + bin[cb + 0]; v.x = h / (1.f + __expf(-h));
                    h = v.y * dd + bin[cb + 1]; v.y = h / (1.f + __expf(-h));
                    h = v.z * dd + bin[cb + 2]; v.z = h / (1.f + __expf(-h));
                    h = v.w * dd + bin[cb + 3]; v.w = h / (1.f + __expf(-h));
                }
            }
            int c = c4 * 4;
            Xs[r][c]     = v.x;
            Xs[r][c + 1] = v.y;
            Xs[r][c + 2] = v.z;
            Xs[r][c + 3] = v.w;
        }
        __syncthreads();

        for (int k = 0; k < KC; ++k) {
            float xv[RPT], wv[OPT];
#pragma unroll
            for (int i = 0; i < RPT; ++i) xv[i] = Xs[rg + i][k];
#pragma unroll
            for (int j = 0; j < OPT; ++j) wv[j] = Ws[k * OUT + og + j];
#pragma unroll
            for (int i = 0; i < RPT; ++i)
#pragma unroll
                for (int j = 0; j < OPT; ++j) acc[i][j] += xv[i] * wv[j];
        }
        __syncthreads();
    }

#pragma unroll
    for (int i = 0; i < RPT; ++i) {
        int row = row0 + rg + i;
        if (row < n) {
            float dd = dis[row];
#pragma unroll
            for (int j = 0; j < OPT; ++j) {
                float v = acc[i][j] * dd;
                size_t idx = (size_t)row * OUT + og + j;
                hs[idx]  = v;
                agg[idx] = v;
            }
        }
    }
}

// ---------------- edge scatter-add ----------------
template <int F>
__global__ __launch_bounds__(THREADS) void agg_kernel(
    const int* __restrict__ src, const int* __restrict__ dst,
    const float* __restrict__ hs, float* __restrict__ agg, int e)
{
    long long idx = (long long)blockIdx.x * blockDim.x + threadIdx.x;
    int ei = (int)(idx >> 6);
    int f  = (int)(idx & 63);
    if (ei < e && f < F) {
        int s = src[ei];
        int d = dst[ei];
        unsafeAtomicAdd(&agg[(size_t)d * F + f], hs[(size_t)s * F + f]);
    }
}

// ---------------- final bias + log_softmax (in-place on d_out) ----------------
__global__ __launch_bounds__(THREADS) void lsm_kernel(
    float* __restrict__ io, const float* __restrict__ dis,
    const float* __restrict__ b, int n)
{
    int gtid = blockIdx.x * blockDim.x + threadIdx.x;
    int wid  = gtid >> 6;
    int lane = gtid & 63;
    if (wid >= n) return;
    float val = 0.f, v = -1e30f;
    if (lane < 40) {
        val = io[(size_t)wid * 40 + lane] * dis[wid] + b[lane];
        v = val;
    }
#pragma unroll
    for (int off = 32; off > 0; off >>= 1) v = fmaxf(v, __shfl_xor(v, off));
    float ex = (lane < 40) ? __expf(val - v) : 0.f;
#pragma unroll
    for (int off = 32; off > 0; off >>= 1) ex += __shfl_xor(ex, off);
    if (lane < 40) io[(size_t)wid * 40 + lane] = val - v - __logf(ex);
}

// ---------------- launch ----------------
extern "C" void kernel_launch(void* const* d_in, const int* in_sizes, int n_in,
                              void* d_out, int out_size, void* d_ws, size_t ws_size,
                              hipStream_t stream) {
    const float* x  = (const float*)d_in[0];
    const int*   ei = (const int*)d_in[1];
    const float* W1 = (const float*)d_in[2];
    const float* b1 = (const float*)d_in[3];
    const float* W2 = (const float*)d_in[4];
    const float* b2 = (const float*)d_in[5];
    const float* W3 = (const float*)d_in[6];
    const float* b3 = (const float*)d_in[7];
    float* out = (float*)d_out;

    const int n = in_sizes[0] / 128;
    const int e = in_sizes[1] / 2;
    const int* src = ei;
    const int* dst = ei + e;

    // workspace layout: dis[n] | buf0[n*64] | buf1[n*64]; cnt aliases buf1.
    float* dis  = (float*)d_ws;
    float* buf0 = dis + n;
    float* buf1 = buf0 + (size_t)n * 64;
    int*   cnt  = (int*)buf1;  // consumed before buf1's first float write

    const int gb_n    = (n + THREADS - 1) / THREADS;
    const int gb_e    = (e + THREADS - 1) / THREADS;
    const int gb_rows = (n + 63) / 64;
    const long long agg_threads = (long long)e * 64;
    const int gb_agg  = (int)((agg_threads + THREADS - 1) / THREADS);
    const int gb_lsm  = (int)(((long long)n * 64 + THREADS - 1) / THREADS);

    init_cnt_kernel<<<gb_n, THREADS, 0, stream>>>(cnt, n);
    count_kernel<<<gb_e, THREADS, 0, stream>>>(dst, cnt, e);
    dis_kernel<<<gb_n, THREADS, 0, stream>>>(cnt, dis, n);

    // layer 1: x[n,128] @ W1 -> buf0 (Hs1), buf1 (AGG1 init)
    gemm_kernel<128, 64, false><<<gb_rows, THREADS, 0, stream>>>(
        x, W1, nullptr, dis, buf0, buf1, n);
    agg_kernel<64><<<gb_agg, THREADS, 0, stream>>>(src, dst, buf0, buf1, e);

    // layer 2: swish(buf1*dis+b1) @ W2 -> buf0 (Hs2), buf1 (AGG2 init, in-place)
    gemm_kernel<64, 64, true><<<gb_rows, THREADS, 0, stream>>>(
        buf1, W2, b1, dis, buf0, buf1, n);
    agg_kernel<64><<<gb_agg, THREADS, 0, stream>>>(src, dst, buf0, buf1, e);

    // layer 3: swish(buf1*dis+b2) @ W3 -> buf0 (Hs3, stride 40), d_out (AGG3 init)
    gemm_kernel<64, 40, true><<<gb_rows, THREADS, 0, stream>>>(
        buf1, W3, b2, dis, buf0, out, n);
    agg_kernel<40><<<gb_agg, THREADS, 0, stream>>>(src, dst, buf0, out, e);

    // final: out = log_softmax(out*dis + b3) in-place
    lsm_kernel<<<gb_lsm, THREADS, 0, stream>>>(out, dis, b3, n);
}

// Round 2
// 629.697 us; speedup vs baseline: 1.8250x; 1.8250x over previous
//
#include <hip/hip_runtime.h>
#include <math.h>

#define THREADS 256
#define SCAN_T 256

// ---------------- degree / CSR build ----------------

__global__ __launch_bounds__(THREADS) void zero_kernel(int* __restrict__ p, int n) {
    int i = blockIdx.x * blockDim.x + threadIdx.x;
    if (i < n) p[i] = 0;
}

__global__ __launch_bounds__(THREADS) void count_kernel(const int* __restrict__ dst,
                                                        int* __restrict__ cnt, int e) {
    int i = blockIdx.x * blockDim.x + threadIdx.x;
    if (i < e) atomicAdd(&cnt[dst[i]], 1);
}

__global__ __launch_bounds__(THREADS) void dis_kernel(const int* __restrict__ cnt,
                                                      float* __restrict__ dis, int n) {
    int i = blockIdx.x * blockDim.x + threadIdx.x;
    if (i < n) dis[i] = rsqrtf((float)(cnt[i] + 1));  // +1 self-loop
}

// block-local exclusive scan; block totals to bsum
__global__ __launch_bounds__(SCAN_T) void scan1_kernel(const int* __restrict__ cnt,
                                                       int* __restrict__ rowptr,
                                                       int* __restrict__ bsum, int n) {
    __shared__ int s[SCAN_T];
    int i = blockIdx.x * SCAN_T + threadIdx.x;
    int v = (i < n) ? cnt[i] : 0;
    s[threadIdx.x] = v;
    __syncthreads();
    for (int off = 1; off < SCAN_T; off <<= 1) {
        int t = (threadIdx.x >= off) ? s[threadIdx.x - off] : 0;
        __syncthreads();
        s[threadIdx.x] += t;
        __syncthreads();
    }
    if (i < n) rowptr[i] = s[threadIdx.x] - v;  // exclusive within block
    if (threadIdx.x == SCAN_T - 1) bsum[blockIdx.x] = s[SCAN_T - 1];
}

// single-block exclusive scan of block sums (nb <= 1024)
__global__ __launch_bounds__(1024) void scan2_kernel(int* __restrict__ bsum, int nb) {
    __shared__ int s[1024];
    int v = (threadIdx.x < nb) ? bsum[threadIdx.x] : 0;
    s[threadIdx.x] = v;
    __syncthreads();
    for (int off = 1; off < 1024; off <<= 1) {
        int t = (threadIdx.x >= off) ? s[threadIdx.x - off] : 0;
        __syncthreads();
        s[threadIdx.x] += t;
        __syncthreads();
    }
    if (threadIdx.x < nb) bsum[threadIdx.x] = s[threadIdx.x] - v;  // exclusive
}

__global__ __launch_bounds__(THREADS) void scan3_kernel(int* __restrict__ rowptr,
                                                        const int* __restrict__ bsum,
                                                        int* __restrict__ cursor,
                                                        int n, int e) {
    int i = blockIdx.x * blockDim.x + threadIdx.x;
    if (i < n) {
        int v = rowptr[i] + bsum[i / SCAN_T];
        rowptr[i] = v;
        cursor[i] = v;
    }
    if (i == 0) rowptr[n] = e;
}

__global__ __launch_bounds__(THREADS) void scatter_kernel(const int* __restrict__ src,
                                                          const int* __restrict__ dst,
                                                          int* __restrict__ cursor,
                                                          int* __restrict__ csr, int e) {
    int i = blockIdx.x * blockDim.x + threadIdx.x;
    if (i < e) {
        int d = dst[i];
        int pos = atomicAdd(&cursor[d], 1);
        csr[pos] = src[i];
    }
}

// ---------------- fused GEMM ----------------
// Per row r:  xrow = PRE ? swish(X[r]*dis[r] + bin) : X[r]
//             hs[r] = (xrow @ W) * dis[r]
template <int KTOT, int OUT, bool PRE>
__global__ __launch_bounds__(THREADS) void gemm_kernel(
    const float* __restrict__ X, const float* __restrict__ W,
    const float* __restrict__ bin, const float* __restrict__ dis,
    float* __restrict__ hs, int n)
{
    constexpr int KC   = 64;
    constexpr int RPT  = (OUT == 64) ? 4 : 2;
    constexpr int OPT  = (OUT == 64) ? 4 : 5;
    constexpr int ROWG = 64 / RPT;

    __shared__ float Xs[64][KC + 1];
    __shared__ float Ws[KC * OUT];

    const int tid  = threadIdx.x;
    const int row0 = blockIdx.x * 64;
    const int rg   = (tid % ROWG) * RPT;
    const int og   = (tid / ROWG) * OPT;

    float acc[RPT][OPT];
#pragma unroll
    for (int i = 0; i < RPT; ++i)
#pragma unroll
        for (int j = 0; j < OPT; ++j) acc[i][j] = 0.f;

    for (int kc = 0; kc < KTOT; kc += KC) {
        const float4* W4 = (const float4*)(W + (size_t)kc * OUT);
        for (int i = tid; i < KC * OUT / 4; i += THREADS)
            ((float4*)Ws)[i] = W4[i];
        for (int i = tid; i < 64 * KC / 4; i += THREADS) {
            int r   = i >> 4;
            int c4  = i & 15;
            int row = row0 + r;
            float4 v = make_float4(0.f, 0.f, 0.f, 0.f);
            if (row < n) {
                v = *(const float4*)(X + (size_t)row * KTOT + kc + c4 * 4);
                if (PRE) {
                    float dd = dis[row];
                    int   cb = kc + c4 * 4;
                    float h;
                    h = v.x * dd + bin[cb + 0]; v.x = h / (1.f + __expf(-h));
                    h = v.y * dd + bin[cb + 1]; v.y = h / (1.f + __expf(-h));
                    h = v.z * dd + bin[cb + 2]; v.z = h / (1.f + __expf(-h));
                    h = v.w * dd + bin[cb + 3]; v.w = h / (1.f + __expf(-h));
                }
            }
            int c = c4 * 4;
            Xs[r][c]     = v.x;
            Xs[r][c + 1] = v.y;
            Xs[r][c + 2] = v.z;
            Xs[r][c + 3] = v.w;
        }
        __syncthreads();

        for (int k = 0; k < KC; ++k) {
            float xv[RPT], wv[OPT];
#pragma unroll
            for (int i = 0; i < RPT; ++i) xv[i] = Xs[rg + i][k];
#pragma unroll
            for (int j = 0; j < OPT; ++j) wv[j] = Ws[k * OUT + og + j];
#pragma unroll
            for (int i = 0; i < RPT; ++i)
#pragma unroll
                for (int j = 0; j < OPT; ++j) acc[i][j] += xv[i] * wv[j];
        }
        __syncthreads();
    }

#pragma unroll
    for (int i = 0; i < RPT; ++i) {
        int row = row0 + rg + i;
        if (row < n) {
            float dd = dis[row];
#pragma unroll
            for (int j = 0; j < OPT; ++j)
                hs[(size_t)row * OUT + og + j] = acc[i][j] * dd;
        }
    }
}

// ---------------- CSR gather-aggregate: one wave per dst row ----------------
// agg[d] = hs[d] + sum_{s in in-edges(d)} hs[s]
template <int F>
__global__ __launch_bounds__(THREADS) void agg_csr_kernel(
    const int* __restrict__ rowptr, const int* __restrict__ csr,
    const float* __restrict__ hs, float* __restrict__ agg, int n)
{
    int gtid = blockIdx.x * blockDim.x + threadIdx.x;
    int d    = gtid >> 6;
    int lane = threadIdx.x & 63;
    if (d >= n) return;

    int beg = rowptr[d], end = rowptr[d + 1];
    float acc = (F == 64 || lane < F) ? hs[(size_t)d * F + lane] : 0.f;  // self-loop

    for (int j = beg; j < end; j += 64) {
        int eidx = (j + lane < end) ? csr[j + lane] : 0;   // coalesced edge read
        int cnt  = min(end - j, 64);
        for (int t = 0; t < cnt; ++t) {
            int s = __shfl(eidx, t);                       // broadcast src id
            if (F == 64 || lane < F)
                acc += hs[(size_t)s * F + lane];           // coalesced row gather
        }
    }
    if (F == 64 || lane < F) agg[(size_t)d * F + lane] = acc;
}

// ---------------- final bias + log_softmax (in-place on d_out) ----------------
__global__ __launch_bounds__(THREADS) void lsm_kernel(
    float* __restrict__ io, const float* __restrict__ dis,
    const float* __restrict__ b, int n)
{
    int gtid = blockIdx.x * blockDim.x + threadIdx.x;
    int wid  = gtid >> 6;
    int lane = gtid & 63;
    if (wid >= n) return;
    float val = 0.f, v = -1e30f;
    if (lane < 40) {
        val = io[(size_t)wid * 40 + lane] * dis[wid] + b[lane];
        v = val;
    }
#pragma unroll
    for (int off = 32; off > 0; off >>= 1) v = fmaxf(v, __shfl_xor(v, off));
    float ex = (lane < 40) ? __expf(val - v) : 0.f;
#pragma unroll
    for (int off = 32; off > 0; off >>= 1) ex += __shfl_xor(ex, off);
    if (lane < 40) io[(size_t)wid * 40 + lane] = val - v - __logf(ex);
}

// ---------------- launch ----------------
static inline size_t align_up(size_t v, size_t a) { return (v + a - 1) & ~(a - 1); }

extern "C" void kernel_launch(void* const* d_in, const int* in_sizes, int n_in,
                              void* d_out, int out_size, void* d_ws, size_t ws_size,
                              hipStream_t stream) {
    const float* x  = (const float*)d_in[0];
    const int*   ei = (const int*)d_in[1];
    const float* W1 = (const float*)d_in[2];
    const float* b1 = (const float*)d_in[3];
    const float* W2 = (const float*)d_in[4];
    const float* b2 = (const float*)d_in[5];
    const float* W3 = (const float*)d_in[6];
    const float* b3 = (const float*)d_in[7];
    float* out = (float*)d_out;

    const int n = in_sizes[0] / 128;
    const int e = in_sizes[1] / 2;
    const int* src = ei;
    const int* dst = ei + e;

    // workspace layout (256B-aligned regions):
    // dis[n] | rowptr[n+1] | bsum[1024] | csr[e] | buf0[n*64] | buf1[n*64]
    // cnt[n], cursor[n] alias buf1 (consumed before buf1's first write).
    char* base = (char*)d_ws;
    size_t off = 0;
    float* dis = (float*)(base + off);        off = align_up(off + (size_t)n * 4, 256);
    int* rowptr = (int*)(base + off);         off = align_up(off + (size_t)(n + 1) * 4, 256);
    int* bsum = (int*)(base + off);           off = align_up(off + 1024 * 4, 256);
    int* csr = (int*)(base + off);            off = align_up(off + (size_t)e * 4, 256);
    float* buf0 = (float*)(base + off);       off = align_up(off + (size_t)n * 64 * 4, 256);
    float* buf1 = (float*)(base + off);       off = align_up(off + (size_t)n * 64 * 4, 256);
    int* cnt = (int*)buf1;
    int* cursor = cnt + n;

    const int gb_n    = (n + THREADS - 1) / THREADS;
    const int gb_e    = (e + THREADS - 1) / THREADS;
    const int gb_rows = (n + 63) / 64;
    const int nb      = (n + SCAN_T - 1) / SCAN_T;   // scan blocks (<=1024)
    const int gb_wave = (int)(((long long)n * 64 + THREADS - 1) / THREADS);

    // CSR build
    zero_kernel<<<gb_n, THREADS, 0, stream>>>(cnt, n);
    count_kernel<<<gb_e, THREADS, 0, stream>>>(dst, cnt, e);
    dis_kernel<<<gb_n, THREADS, 0, stream>>>(cnt, dis, n);
    scan1_kernel<<<nb, SCAN_T, 0, stream>>>(cnt, rowptr, bsum, n);
    scan2_kernel<<<1, 1024, 0, stream>>>(bsum, nb);
    scan3_kernel<<<gb_n, THREADS, 0, stream>>>(rowptr, bsum, cursor, n, e);
    scatter_kernel<<<gb_e, THREADS, 0, stream>>>(src, dst, cursor, csr, e);

    // layer 1: x[n,128] @ W1 -> buf0 (hs1); gather-agg -> buf1
    gemm_kernel<128, 64, false><<<gb_rows, THREADS, 0, stream>>>(x, W1, nullptr, dis, buf0, n);
    agg_csr_kernel<64><<<gb_wave, THREADS, 0, stream>>>(rowptr, csr, buf0, buf1, n);

    // layer 2: swish(buf1*dis+b1) @ W2 -> buf0 (hs2); gather-agg -> buf1
    gemm_kernel<64, 64, true><<<gb_rows, THREADS, 0, stream>>>(buf1, W2, b1, dis, buf0, n);
    agg_csr_kernel<64><<<gb_wave, THREADS, 0, stream>>>(rowptr, csr, buf0, buf1, n);

    // layer 3: swish(buf1*dis+b2) @ W3 -> buf0 (hs3, stride 40); gather-agg -> out
    gemm_kernel<64, 40, true><<<gb_rows, THREADS, 0, stream>>>(buf1, W3, b2, dis, buf0, n);
    agg_csr_kernel<40><<<gb_wave, THREADS, 0, stream>>>(rowptr, csr, buf0, out, n);

    // final: out = log_softmax(out*dis + b3) in-place
    lsm_kernel<<<gb_wave, THREADS, 0, stream>>>(out, dis, b3, n);
}

// Round 3
// 424.787 us; speedup vs baseline: 2.7054x; 1.4824x over previous
//
#include <hip/hip_runtime.h>
#include <math.h>

#define THREADS 256
#define SCAN_T 256
#define BSHIFT 9              // 512 dsts per bucket
#define PASS1_CHUNK 4096

// ---------------- degree / normalization ----------------

__global__ __launch_bounds__(THREADS) void zero_kernel(int* __restrict__ p, int n) {
    int i = blockIdx.x * blockDim.x + threadIdx.x;
    if (i < n) p[i] = 0;
}

__global__ __launch_bounds__(THREADS) void count_kernel(const int* __restrict__ dst,
                                                        int* __restrict__ cnt, int e) {
    int i = blockIdx.x * blockDim.x + threadIdx.x;
    if (i < e) atomicAdd(&cnt[dst[i]], 1);
}

__global__ __launch_bounds__(THREADS) void dis_kernel(const int* __restrict__ cnt,
                                                      float* __restrict__ dis, int n) {
    int i = blockIdx.x * blockDim.x + threadIdx.x;
    if (i < n) dis[i] = rsqrtf((float)(cnt[i] + 1));  // +1 self-loop
}

// block-local exclusive scan; block totals to bsum
__global__ __launch_bounds__(SCAN_T) void scan1_kernel(const int* __restrict__ cnt,
                                                       int* __restrict__ rowptr,
                                                       int* __restrict__ bsum, int n) {
    __shared__ int s[SCAN_T];
    int i = blockIdx.x * SCAN_T + threadIdx.x;
    int v = (i < n) ? cnt[i] : 0;
    s[threadIdx.x] = v;
    __syncthreads();
    for (int off = 1; off < SCAN_T; off <<= 1) {
        int t = (threadIdx.x >= off) ? s[threadIdx.x - off] : 0;
        __syncthreads();
        s[threadIdx.x] += t;
        __syncthreads();
    }
    if (i < n) rowptr[i] = s[threadIdx.x] - v;  // exclusive within block
    if (threadIdx.x == SCAN_T - 1) bsum[blockIdx.x] = s[SCAN_T - 1];
}

__global__ __launch_bounds__(1024) void scan2_kernel(int* __restrict__ bsum, int nb) {
    __shared__ int s[1024];
    int v = (threadIdx.x < nb) ? bsum[threadIdx.x] : 0;
    s[threadIdx.x] = v;
    __syncthreads();
    for (int off = 1; off < 1024; off <<= 1) {
        int t = (threadIdx.x >= off) ? s[threadIdx.x - off] : 0;
        __syncthreads();
        s[threadIdx.x] += t;
        __syncthreads();
    }
    if (threadIdx.x < nb) bsum[threadIdx.x] = s[threadIdx.x] - v;  // exclusive
}

__global__ __launch_bounds__(THREADS) void scan3_kernel(int* __restrict__ rowptr,
                                                        const int* __restrict__ bsum,
                                                        int n, int e) {
    int i = blockIdx.x * blockDim.x + threadIdx.x;
    if (i < n) rowptr[i] += bsum[i / SCAN_T];
    if (i == 0) rowptr[n] = e;
}

// ---------------- bucketed counting sort (CSR build) ----------------

// bucket b's pair-region offset == rowptr[b<<BSHIFT] (csr layout is dst-ordered)
__global__ __launch_bounds__(THREADS) void pcinit_kernel(const int* __restrict__ rowptr,
                                                         int* __restrict__ pcur, int nbuck) {
    int i = blockIdx.x * blockDim.x + threadIdx.x;
    if (i < nbuck) pcur[i] = rowptr[i << BSHIFT];
}

// pass 1: bin edges into per-bucket contiguous regions of `pairs`
__global__ __launch_bounds__(THREADS) void sort1_kernel(
    const int* __restrict__ src, const int* __restrict__ dst,
    int* __restrict__ pcur, int2* __restrict__ pairs, int e, int nbuck)
{
    __shared__ int hist[512], hist2[512], base_s[512];
    const int tid = threadIdx.x;
    const int c0  = blockIdx.x * PASS1_CHUNK;
    for (int i = tid; i < 512; i += THREADS) { hist[i] = 0; hist2[i] = 0; }
    __syncthreads();
    for (int i = tid; i < PASS1_CHUNK; i += THREADS) {
        int idx = c0 + i;
        if (idx < e) atomicAdd(&hist[dst[idx] >> BSHIFT], 1);
    }
    __syncthreads();
    for (int b = tid; b < nbuck; b += THREADS) {
        int h = hist[b];
        base_s[b] = h ? atomicAdd(&pcur[b], h) : 0;
    }
    __syncthreads();
    for (int i = tid; i < PASS1_CHUNK; i += THREADS) {
        int idx = c0 + i;
        if (idx < e) {
            int d = dst[idx];
            int b = d >> BSHIFT;
            int off = atomicAdd(&hist2[b], 1);
            pairs[base_s[b] + off] = make_int2(src[idx], d);
        }
    }
}

// pass 2: one block per bucket; LDS row cursors; csr writes land in a ~32KB window
__global__ __launch_bounds__(THREADS) void sort2_kernel(
    const int* __restrict__ rowptr, const int2* __restrict__ pairs,
    int* __restrict__ csr, int n)
{
    __shared__ int cur[1 << BSHIFT];
    const int d0 = blockIdx.x << BSHIFT;
    const int nd = min(1 << BSHIFT, n - d0);
    for (int i = threadIdx.x; i < nd; i += THREADS) cur[i] = rowptr[d0 + i];
    __syncthreads();
    const int p0 = rowptr[d0], p1 = rowptr[d0 + nd];
    for (int j = p0 + threadIdx.x; j < p1; j += THREADS) {
        int2 pr = pairs[j];
        int pos = atomicAdd(&cur[pr.y - d0], 1);
        csr[pos] = pr.x;
    }
}

// ---------------- fused GEMM ----------------
// Per row r:  xrow = PRE ? swish(X[r]*dis[r] + bin) : X[r]
//             hs[r] = (xrow @ W) * dis[r]
template <int KTOT, int OUT, bool PRE>
__global__ __launch_bounds__(THREADS) void gemm_kernel(
    const float* __restrict__ X, const float* __restrict__ W,
    const float* __restrict__ bin, const float* __restrict__ dis,
    float* __restrict__ hs, int n)
{
    constexpr int KC   = 64;
    constexpr int RPT  = (OUT == 64) ? 4 : 2;
    constexpr int OPT  = (OUT == 64) ? 4 : 5;
    constexpr int ROWG = 64 / RPT;

    __shared__ float Xs[64][KC + 1];
    __shared__ float Ws[KC * OUT];

    const int tid  = threadIdx.x;
    const int row0 = blockIdx.x * 64;
    const int rg   = (tid % ROWG) * RPT;
    const int og   = (tid / ROWG) * OPT;

    float acc[RPT][OPT];
#pragma unroll
    for (int i = 0; i < RPT; ++i)
#pragma unroll
        for (int j = 0; j < OPT; ++j) acc[i][j] = 0.f;

    for (int kc = 0; kc < KTOT; kc += KC) {
        const float4* W4 = (const float4*)(W + (size_t)kc * OUT);
        for (int i = tid; i < KC * OUT / 4; i += THREADS)
            ((float4*)Ws)[i] = W4[i];
        for (int i = tid; i < 64 * KC / 4; i += THREADS) {
            int r   = i >> 4;
            int c4  = i & 15;
            int row = row0 + r;
            float4 v = make_float4(0.f, 0.f, 0.f, 0.f);
            if (row < n) {
                v = *(const float4*)(X + (size_t)row * KTOT + kc + c4 * 4);
                if (PRE) {
                    float dd = dis[row];
                    int   cb = kc + c4 * 4;
                    float h;
                    h = v.x * dd + bin[cb + 0]; v.x = h / (1.f + __expf(-h));
                    h = v.y * dd + bin[cb + 1]; v.y = h / (1.f + __expf(-h));
                    h = v.z * dd + bin[cb + 2]; v.z = h / (1.f + __expf(-h));
                    h = v.w * dd + bin[cb + 3]; v.w = h / (1.f + __expf(-h));
                }
            }
            int c = c4 * 4;
            Xs[r][c]     = v.x;
            Xs[r][c + 1] = v.y;
            Xs[r][c + 2] = v.z;
            Xs[r][c + 3] = v.w;
        }
        __syncthreads();

        for (int k = 0; k < KC; ++k) {
            float xv[RPT], wv[OPT];
#pragma unroll
            for (int i = 0; i < RPT; ++i) xv[i] = Xs[rg + i][k];
#pragma unroll
            for (int j = 0; j < OPT; ++j) wv[j] = Ws[k * OUT + og + j];
#pragma unroll
            for (int i = 0; i < RPT; ++i)
#pragma unroll
                for (int j = 0; j < OPT; ++j) acc[i][j] += xv[i] * wv[j];
        }
        __syncthreads();
    }

#pragma unroll
    for (int i = 0; i < RPT; ++i) {
        int row = row0 + rg + i;
        if (row < n) {
            float dd = dis[row];
#pragma unroll
            for (int j = 0; j < OPT; ++j)
                hs[(size_t)row * OUT + og + j] = acc[i][j] * dd;
        }
    }
}

// ---------------- CSR gather-aggregate: one wave per dst row, 4 edges/step ----
// agg[d] = hs[d] + sum_{s in in-edges(d)} hs[s]
// 16 lanes x float4 cover the row; 4 sub-groups process 4 edges concurrently,
// then shfl_xor(16/32) merges sub-group partials.
template <int F>
__global__ __launch_bounds__(THREADS) void agg_csr4_kernel(
    const int* __restrict__ rowptr, const int* __restrict__ csr,
    const float* __restrict__ hs, float* __restrict__ agg, int n)
{
    constexpr int C4 = F / 4;                    // float4 chunks per row (16 or 10)
    const int d = blockIdx.x * 4 + (threadIdx.x >> 6);
    const int lane = threadIdx.x & 63;
    if (d >= n) return;
    const int sub = lane >> 4;                   // edge slot 0..3
    const int c4  = lane & 15;                   // chunk index
    const bool act = (c4 < C4);

    const int beg = rowptr[d], end = rowptr[d + 1];
    float4 acc = make_float4(0.f, 0.f, 0.f, 0.f);
    if (sub == 0 && act)                         // self-loop
        acc = *(const float4*)(hs + (size_t)d * F + c4 * 4);

    for (int j = beg; j < end; j += 64) {
        int m = end - j; if (m > 64) m = 64;
        int eidx = (j + lane < end) ? csr[j + lane] : 0;
        for (int t = 0; t < m; t += 4) {
            int slot = t + sub;
            int s = __shfl(eidx, slot);
            if (slot < m && act) {
                float4 v = *(const float4*)(hs + (size_t)s * F + c4 * 4);
                acc.x += v.x; acc.y += v.y; acc.z += v.z; acc.w += v.w;
            }
        }
    }
    acc.x += __shfl_xor(acc.x, 16); acc.y += __shfl_xor(acc.y, 16);
    acc.z += __shfl_xor(acc.z, 16); acc.w += __shfl_xor(acc.w, 16);
    acc.x += __shfl_xor(acc.x, 32); acc.y += __shfl_xor(acc.y, 32);
    acc.z += __shfl_xor(acc.z, 32); acc.w += __shfl_xor(acc.w, 32);
    if (sub == 0 && act)
        *(float4*)(agg + (size_t)d * F + c4 * 4) = acc;
}

// ---------------- final bias + log_softmax (in-place on d_out) ----------------
__global__ __launch_bounds__(THREADS) void lsm_kernel(
    float* __restrict__ io, const float* __restrict__ dis,
    const float* __restrict__ b, int n)
{
    int gtid = blockIdx.x * blockDim.x + threadIdx.x;
    int wid  = gtid >> 6;
    int lane = gtid & 63;
    if (wid >= n) return;
    float val = 0.f, v = -1e30f;
    if (lane < 40) {
        val = io[(size_t)wid * 40 + lane] * dis[wid] + b[lane];
        v = val;
    }
#pragma unroll
    for (int off = 32; off > 0; off >>= 1) v = fmaxf(v, __shfl_xor(v, off));
    float ex = (lane < 40) ? __expf(val - v) : 0.f;
#pragma unroll
    for (int off = 32; off > 0; off >>= 1) ex += __shfl_xor(ex, off);
    if (lane < 40) io[(size_t)wid * 40 + lane] = val - v - __logf(ex);
}

// ---------------- launch ----------------
static inline size_t align_up(size_t v, size_t a) { return (v + a - 1) & ~(a - 1); }

extern "C" void kernel_launch(void* const* d_in, const int* in_sizes, int n_in,
                              void* d_out, int out_size, void* d_ws, size_t ws_size,
                              hipStream_t stream) {
    const float* x  = (const float*)d_in[0];
    const int*   ei = (const int*)d_in[1];
    const float* W1 = (const float*)d_in[2];
    const float* b1 = (const float*)d_in[3];
    const float* W2 = (const float*)d_in[4];
    const float* b2 = (const float*)d_in[5];
    const float* W3 = (const float*)d_in[6];
    const float* b3 = (const float*)d_in[7];
    float* out = (float*)d_out;

    const int n = in_sizes[0] / 128;
    const int e = in_sizes[1] / 2;
    const int* src = ei;
    const int* dst = ei + e;

    // workspace: dis[n] | rowptr[n+1] | bsum[1024] | pcur[512] | csr[e] | buf0 | buf1
    // pairs[e] (int2) aliases buf0 (consumed before gemm1 writes buf0);
    // cnt[n] aliases buf1 (consumed before agg1 writes buf1).
    char* base = (char*)d_ws;
    size_t off = 0;
    float* dis = (float*)(base + off);    off = align_up(off + (size_t)n * 4, 256);
    int* rowptr = (int*)(base + off);     off = align_up(off + (size_t)(n + 1) * 4, 256);
    int* bsum = (int*)(base + off);       off = align_up(off + 1024 * 4, 256);
    int* pcur = (int*)(base + off);       off = align_up(off + 512 * 4, 256);
    int* csr = (int*)(base + off);        off = align_up(off + (size_t)e * 4, 256);
    float* buf0 = (float*)(base + off);   off = align_up(off + (size_t)n * 64 * 4, 256);
    float* buf1 = (float*)(base + off);   off = align_up(off + (size_t)n * 64 * 4, 256);
    int2* pairs = (int2*)buf0;
    int*  cnt   = (int*)buf1;

    const int gb_n    = (n + THREADS - 1) / THREADS;
    const int gb_e    = (e + THREADS - 1) / THREADS;
    const int gb_rows = (n + 63) / 64;
    const int nb_scan = (n + SCAN_T - 1) / SCAN_T;
    const int nbuck   = (n + (1 << BSHIFT) - 1) >> BSHIFT;   // <=512
    const int gb_s1   = (e + PASS1_CHUNK - 1) / PASS1_CHUNK;
    const int gb_agg  = (n + 3) / 4;
    const int gb_lsm  = (int)(((long long)n * 64 + THREADS - 1) / THREADS);

    // CSR build
    zero_kernel<<<gb_n, THREADS, 0, stream>>>(cnt, n);
    count_kernel<<<gb_e, THREADS, 0, stream>>>(dst, cnt, e);
    dis_kernel<<<gb_n, THREADS, 0, stream>>>(cnt, dis, n);
    scan1_kernel<<<nb_scan, SCAN_T, 0, stream>>>(cnt, rowptr, bsum, n);
    scan2_kernel<<<1, 1024, 0, stream>>>(bsum, nb_scan);
    scan3_kernel<<<gb_n, THREADS, 0, stream>>>(rowptr, bsum, n, e);
    pcinit_kernel<<<(nbuck + THREADS - 1) / THREADS, THREADS, 0, stream>>>(rowptr, pcur, nbuck);
    sort1_kernel<<<gb_s1, THREADS, 0, stream>>>(src, dst, pcur, pairs, e, nbuck);
    sort2_kernel<<<nbuck, THREADS, 0, stream>>>(rowptr, pairs, csr, n);

    // layer 1
    gemm_kernel<128, 64, false><<<gb_rows, THREADS, 0, stream>>>(x, W1, nullptr, dis, buf0, n);
    agg_csr4_kernel<64><<<gb_agg, THREADS, 0, stream>>>(rowptr, csr, buf0, buf1, n);

    // layer 2
    gemm_kernel<64, 64, true><<<gb_rows, THREADS, 0, stream>>>(buf1, W2, b1, dis, buf0, n);
    agg_csr4_kernel<64><<<gb_agg, THREADS, 0, stream>>>(rowptr, csr, buf0, buf1, n);

    // layer 3
    gemm_kernel<64, 40, true><<<gb_rows, THREADS, 0, stream>>>(buf1, W3, b2, dis, buf0, n);
    agg_csr4_kernel<40><<<gb_agg, THREADS, 0, stream>>>(rowptr, csr, buf0, out, n);

    // final: out = log_softmax(out*dis + b3) in-place
    lsm_kernel<<<gb_lsm, THREADS, 0, stream>>>(out, dis, b3, n);
}

// Round 4
// 356.994 us; speedup vs baseline: 3.2192x; 1.1899x over previous
//
#include <hip/hip_runtime.h>
#include <math.h>

#define THREADS 256
#define BSHIFT 9              // 512 dsts per bucket
#define BSIZE (1 << BSHIFT)
#define PASS1_CHUNK 4096

// ---------------- bucket histogram ----------------

__global__ __launch_bounds__(THREADS) void bzero_kernel(int* __restrict__ bcnt, int nbuck) {
    int i = threadIdx.x;
    if (i < nbuck) bcnt[i] = 0;
}

// per-chunk LDS histogram of dst buckets; one global atomic per bucket per block
__global__ __launch_bounds__(THREADS) void bhist_kernel(const int* __restrict__ dst,
                                                        int* __restrict__ bcnt, int e, int nbuck) {
    __shared__ int hist[BSIZE];
    const int tid = threadIdx.x;
    const int c0  = blockIdx.x * PASS1_CHUNK;
    for (int i = tid; i < nbuck; i += THREADS) hist[i] = 0;
    __syncthreads();
    for (int i = tid; i < PASS1_CHUNK; i += THREADS) {
        int idx = c0 + i;
        if (idx < e) atomicAdd(&hist[dst[idx] >> BSHIFT], 1);
    }
    __syncthreads();
    for (int b = tid; b < nbuck; b += THREADS) {
        int h = hist[b];
        if (h) atomicAdd(&bcnt[b], h);
    }
}

// single block: exclusive scan of bucket counts -> bbase[0..nbuck], init pcur, rowptr[n]=e
__global__ __launch_bounds__(1024) void bscan_kernel(const int* __restrict__ bcnt,
                                                     int* __restrict__ bbase,
                                                     int* __restrict__ pcur,
                                                     int* __restrict__ rowptr,
                                                     int nbuck, int n, int e) {
    __shared__ int s[1024];
    int v = (threadIdx.x < nbuck) ? bcnt[threadIdx.x] : 0;
    s[threadIdx.x] = v;
    __syncthreads();
    for (int off = 1; off < 1024; off <<= 1) {
        int t = (threadIdx.x >= off) ? s[threadIdx.x - off] : 0;
        __syncthreads();
        s[threadIdx.x] += t;
        __syncthreads();
    }
    if (threadIdx.x < nbuck) {
        int ex = s[threadIdx.x] - v;
        bbase[threadIdx.x] = ex;
        pcur[threadIdx.x]  = ex;
    }
    if (threadIdx.x == 0) { bbase[nbuck] = e; rowptr[n] = e; }
}

// ---------------- bucketed counting sort pass 1 ----------------
// bin (src,dst) pairs into per-bucket contiguous regions of `pairs`
__global__ __launch_bounds__(THREADS) void sort1_kernel(
    const int* __restrict__ src, const int* __restrict__ dst,
    int* __restrict__ pcur, int2* __restrict__ pairs, int e, int nbuck)
{
    __shared__ int hist[BSIZE], hist2[BSIZE], base_s[BSIZE];
    const int tid = threadIdx.x;
    const int c0  = blockIdx.x * PASS1_CHUNK;
    for (int i = tid; i < nbuck; i += THREADS) { hist[i] = 0; hist2[i] = 0; }
    __syncthreads();
    for (int i = tid; i < PASS1_CHUNK; i += THREADS) {
        int idx = c0 + i;
        if (idx < e) atomicAdd(&hist[dst[idx] >> BSHIFT], 1);
    }
    __syncthreads();
    for (int b = tid; b < nbuck; b += THREADS) {
        int h = hist[b];
        base_s[b] = h ? atomicAdd(&pcur[b], h) : 0;
    }
    __syncthreads();
    for (int i = tid; i < PASS1_CHUNK; i += THREADS) {
        int idx = c0 + i;
        if (idx < e) {
            int d = dst[idx];
            int b = d >> BSHIFT;
            int off = atomicAdd(&hist2[b], 1);
            pairs[base_s[b] + off] = make_int2(src[idx], d);
        }
    }
}

// ---------------- sort pass 2 (fused: degree count + rowptr + dis + csr scatter)
// one block per bucket; all per-node atomics are LDS; csr writes land in a
// contiguous ~32KB window owned by this block.
__global__ __launch_bounds__(THREADS) void sort2_kernel(
    const int* __restrict__ bbase, const int2* __restrict__ pairs,
    int* __restrict__ rowptr, float* __restrict__ dis,
    int* __restrict__ csr, int n)
{
    __shared__ int cnt[BSIZE];   // degree counts, then reused as nothing
    __shared__ int cur[BSIZE];   // local offsets -> write cursors
    __shared__ int s2[THREADS];  // scan workspace (2 elems/thread)

    const int b  = blockIdx.x;
    const int d0 = b << BSHIFT;
    const int nd = min(BSIZE, n - d0);
    const int p0 = bbase[b], p1 = bbase[b + 1];
    const int tid = threadIdx.x;

    for (int i = tid; i < BSIZE; i += THREADS) cnt[i] = 0;
    __syncthreads();

    // pass A: count in-degrees (LDS atomics)
    for (int j = p0 + tid; j < p1; j += THREADS)
        atomicAdd(&cnt[pairs[j].y - d0], 1);
    __syncthreads();

    // exclusive scan of cnt[0..511] with 256 threads (2 elems each)
    int c0v = cnt[2 * tid], c1v = cnt[2 * tid + 1];
    int psum = c0v + c1v;
    s2[tid] = psum;
    __syncthreads();
    for (int off = 1; off < THREADS; off <<= 1) {
        int t = (tid >= off) ? s2[tid - off] : 0;
        __syncthreads();
        s2[tid] += t;
        __syncthreads();
    }
    int ex = s2[tid] - psum;            // exclusive prefix of pair-sums
    cur[2 * tid]     = p0 + ex;
    cur[2 * tid + 1] = p0 + ex + c0v;
    __syncthreads();

    // rowptr + dis for this bucket's nodes
    for (int i = tid; i < nd; i += THREADS) {
        rowptr[d0 + i] = cur[i];
        dis[d0 + i] = rsqrtf((float)(cnt[i] + 1));   // +1 self-loop
    }
    __syncthreads();

    // pass B: scatter srcs into csr (LDS cursor atomics)
    for (int j = p0 + tid; j < p1; j += THREADS) {
        int2 pr = pairs[j];
        int pos = atomicAdd(&cur[pr.y - d0], 1);
        csr[pos] = pr.x;
    }
}

// ---------------- fused GEMM ----------------
// Per row r:  xrow = PRE ? swish(X[r]*dis[r] + bin) : X[r]
//             hs[r] = (xrow @ W) * dis[r]
template <int KTOT, int OUT, bool PRE>
__global__ __launch_bounds__(THREADS) void gemm_kernel(
    const float* __restrict__ X, const float* __restrict__ W,
    const float* __restrict__ bin, const float* __restrict__ dis,
    float* __restrict__ hs, int n)
{
    constexpr int KC   = 64;
    constexpr int RPT  = (OUT == 64) ? 4 : 2;
    constexpr int OPT  = (OUT == 64) ? 4 : 5;
    constexpr int ROWG = 64 / RPT;

    __shared__ float Xs[64][KC + 1];
    __shared__ float Ws[KC * OUT];

    const int tid  = threadIdx.x;
    const int row0 = blockIdx.x * 64;
    const int rg   = (tid % ROWG) * RPT;
    const int og   = (tid / ROWG) * OPT;

    float acc[RPT][OPT];
#pragma unroll
    for (int i = 0; i < RPT; ++i)
#pragma unroll
        for (int j = 0; j < OPT; ++j) acc[i][j] = 0.f;

    for (int kc = 0; kc < KTOT; kc += KC) {
        const float4* W4 = (const float4*)(W + (size_t)kc * OUT);
        for (int i = tid; i < KC * OUT / 4; i += THREADS)
            ((float4*)Ws)[i] = W4[i];
        for (int i = tid; i < 64 * KC / 4; i += THREADS) {
            int r   = i >> 4;
            int c4  = i & 15;
            int row = row0 + r;
            float4 v = make_float4(0.f, 0.f, 0.f, 0.f);
            if (row < n) {
                v = *(const float4*)(X + (size_t)row * KTOT + kc + c4 * 4);
                if (PRE) {
                    float dd = dis[row];
                    int   cb = kc + c4 * 4;
                    float h;
                    h = v.x * dd + bin[cb + 0]; v.x = h / (1.f + __expf(-h));
                    h = v.y * dd + bin[cb + 1]; v.y = h / (1.f + __expf(-h));
                    h = v.z * dd + bin[cb + 2]; v.z = h / (1.f + __expf(-h));
                    h = v.w * dd + bin[cb + 3]; v.w = h / (1.f + __expf(-h));
                }
            }
            int c = c4 * 4;
            Xs[r][c]     = v.x;
            Xs[r][c + 1] = v.y;
            Xs[r][c + 2] = v.z;
            Xs[r][c + 3] = v.w;
        }
        __syncthreads();

        for (int k = 0; k < KC; ++k) {
            float xv[RPT], wv[OPT];
#pragma unroll
            for (int i = 0; i < RPT; ++i) xv[i] = Xs[rg + i][k];
#pragma unroll
            for (int j = 0; j < OPT; ++j) wv[j] = Ws[k * OUT + og + j];
#pragma unroll
            for (int i = 0; i < RPT; ++i)
#pragma unroll
                for (int j = 0; j < OPT; ++j) acc[i][j] += xv[i] * wv[j];
        }
        __syncthreads();
    }

#pragma unroll
    for (int i = 0; i < RPT; ++i) {
        int row = row0 + rg + i;
        if (row < n) {
            float dd = dis[row];
#pragma unroll
            for (int j = 0; j < OPT; ++j)
                hs[(size_t)row * OUT + og + j] = acc[i][j] * dd;
        }
    }
}

// ---------------- CSR gather-aggregate: one wave per dst row, 4 edges/step ----
// agg[d] = hs[d] + sum_{s in in-edges(d)} hs[s]
template <int F>
__global__ __launch_bounds__(THREADS) void agg_csr4_kernel(
    const int* __restrict__ rowptr, const int* __restrict__ csr,
    const float* __restrict__ hs, float* __restrict__ agg, int n)
{
    constexpr int C4 = F / 4;
    const int d = blockIdx.x * 4 + (threadIdx.x >> 6);
    const int lane = threadIdx.x & 63;
    if (d >= n) return;
    const int sub = lane >> 4;
    const int c4  = lane & 15;
    const bool act = (c4 < C4);

    const int beg = rowptr[d], end = rowptr[d + 1];
    float4 acc = make_float4(0.f, 0.f, 0.f, 0.f);
    if (sub == 0 && act)
        acc = *(const float4*)(hs + (size_t)d * F + c4 * 4);

    for (int j = beg; j < end; j += 64) {
        int m = end - j; if (m > 64) m = 64;
        int eidx = (j + lane < end) ? csr[j + lane] : 0;
        for (int t = 0; t < m; t += 4) {
            int slot = t + sub;
            int s = __shfl(eidx, slot);
            if (slot < m && act) {
                float4 v = *(const float4*)(hs + (size_t)s * F + c4 * 4);
                acc.x += v.x; acc.y += v.y; acc.z += v.z; acc.w += v.w;
            }
        }
    }
    acc.x += __shfl_xor(acc.x, 16); acc.y += __shfl_xor(acc.y, 16);
    acc.z += __shfl_xor(acc.z, 16); acc.w += __shfl_xor(acc.w, 16);
    acc.x += __shfl_xor(acc.x, 32); acc.y += __shfl_xor(acc.y, 32);
    acc.z += __shfl_xor(acc.z, 32); acc.w += __shfl_xor(acc.w, 32);
    if (sub == 0 && act)
        *(float4*)(agg + (size_t)d * F + c4 * 4) = acc;
}

// ---------------- layer-3 aggregate fused with bias + log_softmax ------------
// out[d] = log_softmax( (hs3[d] + sum_src hs3[src]) * dis[d] + b3 )
__global__ __launch_bounds__(THREADS) void agg40_lsm_kernel(
    const int* __restrict__ rowptr, const int* __restrict__ csr,
    const float* __restrict__ hs, const float* __restrict__ dis,
    const float* __restrict__ b3, float* __restrict__ out, int n)
{
    constexpr int F = 40, C4 = 10;
    const int d = blockIdx.x * 4 + (threadIdx.x >> 6);
    const int lane = threadIdx.x & 63;
    if (d >= n) return;
    const int sub = lane >> 4;
    const int c4  = lane & 15;
    const bool act = (c4 < C4);

    const int beg = rowptr[d], end = rowptr[d + 1];
    float4 acc = make_float4(0.f, 0.f, 0.f, 0.f);
    if (sub == 0 && act)
        acc = *(const float4*)(hs + (size_t)d * F + c4 * 4);

    for (int j = beg; j < end; j += 64) {
        int m = end - j; if (m > 64) m = 64;
        int eidx = (j + lane < end) ? csr[j + lane] : 0;
        for (int t = 0; t < m; t += 4) {
            int slot = t + sub;
            int s = __shfl(eidx, slot);
            if (slot < m && act) {
                float4 v = *(const float4*)(hs + (size_t)s * F + c4 * 4);
                acc.x += v.x; acc.y += v.y; acc.z += v.z; acc.w += v.w;
            }
        }
    }
    acc.x += __shfl_xor(acc.x, 16); acc.y += __shfl_xor(acc.y, 16);
    acc.z += __shfl_xor(acc.z, 16); acc.w += __shfl_xor(acc.w, 16);
    acc.x += __shfl_xor(acc.x, 32); acc.y += __shfl_xor(acc.y, 32);
    acc.z += __shfl_xor(acc.z, 32); acc.w += __shfl_xor(acc.w, 32);

    if (sub != 0) return;   // lanes 0..15 carry the row; xor masks below stay <16

    float4 val = make_float4(-1e30f, -1e30f, -1e30f, -1e30f);
    if (act) {
        float dd = dis[d];
        val.x = acc.x * dd + b3[c4 * 4 + 0];
        val.y = acc.y * dd + b3[c4 * 4 + 1];
        val.z = acc.z * dd + b3[c4 * 4 + 2];
        val.w = acc.w * dd + b3[c4 * 4 + 3];
    }
    float mx = fmaxf(fmaxf(val.x, val.y), fmaxf(val.z, val.w));
#pragma unroll
    for (int off = 8; off > 0; off >>= 1) mx = fmaxf(mx, __shfl_xor(mx, off));
    float es = act ? (__expf(val.x - mx) + __expf(val.y - mx) +
                      __expf(val.z - mx) + __expf(val.w - mx)) : 0.f;
#pragma unroll
    for (int off = 8; off > 0; off >>= 1) es += __shfl_xor(es, off);
    float lse = mx + __logf(es);
    if (act) {
        float4 o = make_float4(val.x - lse, val.y - lse, val.z - lse, val.w - lse);
        *(float4*)(out + (size_t)d * F + c4 * 4) = o;
    }
}

// ---------------- launch ----------------
static inline size_t align_up(size_t v, size_t a) { return (v + a - 1) & ~(a - 1); }

extern "C" void kernel_launch(void* const* d_in, const int* in_sizes, int n_in,
                              void* d_out, int out_size, void* d_ws, size_t ws_size,
                              hipStream_t stream) {
    const float* x  = (const float*)d_in[0];
    const int*   ei = (const int*)d_in[1];
    const float* W1 = (const float*)d_in[2];
    const float* b1 = (const float*)d_in[3];
    const float* W2 = (const float*)d_in[4];
    const float* b2 = (const float*)d_in[5];
    const float* W3 = (const float*)d_in[6];
    const float* b3 = (const float*)d_in[7];
    float* out = (float*)d_out;

    const int n = in_sizes[0] / 128;
    const int e = in_sizes[1] / 2;
    const int* src = ei;
    const int* dst = ei + e;

    // workspace: dis[n] | rowptr[n+1] | bcnt[1k] | bbase[1k+1] | pcur[1k] | csr[e] | buf0 | buf1
    // pairs[e] (int2) aliases buf0 (consumed in sort2 before gemm1 writes buf0).
    char* base = (char*)d_ws;
    size_t off = 0;
    float* dis = (float*)(base + off);    off = align_up(off + (size_t)n * 4, 256);
    int* rowptr = (int*)(base + off);     off = align_up(off + (size_t)(n + 1) * 4, 256);
    int* bcnt = (int*)(base + off);       off = align_up(off + 1024 * 4, 256);
    int* bbase = (int*)(base + off);      off = align_up(off + 1025 * 4, 256);
    int* pcur = (int*)(base + off);       off = align_up(off + 1024 * 4, 256);
    int* csr = (int*)(base + off);        off = align_up(off + (size_t)e * 4, 256);
    float* buf0 = (float*)(base + off);   off = align_up(off + (size_t)n * 64 * 4, 256);
    float* buf1 = (float*)(base + off);   off = align_up(off + (size_t)n * 64 * 4, 256);
    int2* pairs = (int2*)buf0;

    const int gb_rows = (n + 63) / 64;
    const int nbuck   = (n + BSIZE - 1) >> BSHIFT;           // 196 for n=100k
    const int gb_s1   = (e + PASS1_CHUNK - 1) / PASS1_CHUNK;
    const int gb_agg  = (n + 3) / 4;

    // CSR build (all per-node/per-edge atomics are LDS-local)
    bzero_kernel<<<1, THREADS, 0, stream>>>(bcnt, nbuck);
    bhist_kernel<<<gb_s1, THREADS, 0, stream>>>(dst, bcnt, e, nbuck);
    bscan_kernel<<<1, 1024, 0, stream>>>(bcnt, bbase, pcur, rowptr, nbuck, n, e);
    sort1_kernel<<<gb_s1, THREADS, 0, stream>>>(src, dst, pcur, pairs, e, nbuck);
    sort2_kernel<<<nbuck, THREADS, 0, stream>>>(bbase, pairs, rowptr, dis, csr, n);

    // layer 1
    gemm_kernel<128, 64, false><<<gb_rows, THREADS, 0, stream>>>(x, W1, nullptr, dis, buf0, n);
    agg_csr4_kernel<64><<<gb_agg, THREADS, 0, stream>>>(rowptr, csr, buf0, buf1, n);

    // layer 2
    gemm_kernel<64, 64, true><<<gb_rows, THREADS, 0, stream>>>(buf1, W2, b1, dis, buf0, n);
    agg_csr4_kernel<64><<<gb_agg, THREADS, 0, stream>>>(rowptr, csr, buf0, buf1, n);

    // layer 3 (+ fused bias + log_softmax)
    gemm_kernel<64, 40, true><<<gb_rows, THREADS, 0, stream>>>(buf1, W3, b2, dis, buf0, n);
    agg40_lsm_kernel<<<gb_agg, THREADS, 0, stream>>>(rowptr, csr, buf0, dis, b3, out, n);
}

// Round 5
// 326.126 us; speedup vs baseline: 3.5239x; 1.0946x over previous
//
#include <hip/hip_runtime.h>
#include <math.h>

#define THREADS 256
#define BSHIFT 9              // 512 dsts per bucket
#define BSIZE (1 << BSHIFT)
#define PASS1_CHUNK 4096
#define SRC_BITS 17           // n < 131072

typedef unsigned int u32;
typedef unsigned short u16;

__device__ __forceinline__ u16 f2bf(float f) {      // RNE fp32 -> bf16
    u32 u = __float_as_uint(f);
    u = (u + 0x7fffu + ((u >> 16) & 1u)) >> 16;
    return (u16)u;
}

// ---------------- bucket histogram ----------------

__global__ __launch_bounds__(THREADS) void bzero_kernel(int* __restrict__ bcnt, int nbuck) {
    int i = threadIdx.x;
    if (i < nbuck) bcnt[i] = 0;
}

__global__ __launch_bounds__(THREADS) void bhist_kernel(const int* __restrict__ dst,
                                                        int* __restrict__ bcnt, int e, int nbuck) {
    __shared__ int hist[BSIZE];
    const int tid = threadIdx.x;
    const int c0  = blockIdx.x * PASS1_CHUNK;
    for (int i = tid; i < nbuck; i += THREADS) hist[i] = 0;
    __syncthreads();
    for (int i = tid; i < PASS1_CHUNK; i += THREADS) {
        int idx = c0 + i;
        if (idx < e) atomicAdd(&hist[dst[idx] >> BSHIFT], 1);
    }
    __syncthreads();
    for (int b = tid; b < nbuck; b += THREADS) {
        int h = hist[b];
        if (h) atomicAdd(&bcnt[b], h);
    }
}

// single block: exclusive scan of bucket counts -> bbase, pcur; rowptr[n]=e
__global__ __launch_bounds__(1024) void bscan_kernel(const int* __restrict__ bcnt,
                                                     int* __restrict__ bbase,
                                                     int* __restrict__ pcur,
                                                     int* __restrict__ rowptr,
                                                     int nbuck, int n, int e) {
    __shared__ int s[1024];
    int v = (threadIdx.x < nbuck) ? bcnt[threadIdx.x] : 0;
    s[threadIdx.x] = v;
    __syncthreads();
    for (int off = 1; off < 1024; off <<= 1) {
        int t = (threadIdx.x >= off) ? s[threadIdx.x - off] : 0;
        __syncthreads();
        s[threadIdx.x] += t;
        __syncthreads();
    }
    if (threadIdx.x < nbuck) {
        int ex = s[threadIdx.x] - v;
        bbase[threadIdx.x] = ex;
        pcur[threadIdx.x]  = ex;
    }
    if (threadIdx.x == 0) { bbase[nbuck] = e; rowptr[n] = e; }
}

// ---------------- sort pass 1: bin packed (ld<<17|src) into bucket regions ----

__global__ __launch_bounds__(THREADS) void sort1_kernel(
    const int* __restrict__ src, const int* __restrict__ dst,
    int* __restrict__ pcur, u32* __restrict__ pairs, int e, int nbuck)
{
    __shared__ int hist[BSIZE], hist2[BSIZE], base_s[BSIZE];
    const int tid = threadIdx.x;
    const int c0  = blockIdx.x * PASS1_CHUNK;
    for (int i = tid; i < nbuck; i += THREADS) { hist[i] = 0; hist2[i] = 0; }
    __syncthreads();
    for (int i = tid; i < PASS1_CHUNK; i += THREADS) {
        int idx = c0 + i;
        if (idx < e) atomicAdd(&hist[dst[idx] >> BSHIFT], 1);
    }
    __syncthreads();
    for (int b = tid; b < nbuck; b += THREADS) {
        int h = hist[b];
        base_s[b] = h ? atomicAdd(&pcur[b], h) : 0;
    }
    __syncthreads();
    for (int i = tid; i < PASS1_CHUNK; i += THREADS) {
        int idx = c0 + i;
        if (idx < e) {
            int d = dst[idx];
            int b = d >> BSHIFT;
            int off = atomicAdd(&hist2[b], 1);
            pairs[base_s[b] + off] = ((u32)(d & (BSIZE - 1)) << SRC_BITS) | (u32)src[idx];
        }
    }
}

// ---------------- sort pass 2: degree count + rowptr + dis + csr scatter ------

__global__ __launch_bounds__(THREADS) void sort2_kernel(
    const int* __restrict__ bbase, const u32* __restrict__ pairs,
    int* __restrict__ rowptr, float* __restrict__ dis,
    int* __restrict__ csr, int n)
{
    __shared__ int cnt[BSIZE];
    __shared__ int cur[BSIZE];
    __shared__ int s2[THREADS];

    const int b  = blockIdx.x;
    const int d0 = b << BSHIFT;
    const int nd = min(BSIZE, n - d0);
    const int p0 = bbase[b], p1 = bbase[b + 1];
    const int tid = threadIdx.x;

    for (int i = tid; i < BSIZE; i += THREADS) cnt[i] = 0;
    __syncthreads();

    for (int j = p0 + tid; j < p1; j += THREADS)
        atomicAdd(&cnt[pairs[j] >> SRC_BITS], 1);
    __syncthreads();

    int c0v = cnt[2 * tid], c1v = cnt[2 * tid + 1];
    int psum = c0v + c1v;
    s2[tid] = psum;
    __syncthreads();
    for (int off = 1; off < THREADS; off <<= 1) {
        int t = (tid >= off) ? s2[tid - off] : 0;
        __syncthreads();
        s2[tid] += t;
        __syncthreads();
    }
    int ex = s2[tid] - psum;
    cur[2 * tid]     = p0 + ex;
    cur[2 * tid + 1] = p0 + ex + c0v;
    __syncthreads();

    for (int i = tid; i < nd; i += THREADS) {
        rowptr[d0 + i] = cur[i];
        dis[d0 + i] = rsqrtf((float)(cnt[i] + 1));   // +1 self-loop
    }
    __syncthreads();

    for (int j = p0 + tid; j < p1; j += THREADS) {
        u32 pr = pairs[j];
        int pos = atomicAdd(&cur[pr >> SRC_BITS], 1);
        csr[pos] = (int)(pr & ((1u << SRC_BITS) - 1));
    }
}

// ---------------- fused GEMM (bf16 hs output) ----------------
// Per row r:  xrow = PRE ? swish(X[r]*dis[r] + bin) : X[r]
//             hs[r] = bf16( (xrow @ W) * dis[r] )
template <int KTOT, int OUT, int SOUT, bool PRE>
__global__ __launch_bounds__(THREADS) void gemm_kernel(
    const float* __restrict__ X, const float* __restrict__ W,
    const float* __restrict__ bin, const float* __restrict__ dis,
    u16* __restrict__ hs, int n)
{
    constexpr int KC   = 64;
    constexpr int RPT  = (OUT == 64) ? 4 : 2;
    constexpr int OPT  = (OUT == 64) ? 4 : 5;
    constexpr int ROWG = 64 / RPT;

    __shared__ float Xs[64][KC + 1];
    __shared__ float Ws[KC * OUT];

    const int tid  = threadIdx.x;
    const int row0 = blockIdx.x * 64;
    const int rg   = (tid % ROWG) * RPT;
    const int og   = (tid / ROWG) * OPT;

    float acc[RPT][OPT];
#pragma unroll
    for (int i = 0; i < RPT; ++i)
#pragma unroll
        for (int j = 0; j < OPT; ++j) acc[i][j] = 0.f;

    for (int kc = 0; kc < KTOT; kc += KC) {
        const float4* W4 = (const float4*)(W + (size_t)kc * OUT);
        for (int i = tid; i < KC * OUT / 4; i += THREADS)
            ((float4*)Ws)[i] = W4[i];
        for (int i = tid; i < 64 * KC / 4; i += THREADS) {
            int r   = i >> 4;
            int c4  = i & 15;
            int row = row0 + r;
            float4 v = make_float4(0.f, 0.f, 0.f, 0.f);
            if (row < n) {
                v = *(const float4*)(X + (size_t)row * KTOT + kc + c4 * 4);
                if (PRE) {
                    float dd = dis[row];
                    int   cb = kc + c4 * 4;
                    float h;
                    h = v.x * dd + bin[cb + 0]; v.x = h / (1.f + __expf(-h));
                    h = v.y * dd + bin[cb + 1]; v.y = h / (1.f + __expf(-h));
                    h = v.z * dd + bin[cb + 2]; v.z = h / (1.f + __expf(-h));
                    h = v.w * dd + bin[cb + 3]; v.w = h / (1.f + __expf(-h));
                }
            }
            int c = c4 * 4;
            Xs[r][c]     = v.x;
            Xs[r][c + 1] = v.y;
            Xs[r][c + 2] = v.z;
            Xs[r][c + 3] = v.w;
        }
        __syncthreads();

        for (int k = 0; k < KC; ++k) {
            float xv[RPT], wv[OPT];
#pragma unroll
            for (int i = 0; i < RPT; ++i) xv[i] = Xs[rg + i][k];
#pragma unroll
            for (int j = 0; j < OPT; ++j) wv[j] = Ws[k * OUT + og + j];
#pragma unroll
            for (int i = 0; i < RPT; ++i)
#pragma unroll
                for (int j = 0; j < OPT; ++j) acc[i][j] += xv[i] * wv[j];
        }
        __syncthreads();
    }

#pragma unroll
    for (int i = 0; i < RPT; ++i) {
        int row = row0 + rg + i;
        if (row < n) {
            float dd = dis[row];
            if (OUT == 64) {
                ushort4 o;
                o.x = f2bf(acc[i][0] * dd);
                o.y = f2bf(acc[i][1] * dd);
                o.z = f2bf(acc[i][2] * dd);
                o.w = f2bf(acc[i][3] * dd);
                *(ushort4*)(hs + (size_t)row * SOUT + og) = o;
            } else {
#pragma unroll
                for (int j = 0; j < OPT; ++j)
                    hs[(size_t)row * SOUT + og + j] = f2bf(acc[i][j] * dd);
            }
        }
    }
}

// ---------------- CSR gather-aggregate (bf16 gathers, fp32 out) ----------------
// agg[d] = hs[d] + sum_{s in in-edges(d)} hs[s]
__global__ __launch_bounds__(THREADS) void agg_csr4_kernel(
    const int* __restrict__ rowptr, const int* __restrict__ csr,
    const u16* __restrict__ hs, float* __restrict__ agg, int n)
{
    const int d = blockIdx.x * 4 + (threadIdx.x >> 6);
    const int lane = threadIdx.x & 63;
    if (d >= n) return;
    const int sub = lane >> 4;
    const int c4  = lane & 15;

    const int beg = rowptr[d], end = rowptr[d + 1];
    float4 acc = make_float4(0.f, 0.f, 0.f, 0.f);
    if (sub == 0) {
        uint2 u = *(const uint2*)(hs + (size_t)d * 64 + c4 * 4);
        acc.x = __uint_as_float(u.x << 16);
        acc.y = __uint_as_float(u.x & 0xffff0000u);
        acc.z = __uint_as_float(u.y << 16);
        acc.w = __uint_as_float(u.y & 0xffff0000u);
    }

    for (int j = beg; j < end; j += 64) {
        int m = end - j; if (m > 64) m = 64;
        int eidx = (j + lane < end) ? csr[j + lane] : 0;
        for (int t = 0; t < m; t += 4) {
            int slot = t + sub;
            int s = __shfl(eidx, slot);
            if (slot < m) {
                uint2 u = *(const uint2*)(hs + (size_t)s * 64 + c4 * 4);
                acc.x += __uint_as_float(u.x << 16);
                acc.y += __uint_as_float(u.x & 0xffff0000u);
                acc.z += __uint_as_float(u.y << 16);
                acc.w += __uint_as_float(u.y & 0xffff0000u);
            }
        }
    }
    acc.x += __shfl_xor(acc.x, 16); acc.y += __shfl_xor(acc.y, 16);
    acc.z += __shfl_xor(acc.z, 16); acc.w += __shfl_xor(acc.w, 16);
    acc.x += __shfl_xor(acc.x, 32); acc.y += __shfl_xor(acc.y, 32);
    acc.z += __shfl_xor(acc.z, 32); acc.w += __shfl_xor(acc.w, 32);
    if (sub == 0)
        *(float4*)(agg + (size_t)d * 64 + c4 * 4) = acc;
}

// ---------------- layer-3 aggregate + bias + log_softmax (bf16 gathers) -------
// hs3 rows: 40 bf16 at stride 48 (96B -> always 2 cache lines)
__global__ __launch_bounds__(THREADS) void agg40_lsm_kernel(
    const int* __restrict__ rowptr, const int* __restrict__ csr,
    const u16* __restrict__ hs, const float* __restrict__ dis,
    const float* __restrict__ b3, float* __restrict__ out, int n)
{
    constexpr int S = 48, C4 = 10;
    const int d = blockIdx.x * 4 + (threadIdx.x >> 6);
    const int lane = threadIdx.x & 63;
    if (d >= n) return;
    const int sub = lane >> 4;
    const int c4  = lane & 15;
    const bool act = (c4 < C4);

    const int beg = rowptr[d], end = rowptr[d + 1];
    float4 acc = make_float4(0.f, 0.f, 0.f, 0.f);
    if (sub == 0 && act) {
        uint2 u = *(const uint2*)(hs + (size_t)d * S + c4 * 4);
        acc.x = __uint_as_float(u.x << 16);
        acc.y = __uint_as_float(u.x & 0xffff0000u);
        acc.z = __uint_as_float(u.y << 16);
        acc.w = __uint_as_float(u.y & 0xffff0000u);
    }

    for (int j = beg; j < end; j += 64) {
        int m = end - j; if (m > 64) m = 64;
        int eidx = (j + lane < end) ? csr[j + lane] : 0;
        for (int t = 0; t < m; t += 4) {
            int slot = t + sub;
            int s = __shfl(eidx, slot);
            if (slot < m && act) {
                uint2 u = *(const uint2*)(hs + (size_t)s * S + c4 * 4);
                acc.x += __uint_as_float(u.x << 16);
                acc.y += __uint_as_float(u.x & 0xffff0000u);
                acc.z += __uint_as_float(u.y << 16);
                acc.w += __uint_as_float(u.y & 0xffff0000u);
            }
        }
    }
    acc.x += __shfl_xor(acc.x, 16); acc.y += __shfl_xor(acc.y, 16);
    acc.z += __shfl_xor(acc.z, 16); acc.w += __shfl_xor(acc.w, 16);
    acc.x += __shfl_xor(acc.x, 32); acc.y += __shfl_xor(acc.y, 32);
    acc.z += __shfl_xor(acc.z, 32); acc.w += __shfl_xor(acc.w, 32);

    if (sub != 0) return;   // lanes 0..15 carry the row

    float4 val = make_float4(-1e30f, -1e30f, -1e30f, -1e30f);
    if (act) {
        float dd = dis[d];
        val.x = acc.x * dd + b3[c4 * 4 + 0];
        val.y = acc.y * dd + b3[c4 * 4 + 1];
        val.z = acc.z * dd + b3[c4 * 4 + 2];
        val.w = acc.w * dd + b3[c4 * 4 + 3];
    }
    float mx = fmaxf(fmaxf(val.x, val.y), fmaxf(val.z, val.w));
#pragma unroll
    for (int off = 8; off > 0; off >>= 1) mx = fmaxf(mx, __shfl_xor(mx, off));
    float es = act ? (__expf(val.x - mx) + __expf(val.y - mx) +
                      __expf(val.z - mx) + __expf(val.w - mx)) : 0.f;
#pragma unroll
    for (int off = 8; off > 0; off >>= 1) es += __shfl_xor(es, off);
    float lse = mx + __logf(es);
    if (act) {
        float4 o = make_float4(val.x - lse, val.y - lse, val.z - lse, val.w - lse);
        *(float4*)(out + (size_t)d * 40 + c4 * 4) = o;
    }
}

// ---------------- launch ----------------
static inline size_t align_up(size_t v, size_t a) { return (v + a - 1) & ~(a - 1); }

extern "C" void kernel_launch(void* const* d_in, const int* in_sizes, int n_in,
                              void* d_out, int out_size, void* d_ws, size_t ws_size,
                              hipStream_t stream) {
    const float* x  = (const float*)d_in[0];
    const int*   ei = (const int*)d_in[1];
    const float* W1 = (const float*)d_in[2];
    const float* b1 = (const float*)d_in[3];
    const float* W2 = (const float*)d_in[4];
    const float* b2 = (const float*)d_in[5];
    const float* W3 = (const float*)d_in[6];
    const float* b3 = (const float*)d_in[7];
    float* out = (float*)d_out;

    const int n = in_sizes[0] / 128;
    const int e = in_sizes[1] / 2;
    const int* src = ei;
    const int* dst = ei + e;

    // workspace: dis[n] | rowptr[n+1] | bcnt[1k] | bbase[1k+1] | pcur[1k] |
    //            csr[e] | hsb (n*64 u16) | aggbuf (n*64 f32)
    // pairs u32[e] aliases hsb (consumed in sort2 before gemm1 writes hsb).
    char* base = (char*)d_ws;
    size_t off = 0;
    float* dis = (float*)(base + off);    off = align_up(off + (size_t)n * 4, 256);
    int* rowptr = (int*)(base + off);     off = align_up(off + (size_t)(n + 1) * 4, 256);
    int* bcnt = (int*)(base + off);       off = align_up(off + 1024 * 4, 256);
    int* bbase = (int*)(base + off);      off = align_up(off + 1025 * 4, 256);
    int* pcur = (int*)(base + off);       off = align_up(off + 1024 * 4, 256);
    int* csr = (int*)(base + off);        off = align_up(off + (size_t)e * 4, 256);
    u16* hsb = (u16*)(base + off);        off = align_up(off + (size_t)n * 64 * 2, 256);
    float* aggbuf = (float*)(base + off); off = align_up(off + (size_t)n * 64 * 4, 256);
    u32* pairs = (u32*)hsb;

    const int gb_rows = (n + 63) / 64;
    const int nbuck   = (n + BSIZE - 1) >> BSHIFT;
    const int gb_s1   = (e + PASS1_CHUNK - 1) / PASS1_CHUNK;
    const int gb_agg  = (n + 3) / 4;

    // CSR build
    bzero_kernel<<<1, THREADS, 0, stream>>>(bcnt, nbuck);
    bhist_kernel<<<gb_s1, THREADS, 0, stream>>>(dst, bcnt, e, nbuck);
    bscan_kernel<<<1, 1024, 0, stream>>>(bcnt, bbase, pcur, rowptr, nbuck, n, e);
    sort1_kernel<<<gb_s1, THREADS, 0, stream>>>(src, dst, pcur, pairs, e, nbuck);
    sort2_kernel<<<nbuck, THREADS, 0, stream>>>(bbase, pairs, rowptr, dis, csr, n);

    // layer 1: x @ W1 -> hsb (bf16); gather-agg -> aggbuf (f32)
    gemm_kernel<128, 64, 64, false><<<gb_rows, THREADS, 0, stream>>>(x, W1, nullptr, dis, hsb, n);
    agg_csr4_kernel<<<gb_agg, THREADS, 0, stream>>>(rowptr, csr, hsb, aggbuf, n);

    // layer 2
    gemm_kernel<64, 64, 64, true><<<gb_rows, THREADS, 0, stream>>>(aggbuf, W2, b1, dis, hsb, n);
    agg_csr4_kernel<<<gb_agg, THREADS, 0, stream>>>(rowptr, csr, hsb, aggbuf, n);

    // layer 3 (+ fused bias + log_softmax); hs3 stride 48
    gemm_kernel<64, 40, 48, true><<<gb_rows, THREADS, 0, stream>>>(aggbuf, W3, b2, dis, hsb, n);
    agg40_lsm_kernel<<<gb_agg, THREADS, 0, stream>>>(rowptr, csr, hsb, dis, b3, out, n);
}

// Round 6
// 310.850 us; speedup vs baseline: 3.6971x; 1.0491x over previous
//
#include <hip/hip_runtime.h>
#include <math.h>

#define THREADS 256
#define BSHIFT 9              // 512 dsts per bucket
#define BSIZE (1 << BSHIFT)
#define PASS1_CHUNK 4096
#define SRC_BITS 17           // n < 131072

typedef unsigned int u32;
typedef unsigned short u16;

__device__ __forceinline__ u16 f2bf(float f) {      // RNE fp32 -> bf16
    u32 u = __float_as_uint(f);
    u = (u + 0x7fffu + ((u >> 16) & 1u)) >> 16;
    return (u16)u;
}
__device__ __forceinline__ float bf_lo(u32 u) { return __uint_as_float(u << 16); }
__device__ __forceinline__ float bf_hi(u32 u) { return __uint_as_float(u & 0xffff0000u); }

// ---------------- bucket histogram ----------------

__global__ __launch_bounds__(THREADS) void bzero_kernel(int* __restrict__ bcnt, int nbuck) {
    int i = threadIdx.x;
    if (i < nbuck) bcnt[i] = 0;
}

__global__ __launch_bounds__(THREADS) void bhist_kernel(const int* __restrict__ dst,
                                                        int* __restrict__ bcnt, int e, int nbuck) {
    __shared__ int hist[BSIZE];
    const int tid = threadIdx.x;
    const int c0  = blockIdx.x * PASS1_CHUNK;
    for (int i = tid; i < nbuck; i += THREADS) hist[i] = 0;
    __syncthreads();
    for (int i = tid; i < PASS1_CHUNK; i += THREADS) {
        int idx = c0 + i;
        if (idx < e) atomicAdd(&hist[dst[idx] >> BSHIFT], 1);
    }
    __syncthreads();
    for (int b = tid; b < nbuck; b += THREADS) {
        int h = hist[b];
        if (h) atomicAdd(&bcnt[b], h);
    }
}

// single block: exclusive scan of bucket counts -> bbase, pcur; rowptr[n]=e
__global__ __launch_bounds__(1024) void bscan_kernel(const int* __restrict__ bcnt,
                                                     int* __restrict__ bbase,
                                                     int* __restrict__ pcur,
                                                     int* __restrict__ rowptr,
                                                     int nbuck, int n, int e) {
    __shared__ int s[1024];
    int v = (threadIdx.x < nbuck) ? bcnt[threadIdx.x] : 0;
    s[threadIdx.x] = v;
    __syncthreads();
    for (int off = 1; off < 1024; off <<= 1) {
        int t = (threadIdx.x >= off) ? s[threadIdx.x - off] : 0;
        __syncthreads();
        s[threadIdx.x] += t;
        __syncthreads();
    }
    if (threadIdx.x < nbuck) {
        int ex = s[threadIdx.x] - v;
        bbase[threadIdx.x] = ex;
        pcur[threadIdx.x]  = ex;
    }
    if (threadIdx.x == 0) { bbase[nbuck] = e; rowptr[n] = e; }
}

// ---------------- sort pass 1: bin packed (ld<<17|src) into bucket regions ----

__global__ __launch_bounds__(THREADS) void sort1_kernel(
    const int* __restrict__ src, const int* __restrict__ dst,
    int* __restrict__ pcur, u32* __restrict__ pairs, int e, int nbuck)
{
    __shared__ int hist[BSIZE], hist2[BSIZE], base_s[BSIZE];
    const int tid = threadIdx.x;
    const int c0  = blockIdx.x * PASS1_CHUNK;
    for (int i = tid; i < nbuck; i += THREADS) { hist[i] = 0; hist2[i] = 0; }
    __syncthreads();
    for (int i = tid; i < PASS1_CHUNK; i += THREADS) {
        int idx = c0 + i;
        if (idx < e) atomicAdd(&hist[dst[idx] >> BSHIFT], 1);
    }
    __syncthreads();
    for (int b = tid; b < nbuck; b += THREADS) {
        int h = hist[b];
        base_s[b] = h ? atomicAdd(&pcur[b], h) : 0;
    }
    __syncthreads();
    for (int i = tid; i < PASS1_CHUNK; i += THREADS) {
        int idx = c0 + i;
        if (idx < e) {
            int d = dst[idx];
            int b = d >> BSHIFT;
            int off = atomicAdd(&hist2[b], 1);
            pairs[base_s[b] + off] = ((u32)(d & (BSIZE - 1)) << SRC_BITS) | (u32)src[idx];
        }
    }
}

// ---------------- sort pass 2: degree count + rowptr + dis + csr scatter ------

__global__ __launch_bounds__(THREADS) void sort2_kernel(
    const int* __restrict__ bbase, const u32* __restrict__ pairs,
    int* __restrict__ rowptr, float* __restrict__ dis,
    int* __restrict__ csr, int n)
{
    __shared__ int cnt[BSIZE];
    __shared__ int cur[BSIZE];
    __shared__ int s2[THREADS];

    const int b  = blockIdx.x;
    const int d0 = b << BSHIFT;
    const int nd = min(BSIZE, n - d0);
    const int p0 = bbase[b], p1 = bbase[b + 1];
    const int tid = threadIdx.x;

    for (int i = tid; i < BSIZE; i += THREADS) cnt[i] = 0;
    __syncthreads();

    for (int j = p0 + tid; j < p1; j += THREADS)
        atomicAdd(&cnt[pairs[j] >> SRC_BITS], 1);
    __syncthreads();

    int c0v = cnt[2 * tid], c1v = cnt[2 * tid + 1];
    int psum = c0v + c1v;
    s2[tid] = psum;
    __syncthreads();
    for (int off = 1; off < THREADS; off <<= 1) {
        int t = (tid >= off) ? s2[tid - off] : 0;
        __syncthreads();
        s2[tid] += t;
        __syncthreads();
    }
    int ex = s2[tid] - psum;
    cur[2 * tid]     = p0 + ex;
    cur[2 * tid + 1] = p0 + ex + c0v;
    __syncthreads();

    for (int i = tid; i < nd; i += THREADS) {
        rowptr[d0 + i] = cur[i];
        dis[d0 + i] = rsqrtf((float)(cnt[i] + 1));   // +1 self-loop
    }
    __syncthreads();

    for (int j = p0 + tid; j < p1; j += THREADS) {
        u32 pr = pairs[j];
        int pos = atomicAdd(&cur[pr >> SRC_BITS], 1);
        csr[pos] = (int)(pr & ((1u << SRC_BITS) - 1));
    }
}

// ---------------- fused GEMM (bf16 hs output; bf16 or f32 input) --------------
// Per row r:  xrow = PRE ? swish(Xb[r]*dis[r] + bin) : Xf[r]
//             hs[r] = bf16( (xrow @ W) * dis[r] )
template <int KTOT, int OUT, int SOUT, bool PRE>
__global__ __launch_bounds__(THREADS) void gemm_kernel(
    const float* __restrict__ Xf, const u16* __restrict__ Xb,
    const float* __restrict__ W, const float* __restrict__ bin,
    const float* __restrict__ dis, u16* __restrict__ hs, int n)
{
    constexpr int KC   = 64;
    constexpr int RPT  = (OUT == 64) ? 4 : 2;
    constexpr int OPT  = (OUT == 64) ? 4 : 5;
    constexpr int ROWG = 64 / RPT;

    __shared__ float Xs[64][KC + 1];
    __shared__ float Ws[KC * OUT];

    const int tid  = threadIdx.x;
    const int row0 = blockIdx.x * 64;
    const int rg   = (tid % ROWG) * RPT;
    const int og   = (tid / ROWG) * OPT;

    float acc[RPT][OPT];
#pragma unroll
    for (int i = 0; i < RPT; ++i)
#pragma unroll
        for (int j = 0; j < OPT; ++j) acc[i][j] = 0.f;

    for (int kc = 0; kc < KTOT; kc += KC) {
        const float4* W4 = (const float4*)(W + (size_t)kc * OUT);
        for (int i = tid; i < KC * OUT / 4; i += THREADS)
            ((float4*)Ws)[i] = W4[i];
        if (PRE) {
            // bf16 input, KTOT==64: 8 bf16 (16B) per thread-iter, fused swish
            for (int i = tid; i < 64 * KC / 8; i += THREADS) {
                int r   = i >> 3;
                int c8  = (i & 7) * 8;
                int row = row0 + r;
                float v[8] = {0.f,0.f,0.f,0.f,0.f,0.f,0.f,0.f};
                if (row < n) {
                    uint4 u = *(const uint4*)(Xb + (size_t)row * KTOT + kc + c8);
                    float dd = dis[row];
                    u32 w[4] = {u.x, u.y, u.z, u.w};
#pragma unroll
                    for (int q = 0; q < 4; ++q) {
                        float a0 = bf_lo(w[q]), a1 = bf_hi(w[q]);
                        float h0 = a0 * dd + bin[kc + c8 + 2 * q];
                        float h1 = a1 * dd + bin[kc + c8 + 2 * q + 1];
                        v[2 * q]     = h0 / (1.f + __expf(-h0));
                        v[2 * q + 1] = h1 / (1.f + __expf(-h1));
                    }
                }
#pragma unroll
                for (int q = 0; q < 8; ++q) Xs[r][c8 + q] = v[q];
            }
        } else {
            for (int i = tid; i < 64 * KC / 4; i += THREADS) {
                int r   = i >> 4;
                int c4  = i & 15;
                int row = row0 + r;
                float4 v = make_float4(0.f, 0.f, 0.f, 0.f);
                if (row < n)
                    v = *(const float4*)(Xf + (size_t)row * KTOT + kc + c4 * 4);
                int c = c4 * 4;
                Xs[r][c]     = v.x;
                Xs[r][c + 1] = v.y;
                Xs[r][c + 2] = v.z;
                Xs[r][c + 3] = v.w;
            }
        }
        __syncthreads();

        for (int k = 0; k < KC; ++k) {
            float xv[RPT], wv[OPT];
#pragma unroll
            for (int i = 0; i < RPT; ++i) xv[i] = Xs[rg + i][k];
#pragma unroll
            for (int j = 0; j < OPT; ++j) wv[j] = Ws[k * OUT + og + j];
#pragma unroll
            for (int i = 0; i < RPT; ++i)
#pragma unroll
                for (int j = 0; j < OPT; ++j) acc[i][j] += xv[i] * wv[j];
        }
        __syncthreads();
    }

#pragma unroll
    for (int i = 0; i < RPT; ++i) {
        int row = row0 + rg + i;
        if (row < n) {
            float dd = dis[row];
            if (OUT == 64) {
                ushort4 o;
                o.x = f2bf(acc[i][0] * dd);
                o.y = f2bf(acc[i][1] * dd);
                o.z = f2bf(acc[i][2] * dd);
                o.w = f2bf(acc[i][3] * dd);
                *(ushort4*)(hs + (size_t)row * SOUT + og) = o;
            } else {
#pragma unroll
                for (int j = 0; j < OPT; ++j)
                    hs[(size_t)row * SOUT + og + j] = f2bf(acc[i][j] * dd);
            }
        }
    }
}

// ---------------- CSR gather-aggregate: 8 lanes x 16B, 8 edges in flight ------
// agg[d] = bf16( hs[d] + sum_{s in in-edges(d)} hs[s] );  rows are 64 bf16.
__global__ __launch_bounds__(THREADS) void agg64_kernel(
    const int* __restrict__ rowptr, const int* __restrict__ csr,
    const u16* __restrict__ hs, u16* __restrict__ agg, int n)
{
    const int d = blockIdx.x * 4 + (threadIdx.x >> 6);
    const int lane = threadIdx.x & 63;
    if (d >= n) return;
    const int sub = lane >> 3;          // edge slot 0..7
    const int c8  = (lane & 7) * 8;     // feature base (8 bf16 per lane)

    const int beg = rowptr[d], end = rowptr[d + 1];
    float acc[8] = {0.f,0.f,0.f,0.f,0.f,0.f,0.f,0.f};
    if (sub == 0) {
        uint4 u = *(const uint4*)(hs + (size_t)d * 64 + c8);
        acc[0] = bf_lo(u.x); acc[1] = bf_hi(u.x);
        acc[2] = bf_lo(u.y); acc[3] = bf_hi(u.y);
        acc[4] = bf_lo(u.z); acc[5] = bf_hi(u.z);
        acc[6] = bf_lo(u.w); acc[7] = bf_hi(u.w);
    }

    for (int j = beg; j < end; j += 64) {
        int m = end - j; if (m > 64) m = 64;
        int eidx = (j + lane < end) ? csr[j + lane] : 0;
        for (int t = 0; t < m; t += 8) {
            int slot = t + sub;
            int s = __shfl(eidx, slot);
            if (slot < m) {
                uint4 u = *(const uint4*)(hs + (size_t)s * 64 + c8);
                acc[0] += bf_lo(u.x); acc[1] += bf_hi(u.x);
                acc[2] += bf_lo(u.y); acc[3] += bf_hi(u.y);
                acc[4] += bf_lo(u.z); acc[5] += bf_hi(u.z);
                acc[6] += bf_lo(u.w); acc[7] += bf_hi(u.w);
            }
        }
    }
#pragma unroll
    for (int off = 8; off <= 32; off <<= 1)
#pragma unroll
        for (int q = 0; q < 8; ++q) acc[q] += __shfl_xor(acc[q], off);

    if (sub == 0) {
        uint4 o;
        o.x = (u32)f2bf(acc[0]) | ((u32)f2bf(acc[1]) << 16);
        o.y = (u32)f2bf(acc[2]) | ((u32)f2bf(acc[3]) << 16);
        o.z = (u32)f2bf(acc[4]) | ((u32)f2bf(acc[5]) << 16);
        o.w = (u32)f2bf(acc[6]) | ((u32)f2bf(acc[7]) << 16);
        *(uint4*)(agg + (size_t)d * 64 + c8) = o;
    }
}

// ---------------- layer-3 aggregate + bias + log_softmax ----------------------
// hs3 rows: 40 bf16 at stride 48 (96B). 8-lane subgroups, lanes 0..4 active.
__global__ __launch_bounds__(THREADS) void agg40_lsm_kernel(
    const int* __restrict__ rowptr, const int* __restrict__ csr,
    const u16* __restrict__ hs, const float* __restrict__ dis,
    const float* __restrict__ b3, float* __restrict__ out, int n)
{
    constexpr int S = 48;
    const int d = blockIdx.x * 4 + (threadIdx.x >> 6);
    const int lane = threadIdx.x & 63;
    if (d >= n) return;
    const int sub = lane >> 3;
    const int cl  = lane & 7;           // 16B chunk index; 0..4 active
    const bool act = (cl < 5);
    const int c8 = cl * 8;

    const int beg = rowptr[d], end = rowptr[d + 1];
    float acc[8] = {0.f,0.f,0.f,0.f,0.f,0.f,0.f,0.f};
    if (sub == 0 && act) {
        uint4 u = *(const uint4*)(hs + (size_t)d * S + c8);
        acc[0] = bf_lo(u.x); acc[1] = bf_hi(u.x);
        acc[2] = bf_lo(u.y); acc[3] = bf_hi(u.y);
        acc[4] = bf_lo(u.z); acc[5] = bf_hi(u.z);
        acc[6] = bf_lo(u.w); acc[7] = bf_hi(u.w);
    }

    for (int j = beg; j < end; j += 64) {
        int m = end - j; if (m > 64) m = 64;
        int eidx = (j + lane < end) ? csr[j + lane] : 0;
        for (int t = 0; t < m; t += 8) {
            int slot = t + sub;
            int s = __shfl(eidx, slot);
            if (slot < m && act) {
                uint4 u = *(const uint4*)(hs + (size_t)s * S + c8);
                acc[0] += bf_lo(u.x); acc[1] += bf_hi(u.x);
                acc[2] += bf_lo(u.y); acc[3] += bf_hi(u.y);
                acc[4] += bf_lo(u.z); acc[5] += bf_hi(u.z);
                acc[6] += bf_lo(u.w); acc[7] += bf_hi(u.w);
            }
        }
    }
#pragma unroll
    for (int off = 8; off <= 32; off <<= 1)
#pragma unroll
        for (int q = 0; q < 8; ++q) acc[q] += __shfl_xor(acc[q], off);

    if (sub != 0) return;   // lanes 0..7 carry the row (0..4 active)

    float val[8];
    float mx = -1e30f;
    if (act) {
        float dd = dis[d];
#pragma unroll
        for (int q = 0; q < 8; ++q) {
            val[q] = acc[q] * dd + b3[c8 + q];
            mx = fmaxf(mx, val[q]);
        }
    }
#pragma unroll
    for (int off = 4; off > 0; off >>= 1) mx = fmaxf(mx, __shfl_xor(mx, off));
    float es = 0.f;
    if (act) {
#pragma unroll
        for (int q = 0; q < 8; ++q) es += __expf(val[q] - mx);
    }
#pragma unroll
    for (int off = 4; off > 0; off >>= 1) es += __shfl_xor(es, off);
    float lse = mx + __logf(es);
    if (act) {
        float4 o0 = make_float4(val[0]-lse, val[1]-lse, val[2]-lse, val[3]-lse);
        float4 o1 = make_float4(val[4]-lse, val[5]-lse, val[6]-lse, val[7]-lse);
        *(float4*)(out + (size_t)d * 40 + c8)     = o0;
        *(float4*)(out + (size_t)d * 40 + c8 + 4) = o1;
    }
}

// ---------------- launch ----------------
static inline size_t align_up(size_t v, size_t a) { return (v + a - 1) & ~(a - 1); }

extern "C" void kernel_launch(void* const* d_in, const int* in_sizes, int n_in,
                              void* d_out, int out_size, void* d_ws, size_t ws_size,
                              hipStream_t stream) {
    const float* x  = (const float*)d_in[0];
    const int*   ei = (const int*)d_in[1];
    const float* W1 = (const float*)d_in[2];
    const float* b1 = (const float*)d_in[3];
    const float* W2 = (const float*)d_in[4];
    const float* b2 = (const float*)d_in[5];
    const float* W3 = (const float*)d_in[6];
    const float* b3 = (const float*)d_in[7];
    float* out = (float*)d_out;

    const int n = in_sizes[0] / 128;
    const int e = in_sizes[1] / 2;
    const int* src = ei;
    const int* dst = ei + e;

    // workspace: dis[n] | rowptr[n+1] | bcnt[1k] | bbase[1k+1] | pcur[1k] |
    //            csr[e] | hsb (n*64 u16) | aggb (n*64 u16)
    // pairs u32[e] aliases hsb (consumed in sort2 before gemm1 writes hsb).
    char* base = (char*)d_ws;
    size_t off = 0;
    float* dis = (float*)(base + off);    off = align_up(off + (size_t)n * 4, 256);
    int* rowptr = (int*)(base + off);     off = align_up(off + (size_t)(n + 1) * 4, 256);
    int* bcnt = (int*)(base + off);       off = align_up(off + 1024 * 4, 256);
    int* bbase = (int*)(base + off);      off = align_up(off + 1025 * 4, 256);
    int* pcur = (int*)(base + off);       off = align_up(off + 1024 * 4, 256);
    int* csr = (int*)(base + off);        off = align_up(off + (size_t)e * 4, 256);
    u16* hsb = (u16*)(base + off);        off = align_up(off + (size_t)n * 64 * 2, 256);
    u16* aggb = (u16*)(base + off);       off = align_up(off + (size_t)n * 64 * 2, 256);
    u32* pairs = (u32*)hsb;

    const int gb_rows = (n + 63) / 64;
    const int nbuck   = (n + BSIZE - 1) >> BSHIFT;
    const int gb_s1   = (e + PASS1_CHUNK - 1) / PASS1_CHUNK;
    const int gb_agg  = (n + 3) / 4;

    // CSR build
    bzero_kernel<<<1, THREADS, 0, stream>>>(bcnt, nbuck);
    bhist_kernel<<<gb_s1, THREADS, 0, stream>>>(dst, bcnt, e, nbuck);
    bscan_kernel<<<1, 1024, 0, stream>>>(bcnt, bbase, pcur, rowptr, nbuck, n, e);
    sort1_kernel<<<gb_s1, THREADS, 0, stream>>>(src, dst, pcur, pairs, e, nbuck);
    sort2_kernel<<<nbuck, THREADS, 0, stream>>>(bbase, pairs, rowptr, dis, csr, n);

    // layer 1: x @ W1 -> hsb (bf16); gather-agg -> aggb (bf16)
    gemm_kernel<128, 64, 64, false><<<gb_rows, THREADS, 0, stream>>>(
        x, nullptr, W1, nullptr, dis, hsb, n);
    agg64_kernel<<<gb_agg, THREADS, 0, stream>>>(rowptr, csr, hsb, aggb, n);

    // layer 2: swish(aggb*dis+b1) @ W2 -> hsb; gather-agg -> aggb
    gemm_kernel<64, 64, 64, true><<<gb_rows, THREADS, 0, stream>>>(
        nullptr, aggb, W2, b1, dis, hsb, n);
    agg64_kernel<<<gb_agg, THREADS, 0, stream>>>(rowptr, csr, hsb, aggb, n);

    // layer 3: swish(aggb*dis+b2) @ W3 -> hsb (stride 48); agg + lsm -> out
    gemm_kernel<64, 40, 48, true><<<gb_rows, THREADS, 0, stream>>>(
        nullptr, aggb, W3, b2, dis, hsb, n);
    agg40_lsm_kernel<<<gb_agg, THREADS, 0, stream>>>(rowptr, csr, hsb, dis, b3, out, n);
}

// Round 7
// 288.801 us; speedup vs baseline: 3.9793x; 1.0763x over previous
//
#include <hip/hip_runtime.h>
#include <math.h>

#define THREADS 256
#define BSHIFT 9              // 512 dsts per bucket
#define BSIZE (1 << BSHIFT)
#define PASS1_CHUNK 4096
#define SRC_BITS 17           // n < 131072

typedef unsigned int u32;
typedef unsigned short u16;

__device__ __forceinline__ u16 f2bf(float f) {      // RNE fp32 -> bf16
    u32 u = __float_as_uint(f);
    u = (u + 0x7fffu + ((u >> 16) & 1u)) >> 16;
    return (u16)u;
}
__device__ __forceinline__ float bf_lo(u32 u) { return __uint_as_float(u << 16); }
__device__ __forceinline__ float bf_hi(u32 u) { return __uint_as_float(u & 0xffff0000u); }

// ---------------- bucket histogram ----------------

__global__ __launch_bounds__(THREADS) void bzero_kernel(int* __restrict__ bcnt, int nbuck) {
    int i = threadIdx.x;
    if (i < nbuck) bcnt[i] = 0;
}

__global__ __launch_bounds__(THREADS) void bhist_kernel(const int* __restrict__ dst,
                                                        int* __restrict__ bcnt, int e, int nbuck) {
    __shared__ int hist[BSIZE];
    const int tid = threadIdx.x;
    const int c0  = blockIdx.x * PASS1_CHUNK;
    for (int i = tid; i < nbuck; i += THREADS) hist[i] = 0;
    __syncthreads();
    for (int i = tid; i < PASS1_CHUNK; i += THREADS) {
        int idx = c0 + i;
        if (idx < e) atomicAdd(&hist[dst[idx] >> BSHIFT], 1);
    }
    __syncthreads();
    for (int b = tid; b < nbuck; b += THREADS) {
        int h = hist[b];
        if (h) atomicAdd(&bcnt[b], h);
    }
}

// single block: exclusive scan of bucket counts -> bbase, pcur; rowptr[n]=e
__global__ __launch_bounds__(1024) void bscan_kernel(const int* __restrict__ bcnt,
                                                     int* __restrict__ bbase,
                                                     int* __restrict__ pcur,
                                                     int* __restrict__ rowptr,
                                                     int nbuck, int n, int e) {
    __shared__ int s[1024];
    int v = (threadIdx.x < nbuck) ? bcnt[threadIdx.x] : 0;
    s[threadIdx.x] = v;
    __syncthreads();
    for (int off = 1; off < 1024; off <<= 1) {
        int t = (threadIdx.x >= off) ? s[threadIdx.x - off] : 0;
        __syncthreads();
        s[threadIdx.x] += t;
        __syncthreads();
    }
    if (threadIdx.x < nbuck) {
        int ex = s[threadIdx.x] - v;
        bbase[threadIdx.x] = ex;
        pcur[threadIdx.x]  = ex;
    }
    if (threadIdx.x == 0) { bbase[nbuck] = e; rowptr[n] = e; }
}

// ---------------- sort pass 1: bin packed (ld<<17|src) into bucket regions ----

__global__ __launch_bounds__(THREADS) void sort1_kernel(
    const int* __restrict__ src, const int* __restrict__ dst,
    int* __restrict__ pcur, u32* __restrict__ pairs, int e, int nbuck)
{
    __shared__ int hist[BSIZE], hist2[BSIZE], base_s[BSIZE];
    const int tid = threadIdx.x;
    const int c0  = blockIdx.x * PASS1_CHUNK;
    for (int i = tid; i < nbuck; i += THREADS) { hist[i] = 0; hist2[i] = 0; }
    __syncthreads();
    for (int i = tid; i < PASS1_CHUNK; i += THREADS) {
        int idx = c0 + i;
        if (idx < e) atomicAdd(&hist[dst[idx] >> BSHIFT], 1);
    }
    __syncthreads();
    for (int b = tid; b < nbuck; b += THREADS) {
        int h = hist[b];
        base_s[b] = h ? atomicAdd(&pcur[b], h) : 0;
    }
    __syncthreads();
    for (int i = tid; i < PASS1_CHUNK; i += THREADS) {
        int idx = c0 + i;
        if (idx < e) {
            int d = dst[idx];
            int b = d >> BSHIFT;
            int off = atomicAdd(&hist2[b], 1);
            pairs[base_s[b] + off] = ((u32)(d & (BSIZE - 1)) << SRC_BITS) | (u32)src[idx];
        }
    }
}

// ---------------- sort pass 2: degree count + rowptr + dis + csr scatter ------

__global__ __launch_bounds__(THREADS) void sort2_kernel(
    const int* __restrict__ bbase, const u32* __restrict__ pairs,
    int* __restrict__ rowptr, float* __restrict__ dis,
    int* __restrict__ csr, int n)
{
    __shared__ int cnt[BSIZE];
    __shared__ int cur[BSIZE];
    __shared__ int s2[THREADS];

    const int b  = blockIdx.x;
    const int d0 = b << BSHIFT;
    const int nd = min(BSIZE, n - d0);
    const int p0 = bbase[b], p1 = bbase[b + 1];
    const int tid = threadIdx.x;

    for (int i = tid; i < BSIZE; i += THREADS) cnt[i] = 0;
    __syncthreads();

    for (int j = p0 + tid; j < p1; j += THREADS)
        atomicAdd(&cnt[pairs[j] >> SRC_BITS], 1);
    __syncthreads();

    int c0v = cnt[2 * tid], c1v = cnt[2 * tid + 1];
    int psum = c0v + c1v;
    s2[tid] = psum;
    __syncthreads();
    for (int off = 1; off < THREADS; off <<= 1) {
        int t = (tid >= off) ? s2[tid - off] : 0;
        __syncthreads();
        s2[tid] += t;
        __syncthreads();
    }
    int ex = s2[tid] - psum;
    cur[2 * tid]     = p0 + ex;
    cur[2 * tid + 1] = p0 + ex + c0v;
    __syncthreads();

    for (int i = tid; i < nd; i += THREADS) {
        rowptr[d0 + i] = cur[i];
        dis[d0 + i] = rsqrtf((float)(cnt[i] + 1));   // +1 self-loop
    }
    __syncthreads();

    for (int j = p0 + tid; j < p1; j += THREADS) {
        u32 pr = pairs[j];
        int pos = atomicAdd(&cur[pr >> SRC_BITS], 1);
        csr[pos] = (int)(pr & ((1u << SRC_BITS) - 1));
    }
}

// ---------------- fused GEMM (bf16 hs output; bf16 or f32 input) --------------
// Per row r:  xrow = PRE ? swish(Xb[r]*dis[r] + bin) : Xf[r]
//             hs[r] = bf16( (xrow @ W) * dis[r] )
template <int KTOT, int OUT, int SOUT, bool PRE>
__global__ __launch_bounds__(THREADS) void gemm_kernel(
    const float* __restrict__ Xf, const u16* __restrict__ Xb,
    const float* __restrict__ W, const float* __restrict__ bin,
    const float* __restrict__ dis, u16* __restrict__ hs, int n)
{
    constexpr int KC   = 64;
    constexpr int RPT  = (OUT == 64) ? 4 : 2;
    constexpr int OPT  = (OUT == 64) ? 4 : 5;
    constexpr int ROWG = 64 / RPT;

    __shared__ float Xs[64][KC + 1];
    __shared__ float Ws[KC * OUT];

    const int tid  = threadIdx.x;
    const int row0 = blockIdx.x * 64;
    const int rg   = (tid % ROWG) * RPT;
    const int og   = (tid / ROWG) * OPT;

    float acc[RPT][OPT];
#pragma unroll
    for (int i = 0; i < RPT; ++i)
#pragma unroll
        for (int j = 0; j < OPT; ++j) acc[i][j] = 0.f;

    for (int kc = 0; kc < KTOT; kc += KC) {
        const float4* W4 = (const float4*)(W + (size_t)kc * OUT);
        for (int i = tid; i < KC * OUT / 4; i += THREADS)
            ((float4*)Ws)[i] = W4[i];
        if (PRE) {
            for (int i = tid; i < 64 * KC / 8; i += THREADS) {
                int r   = i >> 3;
                int c8  = (i & 7) * 8;
                int row = row0 + r;
                float v[8] = {0.f,0.f,0.f,0.f,0.f,0.f,0.f,0.f};
                if (row < n) {
                    uint4 u = *(const uint4*)(Xb + (size_t)row * KTOT + kc + c8);
                    float dd = dis[row];
                    u32 w[4] = {u.x, u.y, u.z, u.w};
#pragma unroll
                    for (int q = 0; q < 4; ++q) {
                        float a0 = bf_lo(w[q]), a1 = bf_hi(w[q]);
                        float h0 = a0 * dd + bin[kc + c8 + 2 * q];
                        float h1 = a1 * dd + bin[kc + c8 + 2 * q + 1];
                        v[2 * q]     = h0 / (1.f + __expf(-h0));
                        v[2 * q + 1] = h1 / (1.f + __expf(-h1));
                    }
                }
#pragma unroll
                for (int q = 0; q < 8; ++q) Xs[r][c8 + q] = v[q];
            }
        } else {
            for (int i = tid; i < 64 * KC / 4; i += THREADS) {
                int r   = i >> 4;
                int c4  = i & 15;
                int row = row0 + r;
                float4 v = make_float4(0.f, 0.f, 0.f, 0.f);
                if (row < n)
                    v = *(const float4*)(Xf + (size_t)row * KTOT + kc + c4 * 4);
                int c = c4 * 4;
                Xs[r][c]     = v.x;
                Xs[r][c + 1] = v.y;
                Xs[r][c + 2] = v.z;
                Xs[r][c + 3] = v.w;
            }
        }
        __syncthreads();

        for (int k = 0; k < KC; ++k) {
            float xv[RPT], wv[OPT];
#pragma unroll
            for (int i = 0; i < RPT; ++i) xv[i] = Xs[rg + i][k];
#pragma unroll
            for (int j = 0; j < OPT; ++j) wv[j] = Ws[k * OUT + og + j];
#pragma unroll
            for (int i = 0; i < RPT; ++i)
#pragma unroll
                for (int j = 0; j < OPT; ++j) acc[i][j] += xv[i] * wv[j];
        }
        __syncthreads();
    }

#pragma unroll
    for (int i = 0; i < RPT; ++i) {
        int row = row0 + rg + i;
        if (row < n) {
            float dd = dis[row];
            if (OUT == 64) {
                ushort4 o;
                o.x = f2bf(acc[i][0] * dd);
                o.y = f2bf(acc[i][1] * dd);
                o.z = f2bf(acc[i][2] * dd);
                o.w = f2bf(acc[i][3] * dd);
                *(ushort4*)(hs + (size_t)row * SOUT + og) = o;
            } else {
#pragma unroll
                for (int j = 0; j < OPT; ++j)
                    hs[(size_t)row * SOUT + og + j] = f2bf(acc[i][j] * dd);
            }
        }
    }
}

// ---------------- CSR gather-aggregate: one 8-lane subgroup per dst row -------
// agg[d] = bf16( hs[d] + sum_{s in in-edges(d)} hs[s] );  rows are 64 bf16.
// 8 rows per wave, 32 per block. Features partitioned across the subgroup's
// 8 lanes (16B each); edges serialized within the subgroup -> no cross-subgroup
// reduction, per-row overhead amortized 8x wave-wide.
__global__ __launch_bounds__(THREADS) void agg64_kernel(
    const int* __restrict__ rowptr, const int* __restrict__ csr,
    const u16* __restrict__ hs, u16* __restrict__ agg, int n)
{
    const int lane = threadIdx.x & 63;
    const int sub  = lane >> 3;                 // subgroup 0..7 (one row each)
    const int gl   = lane & 7;                  // lane in subgroup
    const int d = (blockIdx.x * 4 + (threadIdx.x >> 6)) * 8 + sub;
    if (d >= n) return;
    const int c8 = gl * 8;                      // feature base

    const int beg = rowptr[d], end = rowptr[d + 1];
    float acc[8];
    {
        uint4 u = *(const uint4*)(hs + (size_t)d * 64 + c8);   // self-loop
        acc[0] = bf_lo(u.x); acc[1] = bf_hi(u.x);
        acc[2] = bf_lo(u.y); acc[3] = bf_hi(u.y);
        acc[4] = bf_lo(u.z); acc[5] = bf_hi(u.z);
        acc[6] = bf_lo(u.w); acc[7] = bf_hi(u.w);
    }

    for (int t = beg; t < end; t += 8) {
        int eidx = (t + gl < end) ? csr[t + gl] : 0;   // 8 edges for this row
        int m = min(end - t, 8);
        for (int q = 0; q < m; ++q) {
            int s = __shfl(eidx, (sub << 3) + q);      // intra-subgroup broadcast
            uint4 u = *(const uint4*)(hs + (size_t)s * 64 + c8);
            acc[0] += bf_lo(u.x); acc[1] += bf_hi(u.x);
            acc[2] += bf_lo(u.y); acc[3] += bf_hi(u.y);
            acc[4] += bf_lo(u.z); acc[5] += bf_hi(u.z);
            acc[6] += bf_lo(u.w); acc[7] += bf_hi(u.w);
        }
    }

    uint4 o;
    o.x = (u32)f2bf(acc[0]) | ((u32)f2bf(acc[1]) << 16);
    o.y = (u32)f2bf(acc[2]) | ((u32)f2bf(acc[3]) << 16);
    o.z = (u32)f2bf(acc[4]) | ((u32)f2bf(acc[5]) << 16);
    o.w = (u32)f2bf(acc[6]) | ((u32)f2bf(acc[7]) << 16);
    *(uint4*)(agg + (size_t)d * 64 + c8) = o;
}

// ---------------- layer-3 aggregate + bias + log_softmax ----------------------
// hs3 rows: 40 bf16 at stride 48 (96B). One 8-lane subgroup per row; lanes
// gl<5 carry features, all 8 lanes fetch csr edges.
__global__ __launch_bounds__(THREADS) void agg40_lsm_kernel(
    const int* __restrict__ rowptr, const int* __restrict__ csr,
    const u16* __restrict__ hs, const float* __restrict__ dis,
    const float* __restrict__ b3, float* __restrict__ out, int n)
{
    constexpr int S = 48;
    const int lane = threadIdx.x & 63;
    const int sub  = lane >> 3;
    const int gl   = lane & 7;
    const int d = (blockIdx.x * 4 + (threadIdx.x >> 6)) * 8 + sub;
    if (d >= n) return;
    const bool act = (gl < 5);
    const int c8 = gl * 8;

    const int beg = rowptr[d], end = rowptr[d + 1];
    float acc[8] = {0.f,0.f,0.f,0.f,0.f,0.f,0.f,0.f};
    if (act) {
        uint4 u = *(const uint4*)(hs + (size_t)d * S + c8);
        acc[0] = bf_lo(u.x); acc[1] = bf_hi(u.x);
        acc[2] = bf_lo(u.y); acc[3] = bf_hi(u.y);
        acc[4] = bf_lo(u.z); acc[5] = bf_hi(u.z);
        acc[6] = bf_lo(u.w); acc[7] = bf_hi(u.w);
    }

    for (int t = beg; t < end; t += 8) {
        int eidx = (t + gl < end) ? csr[t + gl] : 0;
        int m = min(end - t, 8);
        for (int q = 0; q < m; ++q) {
            int s = __shfl(eidx, (sub << 3) + q);
            if (act) {
                uint4 u = *(const uint4*)(hs + (size_t)s * S + c8);
                acc[0] += bf_lo(u.x); acc[1] += bf_hi(u.x);
                acc[2] += bf_lo(u.y); acc[3] += bf_hi(u.y);
                acc[4] += bf_lo(u.z); acc[5] += bf_hi(u.z);
                acc[6] += bf_lo(u.w); acc[7] += bf_hi(u.w);
            }
        }
    }

    float val[8];
    float mx = -1e30f;
    if (act) {
        float dd = dis[d];
#pragma unroll
        for (int q = 0; q < 8; ++q) {
            val[q] = acc[q] * dd + b3[c8 + q];
            mx = fmaxf(mx, val[q]);
        }
    }
#pragma unroll
    for (int off = 4; off > 0; off >>= 1) mx = fmaxf(mx, __shfl_xor(mx, off));
    float es = 0.f;
    if (act) {
#pragma unroll
        for (int q = 0; q < 8; ++q) es += __expf(val[q] - mx);
    }
#pragma unroll
    for (int off = 4; off > 0; off >>= 1) es += __shfl_xor(es, off);
    float lse = mx + __logf(es);
    if (act) {
        float4 o0 = make_float4(val[0]-lse, val[1]-lse, val[2]-lse, val[3]-lse);
        float4 o1 = make_float4(val[4]-lse, val[5]-lse, val[6]-lse, val[7]-lse);
        *(float4*)(out + (size_t)d * 40 + c8)     = o0;
        *(float4*)(out + (size_t)d * 40 + c8 + 4) = o1;
    }
}

// ---------------- launch ----------------
static inline size_t align_up(size_t v, size_t a) { return (v + a - 1) & ~(a - 1); }

extern "C" void kernel_launch(void* const* d_in, const int* in_sizes, int n_in,
                              void* d_out, int out_size, void* d_ws, size_t ws_size,
                              hipStream_t stream) {
    const float* x  = (const float*)d_in[0];
    const int*   ei = (const int*)d_in[1];
    const float* W1 = (const float*)d_in[2];
    const float* b1 = (const float*)d_in[3];
    const float* W2 = (const float*)d_in[4];
    const float* b2 = (const float*)d_in[5];
    const float* W3 = (const float*)d_in[6];
    const float* b3 = (const float*)d_in[7];
    float* out = (float*)d_out;

    const int n = in_sizes[0] / 128;
    const int e = in_sizes[1] / 2;
    const int* src = ei;
    const int* dst = ei + e;

    // workspace: dis[n] | rowptr[n+1] | bcnt[1k] | bbase[1k+1] | pcur[1k] |
    //            csr[e] | hsb (n*64 u16) | aggb (n*64 u16)
    // pairs u32[e] aliases hsb (consumed in sort2 before gemm1 writes hsb).
    char* base = (char*)d_ws;
    size_t off = 0;
    float* dis = (float*)(base + off);    off = align_up(off + (size_t)n * 4, 256);
    int* rowptr = (int*)(base + off);     off = align_up(off + (size_t)(n + 1) * 4, 256);
    int* bcnt = (int*)(base + off);       off = align_up(off + 1024 * 4, 256);
    int* bbase = (int*)(base + off);      off = align_up(off + 1025 * 4, 256);
    int* pcur = (int*)(base + off);       off = align_up(off + 1024 * 4, 256);
    int* csr = (int*)(base + off);        off = align_up(off + (size_t)e * 4, 256);
    u16* hsb = (u16*)(base + off);        off = align_up(off + (size_t)n * 64 * 2, 256);
    u16* aggb = (u16*)(base + off);       off = align_up(off + (size_t)n * 64 * 2, 256);
    u32* pairs = (u32*)hsb;

    const int gb_rows = (n + 63) / 64;
    const int nbuck   = (n + BSIZE - 1) >> BSHIFT;
    const int gb_s1   = (e + PASS1_CHUNK - 1) / PASS1_CHUNK;
    const int gb_agg  = (n + 31) / 32;          // 32 rows per block (8/wave)

    // CSR build
    bzero_kernel<<<1, THREADS, 0, stream>>>(bcnt, nbuck);
    bhist_kernel<<<gb_s1, THREADS, 0, stream>>>(dst, bcnt, e, nbuck);
    bscan_kernel<<<1, 1024, 0, stream>>>(bcnt, bbase, pcur, rowptr, nbuck, n, e);
    sort1_kernel<<<gb_s1, THREADS, 0, stream>>>(src, dst, pcur, pairs, e, nbuck);
    sort2_kernel<<<nbuck, THREADS, 0, stream>>>(bbase, pairs, rowptr, dis, csr, n);

    // layer 1: x @ W1 -> hsb (bf16); gather-agg -> aggb (bf16)
    gemm_kernel<128, 64, 64, false><<<gb_rows, THREADS, 0, stream>>>(
        x, nullptr, W1, nullptr, dis, hsb, n);
    agg64_kernel<<<gb_agg, THREADS, 0, stream>>>(rowptr, csr, hsb, aggb, n);

    // layer 2: swish(aggb*dis+b1) @ W2 -> hsb; gather-agg -> aggb
    gemm_kernel<64, 64, 64, true><<<gb_rows, THREADS, 0, stream>>>(
        nullptr, aggb, W2, b1, dis, hsb, n);
    agg64_kernel<<<gb_agg, THREADS, 0, stream>>>(rowptr, csr, hsb, aggb, n);

    // layer 3: swish(aggb*dis+b2) @ W3 -> hsb (stride 48); agg + lsm -> out
    gemm_kernel<64, 40, 48, true><<<gb_rows, THREADS, 0, stream>>>(
        nullptr, aggb, W3, b2, dis, hsb, n);
    agg40_lsm_kernel<<<gb_agg, THREADS, 0, stream>>>(rowptr, csr, hsb, dis, b3, out, n);
}

// Round 8
// 226.337 us; speedup vs baseline: 5.0775x; 1.2760x over previous
//
#include <hip/hip_runtime.h>
#include <math.h>

#define THREADS 256
#define BSHIFT 9              // 512 dsts per bucket
#define BSIZE (1 << BSHIFT)
#define PASS1_CHUNK 4096
#define SRC_BITS 17           // n < 131072

typedef unsigned int u32;
typedef unsigned short u16;
typedef __attribute__((ext_vector_type(8))) short short8v;   // 8 bf16 (4 VGPR)
typedef __attribute__((ext_vector_type(4))) float float4v;   // MFMA acc

__device__ __forceinline__ u16 f2bf(float f) {      // RNE fp32 -> bf16
    u32 u = __float_as_uint(f);
    u = (u + 0x7fffu + ((u >> 16) & 1u)) >> 16;
    return (u16)u;
}
__device__ __forceinline__ float bf_lo(u32 u) { return __uint_as_float(u << 16); }
__device__ __forceinline__ float bf_hi(u32 u) { return __uint_as_float(u & 0xffff0000u); }
__device__ __forceinline__ float bf2f(u16 b) { return __uint_as_float(((u32)b) << 16); }

// ---------------- bucket histogram ----------------

__global__ __launch_bounds__(THREADS) void bzero_kernel(int* __restrict__ bcnt, int nbuck) {
    int i = threadIdx.x;
    if (i < nbuck) bcnt[i] = 0;
}

__global__ __launch_bounds__(THREADS) void bhist_kernel(const int* __restrict__ dst,
                                                        int* __restrict__ bcnt, int e, int nbuck) {
    __shared__ int hist[BSIZE];
    const int tid = threadIdx.x;
    const int c0  = blockIdx.x * PASS1_CHUNK;
    for (int i = tid; i < nbuck; i += THREADS) hist[i] = 0;
    __syncthreads();
    for (int i = tid; i < PASS1_CHUNK; i += THREADS) {
        int idx = c0 + i;
        if (idx < e) atomicAdd(&hist[dst[idx] >> BSHIFT], 1);
    }
    __syncthreads();
    for (int b = tid; b < nbuck; b += THREADS) {
        int h = hist[b];
        if (h) atomicAdd(&bcnt[b], h);
    }
}

// single block: exclusive scan of bucket counts -> bbase, pcur; rowptr[n]=e
__global__ __launch_bounds__(1024) void bscan_kernel(const int* __restrict__ bcnt,
                                                     int* __restrict__ bbase,
                                                     int* __restrict__ pcur,
                                                     int* __restrict__ rowptr,
                                                     int nbuck, int n, int e) {
    __shared__ int s[1024];
    int v = (threadIdx.x < nbuck) ? bcnt[threadIdx.x] : 0;
    s[threadIdx.x] = v;
    __syncthreads();
    for (int off = 1; off < 1024; off <<= 1) {
        int t = (threadIdx.x >= off) ? s[threadIdx.x - off] : 0;
        __syncthreads();
        s[threadIdx.x] += t;
        __syncthreads();
    }
    if (threadIdx.x < nbuck) {
        int ex = s[threadIdx.x] - v;
        bbase[threadIdx.x] = ex;
        pcur[threadIdx.x]  = ex;
    }
    if (threadIdx.x == 0) { bbase[nbuck] = e; rowptr[n] = e; }
}

// ---------------- sort pass 1: bin packed (ld<<17|src) into bucket regions ----

__global__ __launch_bounds__(THREADS) void sort1_kernel(
    const int* __restrict__ src, const int* __restrict__ dst,
    int* __restrict__ pcur, u32* __restrict__ pairs, int e, int nbuck)
{
    __shared__ int hist[BSIZE], hist2[BSIZE], base_s[BSIZE];
    const int tid = threadIdx.x;
    const int c0  = blockIdx.x * PASS1_CHUNK;
    for (int i = tid; i < nbuck; i += THREADS) { hist[i] = 0; hist2[i] = 0; }
    __syncthreads();
    for (int i = tid; i < PASS1_CHUNK; i += THREADS) {
        int idx = c0 + i;
        if (idx < e) atomicAdd(&hist[dst[idx] >> BSHIFT], 1);
    }
    __syncthreads();
    for (int b = tid; b < nbuck; b += THREADS) {
        int h = hist[b];
        base_s[b] = h ? atomicAdd(&pcur[b], h) : 0;
    }
    __syncthreads();
    for (int i = tid; i < PASS1_CHUNK; i += THREADS) {
        int idx = c0 + i;
        if (idx < e) {
            int d = dst[idx];
            int b = d >> BSHIFT;
            int off = atomicAdd(&hist2[b], 1);
            pairs[base_s[b] + off] = ((u32)(d & (BSIZE - 1)) << SRC_BITS) | (u32)src[idx];
        }
    }
}

// ---------------- sort pass 2: degree count + rowptr + dis + csr scatter ------

__global__ __launch_bounds__(THREADS) void sort2_kernel(
    const int* __restrict__ bbase, const u32* __restrict__ pairs,
    int* __restrict__ rowptr, float* __restrict__ dis,
    int* __restrict__ csr, int n)
{
    __shared__ int cnt[BSIZE];
    __shared__ int cur[BSIZE];
    __shared__ int s2[THREADS];

    const int b  = blockIdx.x;
    const int d0 = b << BSHIFT;
    const int nd = min(BSIZE, n - d0);
    const int p0 = bbase[b], p1 = bbase[b + 1];
    const int tid = threadIdx.x;

    for (int i = tid; i < BSIZE; i += THREADS) cnt[i] = 0;
    __syncthreads();

    for (int j = p0 + tid; j < p1; j += THREADS)
        atomicAdd(&cnt[pairs[j] >> SRC_BITS], 1);
    __syncthreads();

    int c0v = cnt[2 * tid], c1v = cnt[2 * tid + 1];
    int psum = c0v + c1v;
    s2[tid] = psum;
    __syncthreads();
    for (int off = 1; off < THREADS; off <<= 1) {
        int t = (tid >= off) ? s2[tid - off] : 0;
        __syncthreads();
        s2[tid] += t;
        __syncthreads();
    }
    int ex = s2[tid] - psum;
    cur[2 * tid]     = p0 + ex;
    cur[2 * tid + 1] = p0 + ex + c0v;
    __syncthreads();

    for (int i = tid; i < nd; i += THREADS) {
        rowptr[d0 + i] = cur[i];
        dis[d0 + i] = rsqrtf((float)(cnt[i] + 1));   // +1 self-loop
    }
    __syncthreads();

    for (int j = p0 + tid; j < p1; j += THREADS) {
        u32 pr = pairs[j];
        int pos = atomicAdd(&cur[pr >> SRC_BITS], 1);
        csr[pos] = (int)(pr & ((1u << SRC_BITS) - 1));
    }
}

// ---------------- MFMA GEMM ----------------
// Per row r:  xrow = PRE ? swish(Xb[r]*dis[r] + bin) : bf16(Xf[r])
//             hs[r] = bf16( (xrow @ W) * dis[r] )
// 4 waves/block, 16-row stripe per wave. A-frags direct from global; W staged
// once into LDS as B^T bf16 [col][K] with stride KTOT+8 (16B-aligned,
// uniform bank-quad spread for ds_read_b128).
// Fragment layouts (v_mfma_f32_16x16x32_bf16):
//   A: row = l&15,  k  = (l>>4)*8 + i   (8 contiguous bf16 along K)
//   B: col = l&15,  k  = (l>>4)*8 + i   (read from B^T rows)
//   D: col = l&15, row = (l>>4)*4 + j   (m89-verified)
template <int KTOT, int OUT, int SOUT, bool PRE>
__global__ __launch_bounds__(THREADS) void mfma_gemm_kernel(
    const float* __restrict__ Xf, const u16* __restrict__ Xb,
    const float* __restrict__ W, const float* __restrict__ bin,
    const float* __restrict__ dis, u16* __restrict__ hs, int n)
{
    constexpr int NCG = (OUT + 15) / 16;      // col-frags (4,4,3)
    constexpr int CC  = NCG * 16;             // staged cols (64,64,48)
    constexpr int NKK = KTOT / 32;            // k-steps (4 or 2)
    constexpr int WS  = KTOT + 8;             // WT row stride in elems

    __shared__ u16 WT[CC][WS];                // B^T bf16

    const int tid = threadIdx.x;

    // stage W (fp32 [KTOT][OUT]) -> WT bf16 [c][k], zero-pad c >= OUT
    for (int idx = tid; idx < KTOT * CC; idx += THREADS) {
        int k = idx / CC;
        int c = idx - k * CC;
        float v = (c < OUT) ? W[k * OUT + c] : 0.f;
        WT[c][k] = f2bf(v);
    }
    __syncthreads();

    const int lane  = tid & 63;
    const int rlane = lane & 15;              // A row / D col
    const int kgrp  = lane >> 4;              // k-group 0..3
    const int rbase = blockIdx.x * 64 + (tid >> 6) * 16;

    const int arow = min(rbase + rlane, n - 1);   // clamped A row

    float4v acc[NCG];
#pragma unroll
    for (int g = 0; g < NCG; ++g) acc[g] = (float4v)(0.f);

    float dd_a = PRE ? dis[arow] : 0.f;

#pragma unroll
    for (int kk = 0; kk < NKK; ++kk) {
        const int kb = kk * 32 + kgrp * 8;
        short8v a;
        if (PRE) {
            uint4 u = *(const uint4*)(Xb + (size_t)arow * KTOT + kb);
            u32 w[4] = {u.x, u.y, u.z, u.w};
#pragma unroll
            for (int q = 0; q < 4; ++q) {
                float h0 = bf_lo(w[q]) * dd_a + bin[kb + 2 * q];
                float h1 = bf_hi(w[q]) * dd_a + bin[kb + 2 * q + 1];
                a[2 * q]     = (short)f2bf(h0 / (1.f + __expf(-h0)));
                a[2 * q + 1] = (short)f2bf(h1 / (1.f + __expf(-h1)));
            }
        } else {
            float4 f0 = *(const float4*)(Xf + (size_t)arow * KTOT + kb);
            float4 f1 = *(const float4*)(Xf + (size_t)arow * KTOT + kb + 4);
            a[0] = (short)f2bf(f0.x); a[1] = (short)f2bf(f0.y);
            a[2] = (short)f2bf(f0.z); a[3] = (short)f2bf(f0.w);
            a[4] = (short)f2bf(f1.x); a[5] = (short)f2bf(f1.y);
            a[6] = (short)f2bf(f1.z); a[7] = (short)f2bf(f1.w);
        }
#pragma unroll
        for (int g = 0; g < NCG; ++g) {
            short8v b = *(const short8v*)&WT[g * 16 + rlane][kb];
            acc[g] = __builtin_amdgcn_mfma_f32_16x16x32_bf16(a, b, acc[g], 0, 0, 0);
        }
    }

    // epilogue: D[row=(l>>4)*4+j][col=g*16+rlane] -> hs * dis[row]
#pragma unroll
    for (int j = 0; j < 4; ++j) {
        int row = rbase + kgrp * 4 + j;
        if (row < n) {
            float dd = dis[row];
#pragma unroll
            for (int g = 0; g < NCG; ++g) {
                int col = g * 16 + rlane;
                if (OUT == CC || col < OUT)
                    hs[(size_t)row * SOUT + col] = f2bf(acc[g][j] * dd);
            }
        }
    }
}

// ---------------- CSR gather-aggregate: one 8-lane subgroup per dst row -------
// agg[d] = bf16( hs[d] + sum_{s in in-edges(d)} hs[s] );  rows are 64 bf16.
__global__ __launch_bounds__(THREADS) void agg64_kernel(
    const int* __restrict__ rowptr, const int* __restrict__ csr,
    const u16* __restrict__ hs, u16* __restrict__ agg, int n)
{
    const int lane = threadIdx.x & 63;
    const int sub  = lane >> 3;                 // subgroup 0..7 (one row each)
    const int gl   = lane & 7;                  // lane in subgroup
    const int d = (blockIdx.x * 4 + (threadIdx.x >> 6)) * 8 + sub;
    if (d >= n) return;
    const int c8 = gl * 8;                      // feature base

    const int beg = rowptr[d], end = rowptr[d + 1];
    float acc[8];
    {
        uint4 u = *(const uint4*)(hs + (size_t)d * 64 + c8);   // self-loop
        acc[0] = bf_lo(u.x); acc[1] = bf_hi(u.x);
        acc[2] = bf_lo(u.y); acc[3] = bf_hi(u.y);
        acc[4] = bf_lo(u.z); acc[5] = bf_hi(u.z);
        acc[6] = bf_lo(u.w); acc[7] = bf_hi(u.w);
    }

    for (int t = beg; t < end; t += 8) {
        int eidx = (t + gl < end) ? csr[t + gl] : 0;   // 8 edges for this row
        int m = min(end - t, 8);
        for (int q = 0; q < m; ++q) {
            int s = __shfl(eidx, (sub << 3) + q);      // intra-subgroup broadcast
            uint4 u = *(const uint4*)(hs + (size_t)s * 64 + c8);
            acc[0] += bf_lo(u.x); acc[1] += bf_hi(u.x);
            acc[2] += bf_lo(u.y); acc[3] += bf_hi(u.y);
            acc[4] += bf_lo(u.z); acc[5] += bf_hi(u.z);
            acc[6] += bf_lo(u.w); acc[7] += bf_hi(u.w);
        }
    }

    uint4 o;
    o.x = (u32)f2bf(acc[0]) | ((u32)f2bf(acc[1]) << 16);
    o.y = (u32)f2bf(acc[2]) | ((u32)f2bf(acc[3]) << 16);
    o.z = (u32)f2bf(acc[4]) | ((u32)f2bf(acc[5]) << 16);
    o.w = (u32)f2bf(acc[6]) | ((u32)f2bf(acc[7]) << 16);
    *(uint4*)(agg + (size_t)d * 64 + c8) = o;
}

// ---------------- layer-3 aggregate + bias + log_softmax ----------------------
// hs3 rows: 40 bf16 at stride 48 (96B). One 8-lane subgroup per row; lanes
// gl<5 carry features, all 8 lanes fetch csr edges.
__global__ __launch_bounds__(THREADS) void agg40_lsm_kernel(
    const int* __restrict__ rowptr, const int* __restrict__ csr,
    const u16* __restrict__ hs, const float* __restrict__ dis,
    const float* __restrict__ b3, float* __restrict__ out, int n)
{
    constexpr int S = 48;
    const int lane = threadIdx.x & 63;
    const int sub  = lane >> 3;
    const int gl   = lane & 7;
    const int d = (blockIdx.x * 4 + (threadIdx.x >> 6)) * 8 + sub;
    if (d >= n) return;
    const bool act = (gl < 5);
    const int c8 = gl * 8;

    const int beg = rowptr[d], end = rowptr[d + 1];
    float acc[8] = {0.f,0.f,0.f,0.f,0.f,0.f,0.f,0.f};
    if (act) {
        uint4 u = *(const uint4*)(hs + (size_t)d * S + c8);
        acc[0] = bf_lo(u.x); acc[1] = bf_hi(u.x);
        acc[2] = bf_lo(u.y); acc[3] = bf_hi(u.y);
        acc[4] = bf_lo(u.z); acc[5] = bf_hi(u.z);
        acc[6] = bf_lo(u.w); acc[7] = bf_hi(u.w);
    }

    for (int t = beg; t < end; t += 8) {
        int eidx = (t + gl < end) ? csr[t + gl] : 0;
        int m = min(end - t, 8);
        for (int q = 0; q < m; ++q) {
            int s = __shfl(eidx, (sub << 3) + q);
            if (act) {
                uint4 u = *(const uint4*)(hs + (size_t)s * S + c8);
                acc[0] += bf_lo(u.x); acc[1] += bf_hi(u.x);
                acc[2] += bf_lo(u.y); acc[3] += bf_hi(u.y);
                acc[4] += bf_lo(u.z); acc[5] += bf_hi(u.z);
                acc[6] += bf_lo(u.w); acc[7] += bf_hi(u.w);
            }
        }
    }

    float val[8];
    float mx = -1e30f;
    if (act) {
        float dd = dis[d];
#pragma unroll
        for (int q = 0; q < 8; ++q) {
            val[q] = acc[q] * dd + b3[c8 + q];
            mx = fmaxf(mx, val[q]);
        }
    }
#pragma unroll
    for (int off = 4; off > 0; off >>= 1) mx = fmaxf(mx, __shfl_xor(mx, off));
    float es = 0.f;
    if (act) {
#pragma unroll
        for (int q = 0; q < 8; ++q) es += __expf(val[q] - mx);
    }
#pragma unroll
    for (int off = 4; off > 0; off >>= 1) es += __shfl_xor(es, off);
    float lse = mx + __logf(es);
    if (act) {
        float4 o0 = make_float4(val[0]-lse, val[1]-lse, val[2]-lse, val[3]-lse);
        float4 o1 = make_float4(val[4]-lse, val[5]-lse, val[6]-lse, val[7]-lse);
        *(float4*)(out + (size_t)d * 40 + c8)     = o0;
        *(float4*)(out + (size_t)d * 40 + c8 + 4) = o1;
    }
}

// ---------------- launch ----------------
static inline size_t align_up(size_t v, size_t a) { return (v + a - 1) & ~(a - 1); }

extern "C" void kernel_launch(void* const* d_in, const int* in_sizes, int n_in,
                              void* d_out, int out_size, void* d_ws, size_t ws_size,
                              hipStream_t stream) {
    const float* x  = (const float*)d_in[0];
    const int*   ei = (const int*)d_in[1];
    const float* W1 = (const float*)d_in[2];
    const float* b1 = (const float*)d_in[3];
    const float* W2 = (const float*)d_in[4];
    const float* b2 = (const float*)d_in[5];
    const float* W3 = (const float*)d_in[6];
    const float* b3 = (const float*)d_in[7];
    float* out = (float*)d_out;

    const int n = in_sizes[0] / 128;
    const int e = in_sizes[1] / 2;
    const int* src = ei;
    const int* dst = ei + e;

    // workspace: dis[n] | rowptr[n+1] | bcnt[1k] | bbase[1k+1] | pcur[1k] |
    //            csr[e] | hsb (n*64 u16) | aggb (n*64 u16)
    // pairs u32[e] aliases hsb (consumed in sort2 before gemm1 writes hsb).
    char* base = (char*)d_ws;
    size_t off = 0;
    float* dis = (float*)(base + off);    off = align_up(off + (size_t)n * 4, 256);
    int* rowptr = (int*)(base + off);     off = align_up(off + (size_t)(n + 1) * 4, 256);
    int* bcnt = (int*)(base + off);       off = align_up(off + 1024 * 4, 256);
    int* bbase = (int*)(base + off);      off = align_up(off + 1025 * 4, 256);
    int* pcur = (int*)(base + off);       off = align_up(off + 1024 * 4, 256);
    int* csr = (int*)(base + off);        off = align_up(off + (size_t)e * 4, 256);
    u16* hsb = (u16*)(base + off);        off = align_up(off + (size_t)n * 64 * 2, 256);
    u16* aggb = (u16*)(base + off);       off = align_up(off + (size_t)n * 64 * 2, 256);
    u32* pairs = (u32*)hsb;

    const int gb_rows = (n + 63) / 64;
    const int nbuck   = (n + BSIZE - 1) >> BSHIFT;
    const int gb_s1   = (e + PASS1_CHUNK - 1) / PASS1_CHUNK;
    const int gb_agg  = (n + 31) / 32;          // 32 rows per block (8/wave)

    // CSR build
    bzero_kernel<<<1, THREADS, 0, stream>>>(bcnt, nbuck);
    bhist_kernel<<<gb_s1, THREADS, 0, stream>>>(dst, bcnt, e, nbuck);
    bscan_kernel<<<1, 1024, 0, stream>>>(bcnt, bbase, pcur, rowptr, nbuck, n, e);
    sort1_kernel<<<gb_s1, THREADS, 0, stream>>>(src, dst, pcur, pairs, e, nbuck);
    sort2_kernel<<<nbuck, THREADS, 0, stream>>>(bbase, pairs, rowptr, dis, csr, n);

    // layer 1: x @ W1 -> hsb (bf16); gather-agg -> aggb (bf16)
    mfma_gemm_kernel<128, 64, 64, false><<<gb_rows, THREADS, 0, stream>>>(
        x, nullptr, W1, nullptr, dis, hsb, n);
    agg64_kernel<<<gb_agg, THREADS, 0, stream>>>(rowptr, csr, hsb, aggb, n);

    // layer 2: swish(aggb*dis+b1) @ W2 -> hsb; gather-agg -> aggb
    mfma_gemm_kernel<64, 64, 64, true><<<gb_rows, THREADS, 0, stream>>>(
        nullptr, aggb, W2, b1, dis, hsb, n);
    agg64_kernel<<<gb_agg, THREADS, 0, stream>>>(rowptr, csr, hsb, aggb, n);

    // layer 3: swish(aggb*dis+b2) @ W3 -> hsb (stride 48); agg + lsm -> out
    mfma_gemm_kernel<64, 40, 48, true><<<gb_rows, THREADS, 0, stream>>>(
        nullptr, aggb, W3, b2, dis, hsb, n);
    agg40_lsm_kernel<<<gb_agg, THREADS, 0, stream>>>(rowptr, csr, hsb, dis, b3, out, n);
}

// Round 9
// 212.294 us; speedup vs baseline: 5.4134x; 1.0661x over previous
//
#include <hip/hip_runtime.h>
#include <math.h>

#define THREADS 256
#define BSHIFT 9              // 512 dsts per bucket
#define BSIZE (1 << BSHIFT)
#define PASS1_CHUNK 8192
#define SRC_BITS 17           // n < 131072
#define S2CAP 12288           // sort2 LDS pair-stage capacity (48KB)

typedef unsigned int u32;
typedef unsigned short u16;
typedef __attribute__((ext_vector_type(8))) short short8v;   // 8 bf16 (4 VGPR)
typedef __attribute__((ext_vector_type(4))) float float4v;   // MFMA acc

__device__ __forceinline__ u16 f2bf(float f) {      // RNE fp32 -> bf16
    u32 u = __float_as_uint(f);
    u = (u + 0x7fffu + ((u >> 16) & 1u)) >> 16;
    return (u16)u;
}
__device__ __forceinline__ float bf_lo(u32 u) { return __uint_as_float(u << 16); }
__device__ __forceinline__ float bf_hi(u32 u) { return __uint_as_float(u & 0xffff0000u); }

// ---------------- bucket histogram ----------------

__global__ __launch_bounds__(THREADS) void bzero_kernel(int* __restrict__ bcnt, int nbuck) {
    int i = threadIdx.x;
    if (i < nbuck) bcnt[i] = 0;
}

__global__ __launch_bounds__(THREADS) void bhist_kernel(const int* __restrict__ dst,
                                                        int* __restrict__ bcnt, int e, int nbuck) {
    __shared__ int hist[BSIZE];
    const int tid = threadIdx.x;
    const int c0  = blockIdx.x * PASS1_CHUNK;
    for (int i = tid; i < nbuck; i += THREADS) hist[i] = 0;
    __syncthreads();
    for (int i = tid; i < PASS1_CHUNK; i += THREADS) {
        int idx = c0 + i;
        if (idx < e) atomicAdd(&hist[dst[idx] >> BSHIFT], 1);
    }
    __syncthreads();
    for (int b = tid; b < nbuck; b += THREADS) {
        int h = hist[b];
        if (h) atomicAdd(&bcnt[b], h);
    }
}

// single block: exclusive scan of bucket counts -> bbase, pcur; rowptr[n]=e
__global__ __launch_bounds__(1024) void bscan_kernel(const int* __restrict__ bcnt,
                                                     int* __restrict__ bbase,
                                                     int* __restrict__ pcur,
                                                     int* __restrict__ rowptr,
                                                     int nbuck, int n, int e) {
    __shared__ int s[1024];
    int v = (threadIdx.x < nbuck) ? bcnt[threadIdx.x] : 0;
    s[threadIdx.x] = v;
    __syncthreads();
    for (int off = 1; off < 1024; off <<= 1) {
        int t = (threadIdx.x >= off) ? s[threadIdx.x - off] : 0;
        __syncthreads();
        s[threadIdx.x] += t;
        __syncthreads();
    }
    if (threadIdx.x < nbuck) {
        int ex = s[threadIdx.x] - v;
        bbase[threadIdx.x] = ex;
        pcur[threadIdx.x]  = ex;
    }
    if (threadIdx.x == 0) { bbase[nbuck] = e; rowptr[n] = e; }
}

// ---------------- sort pass 1: bin packed (ld<<17|src) into bucket regions ----

__global__ __launch_bounds__(THREADS) void sort1_kernel(
    const int* __restrict__ src, const int* __restrict__ dst,
    int* __restrict__ pcur, u32* __restrict__ pairs, int e, int nbuck)
{
    __shared__ int hist[BSIZE], hist2[BSIZE], base_s[BSIZE];
    const int tid = threadIdx.x;
    const int c0  = blockIdx.x * PASS1_CHUNK;
    for (int i = tid; i < nbuck; i += THREADS) { hist[i] = 0; hist2[i] = 0; }
    __syncthreads();
    for (int i = tid; i < PASS1_CHUNK; i += THREADS) {
        int idx = c0 + i;
        if (idx < e) atomicAdd(&hist[dst[idx] >> BSHIFT], 1);
    }
    __syncthreads();
    for (int b = tid; b < nbuck; b += THREADS) {
        int h = hist[b];
        base_s[b] = h ? atomicAdd(&pcur[b], h) : 0;
    }
    __syncthreads();
    for (int i = tid; i < PASS1_CHUNK; i += THREADS) {
        int idx = c0 + i;
        if (idx < e) {
            int d = dst[idx];
            int b = d >> BSHIFT;
            int off = atomicAdd(&hist2[b], 1);
            pairs[base_s[b] + off] = ((u32)(d & (BSIZE - 1)) << SRC_BITS) | (u32)src[idx];
        }
    }
}

// ---------------- sort pass 2: degree count + rowptr + dis + csr scatter ------
// One block per bucket (grid ~196 < #CUs, so big LDS is free). Pairs staged
// into LDS during the count pass; scatter pass replays from LDS.

__global__ __launch_bounds__(THREADS) void sort2_kernel(
    const int* __restrict__ bbase, const u32* __restrict__ pairs,
    int* __restrict__ rowptr, float* __restrict__ dis,
    int* __restrict__ csr, int n)
{
    __shared__ int cnt[BSIZE];
    __shared__ int cur[BSIZE];
    __shared__ int s2[THREADS];
    __shared__ u32 pst[S2CAP];

    const int b  = blockIdx.x;
    const int d0 = b << BSHIFT;
    const int nd = min(BSIZE, n - d0);
    const int p0 = bbase[b], p1 = bbase[b + 1];
    const int sz = p1 - p0;
    const int tid = threadIdx.x;

    for (int i = tid; i < BSIZE; i += THREADS) cnt[i] = 0;
    __syncthreads();

    // pass A: count + stage
    for (int j = tid; j < sz; j += THREADS) {
        u32 pr = pairs[p0 + j];
        if (j < S2CAP) pst[j] = pr;
        atomicAdd(&cnt[pr >> SRC_BITS], 1);
    }
    __syncthreads();

    int c0v = cnt[2 * tid], c1v = cnt[2 * tid + 1];
    int psum = c0v + c1v;
    s2[tid] = psum;
    __syncthreads();
    for (int off = 1; off < THREADS; off <<= 1) {
        int t = (tid >= off) ? s2[tid - off] : 0;
        __syncthreads();
        s2[tid] += t;
        __syncthreads();
    }
    int ex = s2[tid] - psum;
    cur[2 * tid]     = p0 + ex;
    cur[2 * tid + 1] = p0 + ex + c0v;
    __syncthreads();

    for (int i = tid; i < nd; i += THREADS) {
        rowptr[d0 + i] = cur[i];
        dis[d0 + i] = rsqrtf((float)(cnt[i] + 1));   // +1 self-loop
    }
    __syncthreads();

    // pass B: scatter (LDS-staged pairs, global fallback past cap)
    for (int j = tid; j < sz; j += THREADS) {
        u32 pr = (j < S2CAP) ? pst[j] : pairs[p0 + j];
        int pos = atomicAdd(&cur[pr >> SRC_BITS], 1);
        csr[pos] = (int)(pr & ((1u << SRC_BITS) - 1));
    }
}

// ---------------- MFMA GEMM ----------------
// Per row r:  xrow = PRE ? swish(Xb[r]*dis[r] + bin) : bf16(Xf[r])
//             hs[r] = bf16( (xrow @ W) * dis[r] )
// 4 waves/block, 16-row stripe per wave. A-frags direct from global; W staged
// once into LDS as B^T bf16 [col][K] stride KTOT+8.
template <int KTOT, int OUT, int SOUT, bool PRE>
__global__ __launch_bounds__(THREADS) void mfma_gemm_kernel(
    const float* __restrict__ Xf, const u16* __restrict__ Xb,
    const float* __restrict__ W, const float* __restrict__ bin,
    const float* __restrict__ dis, u16* __restrict__ hs, int n)
{
    constexpr int NCG = (OUT + 15) / 16;      // col-frags (4,4,3)
    constexpr int CC  = NCG * 16;             // staged cols (64,64,48)
    constexpr int NKK = KTOT / 32;            // k-steps (4 or 2)
    constexpr int WS  = KTOT + 8;             // WT row stride in elems

    __shared__ u16 WT[CC][WS];                // B^T bf16

    const int tid = threadIdx.x;

    for (int idx = tid; idx < KTOT * CC; idx += THREADS) {
        int k = idx / CC;
        int c = idx - k * CC;
        float v = (c < OUT) ? W[k * OUT + c] : 0.f;
        WT[c][k] = f2bf(v);
    }
    __syncthreads();

    const int lane  = tid & 63;
    const int rlane = lane & 15;              // A row / D col
    const int kgrp  = lane >> 4;              // k-group 0..3
    const int rbase = blockIdx.x * 64 + (tid >> 6) * 16;

    const int arow = min(rbase + rlane, n - 1);   // clamped A row

    float4v acc[NCG];
#pragma unroll
    for (int g = 0; g < NCG; ++g) acc[g] = (float4v)(0.f);

    float dd_a = PRE ? dis[arow] : 0.f;

#pragma unroll
    for (int kk = 0; kk < NKK; ++kk) {
        const int kb = kk * 32 + kgrp * 8;
        short8v a;
        if (PRE) {
            uint4 u = *(const uint4*)(Xb + (size_t)arow * KTOT + kb);
            u32 w[4] = {u.x, u.y, u.z, u.w};
#pragma unroll
            for (int q = 0; q < 4; ++q) {
                float h0 = bf_lo(w[q]) * dd_a + bin[kb + 2 * q];
                float h1 = bf_hi(w[q]) * dd_a + bin[kb + 2 * q + 1];
                a[2 * q]     = (short)f2bf(h0 / (1.f + __expf(-h0)));
                a[2 * q + 1] = (short)f2bf(h1 / (1.f + __expf(-h1)));
            }
        } else {
            float4 f0 = *(const float4*)(Xf + (size_t)arow * KTOT + kb);
            float4 f1 = *(const float4*)(Xf + (size_t)arow * KTOT + kb + 4);
            a[0] = (short)f2bf(f0.x); a[1] = (short)f2bf(f0.y);
            a[2] = (short)f2bf(f0.z); a[3] = (short)f2bf(f0.w);
            a[4] = (short)f2bf(f1.x); a[5] = (short)f2bf(f1.y);
            a[6] = (short)f2bf(f1.z); a[7] = (short)f2bf(f1.w);
        }
#pragma unroll
        for (int g = 0; g < NCG; ++g) {
            short8v b = *(const short8v*)&WT[g * 16 + rlane][kb];
            acc[g] = __builtin_amdgcn_mfma_f32_16x16x32_bf16(a, b, acc[g], 0, 0, 0);
        }
    }

#pragma unroll
    for (int j = 0; j < 4; ++j) {
        int row = rbase + kgrp * 4 + j;
        if (row < n) {
            float dd = dis[row];
#pragma unroll
            for (int g = 0; g < NCG; ++g) {
                int col = g * 16 + rlane;
                if (OUT == CC || col < OUT)
                    hs[(size_t)row * SOUT + col] = f2bf(acc[g][j] * dd);
            }
        }
    }
}

// ---------------- CSR gather-aggregate: one 8-lane subgroup per dst row -------
// agg[d] = bf16( hs[d] + sum_{s in in-edges(d)} hs[s] );  rows are 64 bf16.
// Software-pipelined: all 8 gathers of a batch issued into statically-indexed
// regs before accumulation; next csr word prefetched under the gathers.
__global__ __launch_bounds__(THREADS) void agg64_kernel(
    const int* __restrict__ rowptr, const int* __restrict__ csr,
    const u16* __restrict__ hs, u16* __restrict__ agg, int n)
{
    const int lane = threadIdx.x & 63;
    const int sub  = lane >> 3;                 // subgroup 0..7 (one row each)
    const int gl   = lane & 7;                  // lane in subgroup
    const int d = (blockIdx.x * 4 + (threadIdx.x >> 6)) * 8 + sub;
    if (d >= n) return;
    const int c8 = gl * 8;                      // feature base

    const int beg = rowptr[d], end = rowptr[d + 1];
    float acc[8];
    {
        uint4 u = *(const uint4*)(hs + (size_t)d * 64 + c8);   // self-loop
        acc[0] = bf_lo(u.x); acc[1] = bf_hi(u.x);
        acc[2] = bf_lo(u.y); acc[3] = bf_hi(u.y);
        acc[4] = bf_lo(u.z); acc[5] = bf_hi(u.z);
        acc[6] = bf_lo(u.w); acc[7] = bf_hi(u.w);
    }

    int eidx = (beg + gl < end) ? csr[beg + gl] : 0;
    for (int t = beg; t < end; t += 8) {
        const int m = end - t;                  // >=1 (per-subgroup)
        uint4 ub[8];
#pragma unroll
        for (int q = 0; q < 8; ++q) {           // issue gathers (predicated)
            int s = __shfl(eidx, (sub << 3) + q);
            if (q < m) ub[q] = *(const uint4*)(hs + (size_t)s * 64 + c8);
        }
        int eidx_n = (t + 8 + gl < end) ? csr[t + 8 + gl] : 0;  // prefetch
#pragma unroll
        for (int q = 0; q < 8; ++q) {
            if (q < m) {
                acc[0] += bf_lo(ub[q].x); acc[1] += bf_hi(ub[q].x);
                acc[2] += bf_lo(ub[q].y); acc[3] += bf_hi(ub[q].y);
                acc[4] += bf_lo(ub[q].z); acc[5] += bf_hi(ub[q].z);
                acc[6] += bf_lo(ub[q].w); acc[7] += bf_hi(ub[q].w);
            }
        }
        eidx = eidx_n;
    }

    uint4 o;
    o.x = (u32)f2bf(acc[0]) | ((u32)f2bf(acc[1]) << 16);
    o.y = (u32)f2bf(acc[2]) | ((u32)f2bf(acc[3]) << 16);
    o.z = (u32)f2bf(acc[4]) | ((u32)f2bf(acc[5]) << 16);
    o.w = (u32)f2bf(acc[6]) | ((u32)f2bf(acc[7]) << 16);
    *(uint4*)(agg + (size_t)d * 64 + c8) = o;
}

// ---------------- layer-3 aggregate + bias + log_softmax ----------------------
// hs3 rows: 40 bf16 at stride 48 (96B). One 8-lane subgroup per row; lanes
// gl<5 carry features; same software-pipelined batch as agg64.
__global__ __launch_bounds__(THREADS) void agg40_lsm_kernel(
    const int* __restrict__ rowptr, const int* __restrict__ csr,
    const u16* __restrict__ hs, const float* __restrict__ dis,
    const float* __restrict__ b3, float* __restrict__ out, int n)
{
    constexpr int S = 48;
    const int lane = threadIdx.x & 63;
    const int sub  = lane >> 3;
    const int gl   = lane & 7;
    const int d = (blockIdx.x * 4 + (threadIdx.x >> 6)) * 8 + sub;
    if (d >= n) return;
    const bool act = (gl < 5);
    const int c8 = gl * 8;

    const int beg = rowptr[d], end = rowptr[d + 1];
    float acc[8] = {0.f,0.f,0.f,0.f,0.f,0.f,0.f,0.f};
    if (act) {
        uint4 u = *(const uint4*)(hs + (size_t)d * S + c8);
        acc[0] = bf_lo(u.x); acc[1] = bf_hi(u.x);
        acc[2] = bf_lo(u.y); acc[3] = bf_hi(u.y);
        acc[4] = bf_lo(u.z); acc[5] = bf_hi(u.z);
        acc[6] = bf_lo(u.w); acc[7] = bf_hi(u.w);
    }

    int eidx = (beg + gl < end) ? csr[beg + gl] : 0;
    for (int t = beg; t < end; t += 8) {
        const int m = end - t;
        uint4 ub[8];
#pragma unroll
        for (int q = 0; q < 8; ++q) {
            int s = __shfl(eidx, (sub << 3) + q);
            if (q < m && act) ub[q] = *(const uint4*)(hs + (size_t)s * S + c8);
        }
        int eidx_n = (t + 8 + gl < end) ? csr[t + 8 + gl] : 0;
#pragma unroll
        for (int q = 0; q < 8; ++q) {
            if (q < m && act) {
                acc[0] += bf_lo(ub[q].x); acc[1] += bf_hi(ub[q].x);
                acc[2] += bf_lo(ub[q].y); acc[3] += bf_hi(ub[q].y);
                acc[4] += bf_lo(ub[q].z); acc[5] += bf_hi(ub[q].z);
                acc[6] += bf_lo(ub[q].w); acc[7] += bf_hi(ub[q].w);
            }
        }
        eidx = eidx_n;
    }

    float val[8];
    float mx = -1e30f;
    if (act) {
        float dd = dis[d];
#pragma unroll
        for (int q = 0; q < 8; ++q) {
            val[q] = acc[q] * dd + b3[c8 + q];
            mx = fmaxf(mx, val[q]);
        }
    }
#pragma unroll
    for (int off = 4; off > 0; off >>= 1) mx = fmaxf(mx, __shfl_xor(mx, off));
    float es = 0.f;
    if (act) {
#pragma unroll
        for (int q = 0; q < 8; ++q) es += __expf(val[q] - mx);
    }
#pragma unroll
    for (int off = 4; off > 0; off >>= 1) es += __shfl_xor(es, off);
    float lse = mx + __logf(es);
    if (act) {
        float4 o0 = make_float4(val[0]-lse, val[1]-lse, val[2]-lse, val[3]-lse);
        float4 o1 = make_float4(val[4]-lse, val[5]-lse, val[6]-lse, val[7]-lse);
        *(float4*)(out + (size_t)d * 40 + c8)     = o0;
        *(float4*)(out + (size_t)d * 40 + c8 + 4) = o1;
    }
}

// ---------------- launch ----------------
static inline size_t align_up(size_t v, size_t a) { return (v + a - 1) & ~(a - 1); }

extern "C" void kernel_launch(void* const* d_in, const int* in_sizes, int n_in,
                              void* d_out, int out_size, void* d_ws, size_t ws_size,
                              hipStream_t stream) {
    const float* x  = (const float*)d_in[0];
    const int*   ei = (const int*)d_in[1];
    const float* W1 = (const float*)d_in[2];
    const float* b1 = (const float*)d_in[3];
    const float* W2 = (const float*)d_in[4];
    const float* b2 = (const float*)d_in[5];
    const float* W3 = (const float*)d_in[6];
    const float* b3 = (const float*)d_in[7];
    float* out = (float*)d_out;

    const int n = in_sizes[0] / 128;
    const int e = in_sizes[1] / 2;
    const int* src = ei;
    const int* dst = ei + e;

    // workspace: dis[n] | rowptr[n+1] | bcnt[1k] | bbase[1k+1] | pcur[1k] |
    //            csr[e] | hsb (n*64 u16) | aggb (n*64 u16)
    // pairs u32[e] aliases hsb (consumed in sort2 before gemm1 writes hsb).
    char* base = (char*)d_ws;
    size_t off = 0;
    float* dis = (float*)(base + off);    off = align_up(off + (size_t)n * 4, 256);
    int* rowptr = (int*)(base + off);     off = align_up(off + (size_t)(n + 1) * 4, 256);
    int* bcnt = (int*)(base + off);       off = align_up(off + 1024 * 4, 256);
    int* bbase = (int*)(base + off);      off = align_up(off + 1025 * 4, 256);
    int* pcur = (int*)(base + off);       off = align_up(off + 1024 * 4, 256);
    int* csr = (int*)(base + off);        off = align_up(off + (size_t)e * 4, 256);
    u16* hsb = (u16*)(base + off);        off = align_up(off + (size_t)n * 64 * 2, 256);
    u16* aggb = (u16*)(base + off);       off = align_up(off + (size_t)n * 64 * 2, 256);
    u32* pairs = (u32*)hsb;

    const int gb_rows = (n + 63) / 64;
    const int nbuck   = (n + BSIZE - 1) >> BSHIFT;
    const int gb_s1   = (e + PASS1_CHUNK - 1) / PASS1_CHUNK;
    const int gb_agg  = (n + 31) / 32;          // 32 rows per block (8/wave)

    // CSR build
    bzero_kernel<<<1, THREADS, 0, stream>>>(bcnt, nbuck);
    bhist_kernel<<<gb_s1, THREADS, 0, stream>>>(dst, bcnt, e, nbuck);
    bscan_kernel<<<1, 1024, 0, stream>>>(bcnt, bbase, pcur, rowptr, nbuck, n, e);
    sort1_kernel<<<gb_s1, THREADS, 0, stream>>>(src, dst, pcur, pairs, e, nbuck);
    sort2_kernel<<<nbuck, THREADS, 0, stream>>>(bbase, pairs, rowptr, dis, csr, n);

    // layer 1: x @ W1 -> hsb (bf16); gather-agg -> aggb (bf16)
    mfma_gemm_kernel<128, 64, 64, false><<<gb_rows, THREADS, 0, stream>>>(
        x, nullptr, W1, nullptr, dis, hsb, n);
    agg64_kernel<<<gb_agg, THREADS, 0, stream>>>(rowptr, csr, hsb, aggb, n);

    // layer 2: swish(aggb*dis+b1) @ W2 -> hsb; gather-agg -> aggb
    mfma_gemm_kernel<64, 64, 64, true><<<gb_rows, THREADS, 0, stream>>>(
        nullptr, aggb, W2, b1, dis, hsb, n);
    agg64_kernel<<<gb_agg, THREADS, 0, stream>>>(rowptr, csr, hsb, aggb, n);

    // layer 3: swish(aggb*dis+b2) @ W3 -> hsb (stride 48); agg + lsm -> out
    mfma_gemm_kernel<64, 40, 48, true><<<gb_rows, THREADS, 0, stream>>>(
        nullptr, aggb, W3, b2, dis, hsb, n);
    agg40_lsm_kernel<<<gb_agg, THREADS, 0, stream>>>(rowptr, csr, hsb, dis, b3, out, n);
}

// Round 10
// 209.408 us; speedup vs baseline: 5.4880x; 1.0138x over previous
//
#include <hip/hip_runtime.h>
#include <math.h>

#define THREADS 256
#define S1THREADS 512
#define BSHIFT 9              // 512 dsts per bucket
#define BSIZE (1 << BSHIFT)
#define PASS1_CHUNK 2048
#define SRC_BITS 17           // n < 131072
#define S2CAP 12288           // sort2 LDS pair-stage capacity (48KB)

typedef unsigned int u32;
typedef unsigned short u16;
typedef __attribute__((ext_vector_type(8))) short short8v;   // 8 bf16 (4 VGPR)
typedef __attribute__((ext_vector_type(4))) float float4v;   // MFMA acc

__device__ __forceinline__ u16 f2bf(float f) {      // RNE fp32 -> bf16
    u32 u = __float_as_uint(f);
    u = (u + 0x7fffu + ((u >> 16) & 1u)) >> 16;
    return (u16)u;
}
__device__ __forceinline__ float bf_lo(u32 u) { return __uint_as_float(u << 16); }
__device__ __forceinline__ float bf_hi(u32 u) { return __uint_as_float(u & 0xffff0000u); }

// ---------------- bucket histogram ----------------

__global__ __launch_bounds__(THREADS) void bzero_kernel(int* __restrict__ bcnt, int nbuck) {
    int i = threadIdx.x;
    if (i < nbuck) bcnt[i] = 0;
}

__global__ __launch_bounds__(THREADS) void bhist_kernel(const int* __restrict__ dst,
                                                        int* __restrict__ bcnt, int e, int nbuck) {
    __shared__ int hist[BSIZE];
    const int tid = threadIdx.x;
    const int c0  = blockIdx.x * PASS1_CHUNK;
    for (int i = tid; i < nbuck; i += THREADS) hist[i] = 0;
    __syncthreads();
    for (int i = tid; i < PASS1_CHUNK; i += THREADS) {
        int idx = c0 + i;
        if (idx < e) atomicAdd(&hist[dst[idx] >> BSHIFT], 1);
    }
    __syncthreads();
    for (int b = tid; b < nbuck; b += THREADS) {
        int h = hist[b];
        if (h) atomicAdd(&bcnt[b], h);
    }
}

// single block: exclusive scan of bucket counts -> bbase, pcur; rowptr[n]=e
__global__ __launch_bounds__(1024) void bscan_kernel(const int* __restrict__ bcnt,
                                                     int* __restrict__ bbase,
                                                     int* __restrict__ pcur,
                                                     int* __restrict__ rowptr,
                                                     int nbuck, int n, int e) {
    __shared__ int s[1024];
    int v = (threadIdx.x < nbuck) ? bcnt[threadIdx.x] : 0;
    s[threadIdx.x] = v;
    __syncthreads();
    for (int off = 1; off < 1024; off <<= 1) {
        int t = (threadIdx.x >= off) ? s[threadIdx.x - off] : 0;
        __syncthreads();
        s[threadIdx.x] += t;
        __syncthreads();
    }
    if (threadIdx.x < nbuck) {
        int ex = s[threadIdx.x] - v;
        bbase[threadIdx.x] = ex;
        pcur[threadIdx.x]  = ex;
    }
    if (threadIdx.x == 0) { bbase[nbuck] = e; rowptr[n] = e; }
}

// ---------------- sort pass 1: bin packed (ld<<17|src) into bucket regions ----

__global__ __launch_bounds__(S1THREADS) void sort1_kernel(
    const int* __restrict__ src, const int* __restrict__ dst,
    int* __restrict__ pcur, u32* __restrict__ pairs, int e, int nbuck)
{
    __shared__ int hist[BSIZE], hist2[BSIZE], base_s[BSIZE];
    const int tid = threadIdx.x;
    const int c0  = blockIdx.x * PASS1_CHUNK;
    for (int i = tid; i < nbuck; i += S1THREADS) { hist[i] = 0; hist2[i] = 0; }
    __syncthreads();
    for (int i = tid; i < PASS1_CHUNK; i += S1THREADS) {
        int idx = c0 + i;
        if (idx < e) atomicAdd(&hist[dst[idx] >> BSHIFT], 1);
    }
    __syncthreads();
    for (int b = tid; b < nbuck; b += S1THREADS) {
        int h = hist[b];
        base_s[b] = h ? atomicAdd(&pcur[b], h) : 0;
    }
    __syncthreads();
    for (int i = tid; i < PASS1_CHUNK; i += S1THREADS) {
        int idx = c0 + i;
        if (idx < e) {
            int d = dst[idx];
            int b = d >> BSHIFT;
            int off = atomicAdd(&hist2[b], 1);
            pairs[base_s[b] + off] = ((u32)(d & (BSIZE - 1)) << SRC_BITS) | (u32)src[idx];
        }
    }
}

// ---------------- sort pass 2: degree count + rowptr + dis + csr scatter ------
// One block per bucket; 512 threads (2 waves/SIMD on the ~1-block/CU grid).
// Pairs staged into LDS during the count pass; scatter replays from LDS.

__global__ __launch_bounds__(S1THREADS) void sort2_kernel(
    const int* __restrict__ bbase, const u32* __restrict__ pairs,
    int* __restrict__ rowptr, float* __restrict__ dis,
    int* __restrict__ csr, int n)
{
    __shared__ int cnt[BSIZE];
    __shared__ int cur[BSIZE];
    __shared__ int s2[S1THREADS];
    __shared__ u32 pst[S2CAP];

    const int b  = blockIdx.x;
    const int d0 = b << BSHIFT;
    const int nd = min(BSIZE, n - d0);
    const int p0 = bbase[b], p1 = bbase[b + 1];
    const int sz = p1 - p0;
    const int tid = threadIdx.x;

    for (int i = tid; i < BSIZE; i += S1THREADS) cnt[i] = 0;
    __syncthreads();

    // pass A: count + stage
    for (int j = tid; j < sz; j += S1THREADS) {
        u32 pr = pairs[p0 + j];
        if (j < S2CAP) pst[j] = pr;
        atomicAdd(&cnt[pr >> SRC_BITS], 1);
    }
    __syncthreads();

    // exclusive scan of cnt[0..511], one element per thread
    int v = cnt[tid];
    s2[tid] = v;
    __syncthreads();
    for (int off = 1; off < S1THREADS; off <<= 1) {
        int t = (tid >= off) ? s2[tid - off] : 0;
        __syncthreads();
        s2[tid] += t;
        __syncthreads();
    }
    cur[tid] = p0 + s2[tid] - v;
    __syncthreads();

    for (int i = tid; i < nd; i += S1THREADS) {
        rowptr[d0 + i] = cur[i];
        dis[d0 + i] = rsqrtf((float)(cnt[i] + 1));   // +1 self-loop
    }
    __syncthreads();

    // pass B: scatter (LDS-staged pairs, global fallback past cap)
    for (int j = tid; j < sz; j += S1THREADS) {
        u32 pr = (j < S2CAP) ? pst[j] : pairs[p0 + j];
        int pos = atomicAdd(&cur[pr >> SRC_BITS], 1);
        csr[pos] = (int)(pr & ((1u << SRC_BITS) - 1));
    }
}

// ---------------- MFMA GEMM ----------------
// Per row r:  xrow = PRE ? swish(Xb[r]*dis[r] + bin) : bf16(Xf[r])
//             hs[r] = bf16( (xrow @ W) * dis[r] )
// 4 waves/block, 16-row stripe per wave. A-frags direct from global; W staged
// once into LDS as B^T bf16 [col][K] stride KTOT+8.
template <int KTOT, int OUT, int SOUT, bool PRE>
__global__ __launch_bounds__(THREADS) void mfma_gemm_kernel(
    const float* __restrict__ Xf, const u16* __restrict__ Xb,
    const float* __restrict__ W, const float* __restrict__ bin,
    const float* __restrict__ dis, u16* __restrict__ hs, int n)
{
    constexpr int NCG = (OUT + 15) / 16;      // col-frags (4,4,3)
    constexpr int CC  = NCG * 16;             // staged cols (64,64,48)
    constexpr int NKK = KTOT / 32;            // k-steps (4 or 2)
    constexpr int WS  = KTOT + 8;             // WT row stride in elems

    __shared__ u16 WT[CC][WS];                // B^T bf16

    const int tid = threadIdx.x;

    for (int idx = tid; idx < KTOT * CC; idx += THREADS) {
        int k = idx / CC;
        int c = idx - k * CC;
        float v = (c < OUT) ? W[k * OUT + c] : 0.f;
        WT[c][k] = f2bf(v);
    }
    __syncthreads();

    const int lane  = tid & 63;
    const int rlane = lane & 15;              // A row / D col
    const int kgrp  = lane >> 4;              // k-group 0..3
    const int rbase = blockIdx.x * 64 + (tid >> 6) * 16;

    const int arow = min(rbase + rlane, n - 1);   // clamped A row

    float4v acc[NCG];
#pragma unroll
    for (int g = 0; g < NCG; ++g) acc[g] = (float4v)(0.f);

    float dd_a = PRE ? dis[arow] : 0.f;

#pragma unroll
    for (int kk = 0; kk < NKK; ++kk) {
        const int kb = kk * 32 + kgrp * 8;
        short8v a;
        if (PRE) {
            uint4 u = *(const uint4*)(Xb + (size_t)arow * KTOT + kb);
            u32 w[4] = {u.x, u.y, u.z, u.w};
#pragma unroll
            for (int q = 0; q < 4; ++q) {
                float h0 = bf_lo(w[q]) * dd_a + bin[kb + 2 * q];
                float h1 = bf_hi(w[q]) * dd_a + bin[kb + 2 * q + 1];
                a[2 * q]     = (short)f2bf(h0 / (1.f + __expf(-h0)));
                a[2 * q + 1] = (short)f2bf(h1 / (1.f + __expf(-h1)));
            }
        } else {
            float4 f0 = *(const float4*)(Xf + (size_t)arow * KTOT + kb);
            float4 f1 = *(const float4*)(Xf + (size_t)arow * KTOT + kb + 4);
            a[0] = (short)f2bf(f0.x); a[1] = (short)f2bf(f0.y);
            a[2] = (short)f2bf(f0.z); a[3] = (short)f2bf(f0.w);
            a[4] = (short)f2bf(f1.x); a[5] = (short)f2bf(f1.y);
            a[6] = (short)f2bf(f1.z); a[7] = (short)f2bf(f1.w);
        }
#pragma unroll
        for (int g = 0; g < NCG; ++g) {
            short8v b = *(const short8v*)&WT[g * 16 + rlane][kb];
            acc[g] = __builtin_amdgcn_mfma_f32_16x16x32_bf16(a, b, acc[g], 0, 0, 0);
        }
    }

#pragma unroll
    for (int j = 0; j < 4; ++j) {
        int row = rbase + kgrp * 4 + j;
        if (row < n) {
            float dd = dis[row];
#pragma unroll
            for (int g = 0; g < NCG; ++g) {
                int col = g * 16 + rlane;
                if (OUT == CC || col < OUT)
                    hs[(size_t)row * SOUT + col] = f2bf(acc[g][j] * dd);
            }
        }
    }
}

// ---------------- CSR gather-aggregate: one 8-lane subgroup per dst row -------
// agg[d] = bf16( hs[d] + sum_{s in in-edges(d)} hs[s] );  rows are 64 bf16.
// Software-pipelined: all 8 gathers of a batch issued into statically-indexed
// regs before accumulation; next csr word prefetched under the gathers.
__global__ __launch_bounds__(THREADS) void agg64_kernel(
    const int* __restrict__ rowptr, const int* __restrict__ csr,
    const u16* __restrict__ hs, u16* __restrict__ agg, int n)
{
    const int lane = threadIdx.x & 63;
    const int sub  = lane >> 3;                 // subgroup 0..7 (one row each)
    const int gl   = lane & 7;                  // lane in subgroup
    const int d = (blockIdx.x * 4 + (threadIdx.x >> 6)) * 8 + sub;
    if (d >= n) return;
    const int c8 = gl * 8;                      // feature base

    const int beg = rowptr[d], end = rowptr[d + 1];
    float acc[8];
    {
        uint4 u = *(const uint4*)(hs + (size_t)d * 64 + c8);   // self-loop
        acc[0] = bf_lo(u.x); acc[1] = bf_hi(u.x);
        acc[2] = bf_lo(u.y); acc[3] = bf_hi(u.y);
        acc[4] = bf_lo(u.z); acc[5] = bf_hi(u.z);
        acc[6] = bf_lo(u.w); acc[7] = bf_hi(u.w);
    }

    int eidx = (beg + gl < end) ? csr[beg + gl] : 0;
    for (int t = beg; t < end; t += 8) {
        const int m = end - t;                  // >=1 (per-subgroup)
        uint4 ub[8];
#pragma unroll
        for (int q = 0; q < 8; ++q) {           // issue gathers (predicated)
            int s = __shfl(eidx, (sub << 3) + q);
            if (q < m) ub[q] = *(const uint4*)(hs + (size_t)s * 64 + c8);
        }
        int eidx_n = (t + 8 + gl < end) ? csr[t + 8 + gl] : 0;  // prefetch
#pragma unroll
        for (int q = 0; q < 8; ++q) {
            if (q < m) {
                acc[0] += bf_lo(ub[q].x); acc[1] += bf_hi(ub[q].x);
                acc[2] += bf_lo(ub[q].y); acc[3] += bf_hi(ub[q].y);
                acc[4] += bf_lo(ub[q].z); acc[5] += bf_hi(ub[q].z);
                acc[6] += bf_lo(ub[q].w); acc[7] += bf_hi(ub[q].w);
            }
        }
        eidx = eidx_n;
    }

    uint4 o;
    o.x = (u32)f2bf(acc[0]) | ((u32)f2bf(acc[1]) << 16);
    o.y = (u32)f2bf(acc[2]) | ((u32)f2bf(acc[3]) << 16);
    o.z = (u32)f2bf(acc[4]) | ((u32)f2bf(acc[5]) << 16);
    o.w = (u32)f2bf(acc[6]) | ((u32)f2bf(acc[7]) << 16);
    *(uint4*)(agg + (size_t)d * 64 + c8) = o;
}

// ---------------- layer-3 aggregate + bias + log_softmax ----------------------
// hs3 rows: 40 bf16 at stride 48 (96B). One 8-lane subgroup per row; lanes
// gl<5 carry features; same software-pipelined batch as agg64.
__global__ __launch_bounds__(THREADS) void agg40_lsm_kernel(
    const int* __restrict__ rowptr, const int* __restrict__ csr,
    const u16* __restrict__ hs, const float* __restrict__ dis,
    const float* __restrict__ b3, float* __restrict__ out, int n)
{
    constexpr int S = 48;
    const int lane = threadIdx.x & 63;
    const int sub  = lane >> 3;
    const int gl   = lane & 7;
    const int d = (blockIdx.x * 4 + (threadIdx.x >> 6)) * 8 + sub;
    if (d >= n) return;
    const bool act = (gl < 5);
    const int c8 = gl * 8;

    const int beg = rowptr[d], end = rowptr[d + 1];
    float acc[8] = {0.f,0.f,0.f,0.f,0.f,0.f,0.f,0.f};
    if (act) {
        uint4 u = *(const uint4*)(hs + (size_t)d * S + c8);
        acc[0] = bf_lo(u.x); acc[1] = bf_hi(u.x);
        acc[2] = bf_lo(u.y); acc[3] = bf_hi(u.y);
        acc[4] = bf_lo(u.z); acc[5] = bf_hi(u.z);
        acc[6] = bf_lo(u.w); acc[7] = bf_hi(u.w);
    }

    int eidx = (beg + gl < end) ? csr[beg + gl] : 0;
    for (int t = beg; t < end; t += 8) {
        const int m = end - t;
        uint4 ub[8];
#pragma unroll
        for (int q = 0; q < 8; ++q) {
            int s = __shfl(eidx, (sub << 3) + q);
            if (q < m && act) ub[q] = *(const uint4*)(hs + (size_t)s * S + c8);
        }
        int eidx_n = (t + 8 + gl < end) ? csr[t + 8 + gl] : 0;
#pragma unroll
        for (int q = 0; q < 8; ++q) {
            if (q < m && act) {
                acc[0] += bf_lo(ub[q].x); acc[1] += bf_hi(ub[q].x);
                acc[2] += bf_lo(ub[q].y); acc[3] += bf_hi(ub[q].y);
                acc[4] += bf_lo(ub[q].z); acc[5] += bf_hi(ub[q].z);
                acc[6] += bf_lo(ub[q].w); acc[7] += bf_hi(ub[q].w);
            }
        }
        eidx = eidx_n;
    }

    float val[8];
    float mx = -1e30f;
    if (act) {
        float dd = dis[d];
#pragma unroll
        for (int q = 0; q < 8; ++q) {
            val[q] = acc[q] * dd + b3[c8 + q];
            mx = fmaxf(mx, val[q]);
        }
    }
#pragma unroll
    for (int off = 4; off > 0; off >>= 1) mx = fmaxf(mx, __shfl_xor(mx, off));
    float es = 0.f;
    if (act) {
#pragma unroll
        for (int q = 0; q < 8; ++q) es += __expf(val[q] - mx);
    }
#pragma unroll
    for (int off = 4; off > 0; off >>= 1) es += __shfl_xor(es, off);
    float lse = mx + __logf(es);
    if (act) {
        float4 o0 = make_float4(val[0]-lse, val[1]-lse, val[2]-lse, val[3]-lse);
        float4 o1 = make_float4(val[4]-lse, val[5]-lse, val[6]-lse, val[7]-lse);
        *(float4*)(out + (size_t)d * 40 + c8)     = o0;
        *(float4*)(out + (size_t)d * 40 + c8 + 4) = o1;
    }
}

// ---------------- launch ----------------
static inline size_t align_up(size_t v, size_t a) { return (v + a - 1) & ~(a - 1); }

extern "C" void kernel_launch(void* const* d_in, const int* in_sizes, int n_in,
                              void* d_out, int out_size, void* d_ws, size_t ws_size,
                              hipStream_t stream) {
    const float* x  = (const float*)d_in[0];
    const int*   ei = (const int*)d_in[1];
    const float* W1 = (const float*)d_in[2];
    const float* b1 = (const float*)d_in[3];
    const float* W2 = (const float*)d_in[4];
    const float* b2 = (const float*)d_in[5];
    const float* W3 = (const float*)d_in[6];
    const float* b3 = (const float*)d_in[7];
    float* out = (float*)d_out;

    const int n = in_sizes[0] / 128;
    const int e = in_sizes[1] / 2;
    const int* src = ei;
    const int* dst = ei + e;

    // workspace: dis[n] | rowptr[n+1] | bcnt[1k] | bbase[1k+1] | pcur[1k] |
    //            csr[e] | hsb (n*64 u16) | aggb (n*64 u16)
    // pairs u32[e] aliases hsb (consumed in sort2 before gemm1 writes hsb).
    char* base = (char*)d_ws;
    size_t off = 0;
    float* dis = (float*)(base + off);    off = align_up(off + (size_t)n * 4, 256);
    int* rowptr = (int*)(base + off);     off = align_up(off + (size_t)(n + 1) * 4, 256);
    int* bcnt = (int*)(base + off);       off = align_up(off + 1024 * 4, 256);
    int* bbase = (int*)(base + off);      off = align_up(off + 1025 * 4, 256);
    int* pcur = (int*)(base + off);       off = align_up(off + 1024 * 4, 256);
    int* csr = (int*)(base + off);        off = align_up(off + (size_t)e * 4, 256);
    u16* hsb = (u16*)(base + off);        off = align_up(off + (size_t)n * 64 * 2, 256);
    u16* aggb = (u16*)(base + off);       off = align_up(off + (size_t)n * 64 * 2, 256);
    u32* pairs = (u32*)hsb;

    const int gb_rows = (n + 63) / 64;
    const int nbuck   = (n + BSIZE - 1) >> BSHIFT;
    const int gb_s1   = (e + PASS1_CHUNK - 1) / PASS1_CHUNK;
    const int gb_agg  = (n + 31) / 32;          // 32 rows per block (8/wave)

    // CSR build
    bzero_kernel<<<1, THREADS, 0, stream>>>(bcnt, nbuck);
    bhist_kernel<<<gb_s1, THREADS, 0, stream>>>(dst, bcnt, e, nbuck);
    bscan_kernel<<<1, 1024, 0, stream>>>(bcnt, bbase, pcur, rowptr, nbuck, n, e);
    sort1_kernel<<<gb_s1, S1THREADS, 0, stream>>>(src, dst, pcur, pairs, e, nbuck);
    sort2_kernel<<<nbuck, S1THREADS, 0, stream>>>(bbase, pairs, rowptr, dis, csr, n);

    // layer 1: x @ W1 -> hsb (bf16); gather-agg -> aggb (bf16)
    mfma_gemm_kernel<128, 64, 64, false><<<gb_rows, THREADS, 0, stream>>>(
        x, nullptr, W1, nullptr, dis, hsb, n);
    agg64_kernel<<<gb_agg, THREADS, 0, stream>>>(rowptr, csr, hsb, aggb, n);

    // layer 2: swish(aggb*dis+b1) @ W2 -> hsb; gather-agg -> aggb
    mfma_gemm_kernel<64, 64, 64, true><<<gb_rows, THREADS, 0, stream>>>(
        nullptr, aggb, W2, b1, dis, hsb, n);
    agg64_kernel<<<gb_agg, THREADS, 0, stream>>>(rowptr, csr, hsb, aggb, n);

    // layer 3: swish(aggb*dis+b2) @ W3 -> hsb (stride 48); agg + lsm -> out
    mfma_gemm_kernel<64, 40, 48, true><<<gb_rows, THREADS, 0, stream>>>(
        nullptr, aggb, W3, b2, dis, hsb, n);
    agg40_lsm_kernel<<<gb_agg, THREADS, 0, stream>>>(rowptr, csr, hsb, dis, b3, out, n);
}

// Round 11
// 181.534 us; speedup vs baseline: 6.3306x; 1.1535x over previous
//
#include <hip/hip_runtime.h>
#include <math.h>

#define THREADS 256
#define S1THREADS 512
#define BSHIFT 9              // 512 dsts per bucket
#define BSIZE (1 << BSHIFT)
#define PASS1_CHUNK 4096
#define SRC_BITS 17           // n < 131072
#define S2CAP 12288           // sort2 LDS pair-stage capacity (48KB)

typedef unsigned int u32;
typedef unsigned short u16;
typedef __attribute__((ext_vector_type(8))) short short8v;   // 8 bf16 (4 VGPR)
typedef __attribute__((ext_vector_type(4))) float float4v;   // MFMA acc

__device__ __forceinline__ u16 f2bf(float f) {      // RNE fp32 -> bf16
    u32 u = __float_as_uint(f);
    u = (u + 0x7fffu + ((u >> 16) & 1u)) >> 16;
    return (u16)u;
}
__device__ __forceinline__ float bf_lo(u32 u) { return __uint_as_float(u << 16); }
__device__ __forceinline__ float bf_hi(u32 u) { return __uint_as_float(u & 0xffff0000u); }

// ---------------- phase 1: per-block bucket histogram -> hmat[blk][bucket] ----

__global__ __launch_bounds__(S1THREADS) void hist_kernel(
    const int* __restrict__ dst, int* __restrict__ hmat, int e, int nbuck)
{
    __shared__ int hist[BSIZE];
    const int tid = threadIdx.x;
    const int c0  = blockIdx.x * PASS1_CHUNK;
    for (int i = tid; i < nbuck; i += S1THREADS) hist[i] = 0;
    __syncthreads();
    for (int i = tid; i < PASS1_CHUNK; i += S1THREADS) {
        int idx = c0 + i;
        if (idx < e) atomicAdd(&hist[dst[idx] >> BSHIFT], 1);
    }
    __syncthreads();
    for (int b = tid; b < nbuck; b += S1THREADS)
        hmat[blockIdx.x * nbuck + b] = hist[b];
}

// ---------------- phase 2: column scan of hmat -> bmat (relative), bcnt -------
// one block per bucket; exclusive prefix over blocks

__global__ __launch_bounds__(THREADS) void colscan_kernel(
    const int* __restrict__ hmat, int* __restrict__ bmat,
    int* __restrict__ bcnt, int nblk, int nbuck)
{
    __shared__ int s[THREADS];
    const int b = blockIdx.x, tid = threadIdx.x;
    int run = 0;
    for (int t0 = 0; t0 < nblk; t0 += THREADS) {
        int idx = t0 + tid;
        int v = (idx < nblk) ? hmat[idx * nbuck + b] : 0;
        s[tid] = v;
        __syncthreads();
        for (int off = 1; off < THREADS; off <<= 1) {
            int t = (tid >= off) ? s[tid - off] : 0;
            __syncthreads();
            s[tid] += t;
            __syncthreads();
        }
        if (idx < nblk) bmat[idx * nbuck + b] = run + s[tid] - v;
        run += s[THREADS - 1];
        __syncthreads();
    }
    if (tid == 0) bcnt[b] = run;
}

// ---------------- phase 3: scan bucket totals -> bbase; rowptr[n]=e -----------

__global__ __launch_bounds__(1024) void bscan_kernel(const int* __restrict__ bcnt,
                                                     int* __restrict__ bbase,
                                                     int* __restrict__ rowptr,
                                                     int nbuck, int n, int e) {
    __shared__ int s[1024];
    int v = (threadIdx.x < nbuck) ? bcnt[threadIdx.x] : 0;
    s[threadIdx.x] = v;
    __syncthreads();
    for (int off = 1; off < 1024; off <<= 1) {
        int t = (threadIdx.x >= off) ? s[threadIdx.x - off] : 0;
        __syncthreads();
        s[threadIdx.x] += t;
        __syncthreads();
    }
    if (threadIdx.x < nbuck) bbase[threadIdx.x] = s[threadIdx.x] - v;
    if (threadIdx.x == 0) rowptr[n] = e;
}

// ---------------- phase 4: scatter packed (ld<<17|src) into bucket regions ----
// deterministic bases (bbase + bmat): no global atomics, LDS cursors only.

__global__ __launch_bounds__(S1THREADS) void scatter_kernel(
    const int* __restrict__ src, const int* __restrict__ dst,
    const int* __restrict__ bmat, const int* __restrict__ bbase,
    u32* __restrict__ pairs, int e, int nbuck)
{
    __shared__ int base_s[BSIZE], cur[BSIZE];
    const int tid = threadIdx.x;
    const int c0  = blockIdx.x * PASS1_CHUNK;
    for (int b = tid; b < nbuck; b += S1THREADS) {
        base_s[b] = bbase[b] + bmat[blockIdx.x * nbuck + b];
        cur[b] = 0;
    }
    __syncthreads();
    for (int i = tid; i < PASS1_CHUNK; i += S1THREADS) {
        int idx = c0 + i;
        if (idx < e) {
            int d = dst[idx];
            int b = d >> BSHIFT;
            int off = atomicAdd(&cur[b], 1);
            pairs[base_s[b] + off] = ((u32)(d & (BSIZE - 1)) << SRC_BITS) | (u32)src[idx];
        }
    }
}

// ---------------- sort pass 2: degree count + rowptr + dis + csr scatter ------
// One block per bucket; 512 threads. Pairs staged into LDS during the count
// pass; scatter replays from LDS.

__global__ __launch_bounds__(S1THREADS) void sort2_kernel(
    const int* __restrict__ bbase, const u32* __restrict__ pairs,
    int* __restrict__ rowptr, float* __restrict__ dis,
    int* __restrict__ csr, int n, int e)
{
    __shared__ int cnt[BSIZE];
    __shared__ int cur[BSIZE];
    __shared__ int s2[S1THREADS];
    __shared__ u32 pst[S2CAP];

    const int b  = blockIdx.x;
    const int d0 = b << BSHIFT;
    const int nd = min(BSIZE, n - d0);
    const int p0 = bbase[b];
    const int p1 = (d0 + nd >= n) ? e : bbase[b + 1];
    const int sz = p1 - p0;
    const int tid = threadIdx.x;

    for (int i = tid; i < BSIZE; i += S1THREADS) cnt[i] = 0;
    __syncthreads();

    // pass A: count + stage
    for (int j = tid; j < sz; j += S1THREADS) {
        u32 pr = pairs[p0 + j];
        if (j < S2CAP) pst[j] = pr;
        atomicAdd(&cnt[pr >> SRC_BITS], 1);
    }
    __syncthreads();

    // exclusive scan of cnt[0..511], one element per thread
    int v = cnt[tid];
    s2[tid] = v;
    __syncthreads();
    for (int off = 1; off < S1THREADS; off <<= 1) {
        int t = (tid >= off) ? s2[tid - off] : 0;
        __syncthreads();
        s2[tid] += t;
        __syncthreads();
    }
    cur[tid] = p0 + s2[tid] - v;
    __syncthreads();

    for (int i = tid; i < nd; i += S1THREADS) {
        rowptr[d0 + i] = cur[i];
        dis[d0 + i] = rsqrtf((float)(cnt[i] + 1));   // +1 self-loop
    }
    __syncthreads();

    // pass B: scatter (LDS-staged pairs, global fallback past cap)
    for (int j = tid; j < sz; j += S1THREADS) {
        u32 pr = (j < S2CAP) ? pst[j] : pairs[p0 + j];
        int pos = atomicAdd(&cur[pr >> SRC_BITS], 1);
        csr[pos] = (int)(pr & ((1u << SRC_BITS) - 1));
    }
}

// ---------------- MFMA GEMM ----------------
// Per row r:  xrow = PRE ? swish(Xb[r]*dis[r] + bin) : bf16(Xf[r])
//             hs[r] = bf16( (xrow @ W) * dis[r] )
// 4 waves/block, 16-row stripe per wave. A-frags direct from global; W staged
// once into LDS as B^T bf16 [col][K] stride KTOT+8.
template <int KTOT, int OUT, int SOUT, bool PRE>
__global__ __launch_bounds__(THREADS) void mfma_gemm_kernel(
    const float* __restrict__ Xf, const u16* __restrict__ Xb,
    const float* __restrict__ W, const float* __restrict__ bin,
    const float* __restrict__ dis, u16* __restrict__ hs, int n)
{
    constexpr int NCG = (OUT + 15) / 16;      // col-frags (4,4,3)
    constexpr int CC  = NCG * 16;             // staged cols (64,64,48)
    constexpr int NKK = KTOT / 32;            // k-steps (4 or 2)
    constexpr int WS  = KTOT + 8;             // WT row stride in elems

    __shared__ u16 WT[CC][WS];                // B^T bf16

    const int tid = threadIdx.x;

    for (int idx = tid; idx < KTOT * CC; idx += THREADS) {
        int k = idx / CC;
        int c = idx - k * CC;
        float v = (c < OUT) ? W[k * OUT + c] : 0.f;
        WT[c][k] = f2bf(v);
    }
    __syncthreads();

    const int lane  = tid & 63;
    const int rlane = lane & 15;              // A row / D col
    const int kgrp  = lane >> 4;              // k-group 0..3
    const int rbase = blockIdx.x * 64 + (tid >> 6) * 16;

    const int arow = min(rbase + rlane, n - 1);   // clamped A row

    float4v acc[NCG];
#pragma unroll
    for (int g = 0; g < NCG; ++g) acc[g] = (float4v)(0.f);

    float dd_a = PRE ? dis[arow] : 0.f;

#pragma unroll
    for (int kk = 0; kk < NKK; ++kk) {
        const int kb = kk * 32 + kgrp * 8;
        short8v a;
        if (PRE) {
            uint4 u = *(const uint4*)(Xb + (size_t)arow * KTOT + kb);
            u32 w[4] = {u.x, u.y, u.z, u.w};
#pragma unroll
            for (int q = 0; q < 4; ++q) {
                float h0 = bf_lo(w[q]) * dd_a + bin[kb + 2 * q];
                float h1 = bf_hi(w[q]) * dd_a + bin[kb + 2 * q + 1];
                a[2 * q]     = (short)f2bf(h0 / (1.f + __expf(-h0)));
                a[2 * q + 1] = (short)f2bf(h1 / (1.f + __expf(-h1)));
            }
        } else {
            float4 f0 = *(const float4*)(Xf + (size_t)arow * KTOT + kb);
            float4 f1 = *(const float4*)(Xf + (size_t)arow * KTOT + kb + 4);
            a[0] = (short)f2bf(f0.x); a[1] = (short)f2bf(f0.y);
            a[2] = (short)f2bf(f0.z); a[3] = (short)f2bf(f0.w);
            a[4] = (short)f2bf(f1.x); a[5] = (short)f2bf(f1.y);
            a[6] = (short)f2bf(f1.z); a[7] = (short)f2bf(f1.w);
        }
#pragma unroll
        for (int g = 0; g < NCG; ++g) {
            short8v b = *(const short8v*)&WT[g * 16 + rlane][kb];
            acc[g] = __builtin_amdgcn_mfma_f32_16x16x32_bf16(a, b, acc[g], 0, 0, 0);
        }
    }

#pragma unroll
    for (int j = 0; j < 4; ++j) {
        int row = rbase + kgrp * 4 + j;
        if (row < n) {
            float dd = dis[row];
#pragma unroll
            for (int g = 0; g < NCG; ++g) {
                int col = g * 16 + rlane;
                if (OUT == CC || col < OUT)
                    hs[(size_t)row * SOUT + col] = f2bf(acc[g][j] * dd);
            }
        }
    }
}

// ---------------- CSR gather-aggregate: one 8-lane subgroup per dst row -------
// agg[d] = bf16( hs[d] + sum_{s in in-edges(d)} hs[s] );  rows are 64 bf16.
// Software-pipelined: all 8 gathers of a batch issued into statically-indexed
// regs before accumulation; next csr word prefetched under the gathers.
__global__ __launch_bounds__(THREADS) void agg64_kernel(
    const int* __restrict__ rowptr, const int* __restrict__ csr,
    const u16* __restrict__ hs, u16* __restrict__ agg, int n)
{
    const int lane = threadIdx.x & 63;
    const int sub  = lane >> 3;                 // subgroup 0..7 (one row each)
    const int gl   = lane & 7;                  // lane in subgroup
    const int d = (blockIdx.x * 4 + (threadIdx.x >> 6)) * 8 + sub;
    if (d >= n) return;
    const int c8 = gl * 8;                      // feature base

    const int beg = rowptr[d], end = rowptr[d + 1];
    float acc[8];
    {
        uint4 u = *(const uint4*)(hs + (size_t)d * 64 + c8);   // self-loop
        acc[0] = bf_lo(u.x); acc[1] = bf_hi(u.x);
        acc[2] = bf_lo(u.y); acc[3] = bf_hi(u.y);
        acc[4] = bf_lo(u.z); acc[5] = bf_hi(u.z);
        acc[6] = bf_lo(u.w); acc[7] = bf_hi(u.w);
    }

    int eidx = (beg + gl < end) ? csr[beg + gl] : 0;
    for (int t = beg; t < end; t += 8) {
        const int m = end - t;                  // >=1 (per-subgroup)
        uint4 ub[8];
#pragma unroll
        for (int q = 0; q < 8; ++q) {           // issue gathers (predicated)
            int s = __shfl(eidx, (sub << 3) + q);
            if (q < m) ub[q] = *(const uint4*)(hs + (size_t)s * 64 + c8);
        }
        int eidx_n = (t + 8 + gl < end) ? csr[t + 8 + gl] : 0;  // prefetch
#pragma unroll
        for (int q = 0; q < 8; ++q) {
            if (q < m) {
                acc[0] += bf_lo(ub[q].x); acc[1] += bf_hi(ub[q].x);
                acc[2] += bf_lo(ub[q].y); acc[3] += bf_hi(ub[q].y);
                acc[4] += bf_lo(ub[q].z); acc[5] += bf_hi(ub[q].z);
                acc[6] += bf_lo(ub[q].w); acc[7] += bf_hi(ub[q].w);
            }
        }
        eidx = eidx_n;
    }

    uint4 o;
    o.x = (u32)f2bf(acc[0]) | ((u32)f2bf(acc[1]) << 16);
    o.y = (u32)f2bf(acc[2]) | ((u32)f2bf(acc[3]) << 16);
    o.z = (u32)f2bf(acc[4]) | ((u32)f2bf(acc[5]) << 16);
    o.w = (u32)f2bf(acc[6]) | ((u32)f2bf(acc[7]) << 16);
    *(uint4*)(agg + (size_t)d * 64 + c8) = o;
}

// ---------------- layer-3 aggregate + bias + log_softmax ----------------------
// hs3 rows: 40 bf16 at stride 48 (96B). One 8-lane subgroup per row; lanes
// gl<5 carry features; same software-pipelined batch as agg64.
__global__ __launch_bounds__(THREADS) void agg40_lsm_kernel(
    const int* __restrict__ rowptr, const int* __restrict__ csr,
    const u16* __restrict__ hs, const float* __restrict__ dis,
    const float* __restrict__ b3, float* __restrict__ out, int n)
{
    constexpr int S = 48;
    const int lane = threadIdx.x & 63;
    const int sub  = lane >> 3;
    const int gl   = lane & 7;
    const int d = (blockIdx.x * 4 + (threadIdx.x >> 6)) * 8 + sub;
    if (d >= n) return;
    const bool act = (gl < 5);
    const int c8 = gl * 8;

    const int beg = rowptr[d], end = rowptr[d + 1];
    float acc[8] = {0.f,0.f,0.f,0.f,0.f,0.f,0.f,0.f};
    if (act) {
        uint4 u = *(const uint4*)(hs + (size_t)d * S + c8);
        acc[0] = bf_lo(u.x); acc[1] = bf_hi(u.x);
        acc[2] = bf_lo(u.y); acc[3] = bf_hi(u.y);
        acc[4] = bf_lo(u.z); acc[5] = bf_hi(u.z);
        acc[6] = bf_lo(u.w); acc[7] = bf_hi(u.w);
    }

    int eidx = (beg + gl < end) ? csr[beg + gl] : 0;
    for (int t = beg; t < end; t += 8) {
        const int m = end - t;
        uint4 ub[8];
#pragma unroll
        for (int q = 0; q < 8; ++q) {
            int s = __shfl(eidx, (sub << 3) + q);
            if (q < m && act) ub[q] = *(const uint4*)(hs + (size_t)s * S + c8);
        }
        int eidx_n = (t + 8 + gl < end) ? csr[t + 8 + gl] : 0;
#pragma unroll
        for (int q = 0; q < 8; ++q) {
            if (q < m && act) {
                acc[0] += bf_lo(ub[q].x); acc[1] += bf_hi(ub[q].x);
                acc[2] += bf_lo(ub[q].y); acc[3] += bf_hi(ub[q].y);
                acc[4] += bf_lo(ub[q].z); acc[5] += bf_hi(ub[q].z);
                acc[6] += bf_lo(ub[q].w); acc[7] += bf_hi(ub[q].w);
            }
        }
        eidx = eidx_n;
    }

    float val[8];
    float mx = -1e30f;
    if (act) {
        float dd = dis[d];
#pragma unroll
        for (int q = 0; q < 8; ++q) {
            val[q] = acc[q] * dd + b3[c8 + q];
            mx = fmaxf(mx, val[q]);
        }
    }
#pragma unroll
    for (int off = 4; off > 0; off >>= 1) mx = fmaxf(mx, __shfl_xor(mx, off));
    float es = 0.f;
    if (act) {
#pragma unroll
        for (int q = 0; q < 8; ++q) es += __expf(val[q] - mx);
    }
#pragma unroll
    for (int off = 4; off > 0; off >>= 1) es += __shfl_xor(es, off);
    float lse = mx + __logf(es);
    if (act) {
        float4 o0 = make_float4(val[0]-lse, val[1]-lse, val[2]-lse, val[3]-lse);
        float4 o1 = make_float4(val[4]-lse, val[5]-lse, val[6]-lse, val[7]-lse);
        *(float4*)(out + (size_t)d * 40 + c8)     = o0;
        *(float4*)(out + (size_t)d * 40 + c8 + 4) = o1;
    }
}

// ---------------- launch ----------------
static inline size_t align_up(size_t v, size_t a) { return (v + a - 1) & ~(a - 1); }

extern "C" void kernel_launch(void* const* d_in, const int* in_sizes, int n_in,
                              void* d_out, int out_size, void* d_ws, size_t ws_size,
                              hipStream_t stream) {
    const float* x  = (const float*)d_in[0];
    const int*   ei = (const int*)d_in[1];
    const float* W1 = (const float*)d_in[2];
    const float* b1 = (const float*)d_in[3];
    const float* W2 = (const float*)d_in[4];
    const float* b2 = (const float*)d_in[5];
    const float* W3 = (const float*)d_in[6];
    const float* b3 = (const float*)d_in[7];
    float* out = (float*)d_out;

    const int n = in_sizes[0] / 128;
    const int e = in_sizes[1] / 2;
    const int* src = ei;
    const int* dst = ei + e;

    const int nbuck = (n + BSIZE - 1) >> BSHIFT;            // 196 for n=100k
    const int nblk  = (e + PASS1_CHUNK - 1) / PASS1_CHUNK;  // 391

    // workspace: dis[n] | rowptr[n+1] | bcnt[1k] | bbase[1k+1] |
    //            hmat[nblk*nbuck] | bmat[nblk*nbuck] | csr[e] |
    //            hsb (n*64 u16) | aggb (n*64 u16)
    // pairs u32[e] aliases hsb (consumed in sort2 before gemm1 writes hsb).
    char* base = (char*)d_ws;
    size_t off = 0;
    float* dis = (float*)(base + off);    off = align_up(off + (size_t)n * 4, 256);
    int* rowptr = (int*)(base + off);     off = align_up(off + (size_t)(n + 1) * 4, 256);
    int* bcnt = (int*)(base + off);       off = align_up(off + 1024 * 4, 256);
    int* bbase = (int*)(base + off);      off = align_up(off + 1025 * 4, 256);
    int* hmat = (int*)(base + off);       off = align_up(off + (size_t)nblk * nbuck * 4, 256);
    int* bmat = (int*)(base + off);       off = align_up(off + (size_t)nblk * nbuck * 4, 256);
    int* csr = (int*)(base + off);        off = align_up(off + (size_t)e * 4, 256);
    u16* hsb = (u16*)(base + off);        off = align_up(off + (size_t)n * 64 * 2, 256);
    u16* aggb = (u16*)(base + off);       off = align_up(off + (size_t)n * 64 * 2, 256);
    u32* pairs = (u32*)hsb;

    const int gb_rows = (n + 63) / 64;
    const int gb_agg  = (n + 31) / 32;          // 32 rows per block (8/wave)

    // CSR build (deterministic, no global atomics)
    hist_kernel<<<nblk, S1THREADS, 0, stream>>>(dst, hmat, e, nbuck);
    colscan_kernel<<<nbuck, THREADS, 0, stream>>>(hmat, bmat, bcnt, nblk, nbuck);
    bscan_kernel<<<1, 1024, 0, stream>>>(bcnt, bbase, rowptr, nbuck, n, e);
    scatter_kernel<<<nblk, S1THREADS, 0, stream>>>(src, dst, bmat, bbase, pairs, e, nbuck);
    sort2_kernel<<<nbuck, S1THREADS, 0, stream>>>(bbase, pairs, rowptr, dis, csr, n, e);

    // layer 1: x @ W1 -> hsb (bf16); gather-agg -> aggb (bf16)
    mfma_gemm_kernel<128, 64, 64, false><<<gb_rows, THREADS, 0, stream>>>(
        x, nullptr, W1, nullptr, dis, hsb, n);
    agg64_kernel<<<gb_agg, THREADS, 0, stream>>>(rowptr, csr, hsb, aggb, n);

    // layer 2: swish(aggb*dis+b1) @ W2 -> hsb; gather-agg -> aggb
    mfma_gemm_kernel<64, 64, 64, true><<<gb_rows, THREADS, 0, stream>>>(
        nullptr, aggb, W2, b1, dis, hsb, n);
    agg64_kernel<<<gb_agg, THREADS, 0, stream>>>(rowptr, csr, hsb, aggb, n);

    // layer 3: swish(aggb*dis+b2) @ W3 -> hsb (stride 48); agg + lsm -> out
    mfma_gemm_kernel<64, 40, 48, true><<<gb_rows, THREADS, 0, stream>>>(
        nullptr, aggb, W3, b2, dis, hsb, n);
    agg40_lsm_kernel<<<gb_agg, THREADS, 0, stream>>>(rowptr, csr, hsb, dis, b3, out, n);
}

// Round 12
// 175.994 us; speedup vs baseline: 6.5299x; 1.0315x over previous
//
#include <hip/hip_runtime.h>
#include <math.h>

#define THREADS 256
#define S1THREADS 512
#define BSHIFT 9              // 512 dsts per bucket
#define BSIZE (1 << BSHIFT)
#define PASS1_CHUNK 4096
#define SRC_BITS 17           // n < 131072
#define S2CAP 12288           // sort2 LDS pair-stage capacity (48KB)

typedef unsigned int u32;
typedef unsigned short u16;
typedef __attribute__((ext_vector_type(8))) short short8v;   // 8 bf16 (4 VGPR)
typedef __attribute__((ext_vector_type(4))) float float4v;   // MFMA acc

__device__ __forceinline__ u16 f2bf(float f) {      // RNE fp32 -> bf16
    u32 u = __float_as_uint(f);
    u = (u + 0x7fffu + ((u >> 16) & 1u)) >> 16;
    return (u16)u;
}
__device__ __forceinline__ float bf_lo(u32 u) { return __uint_as_float(u << 16); }
__device__ __forceinline__ float bf_hi(u32 u) { return __uint_as_float(u & 0xffff0000u); }

// ---------------- phase 1: per-block bucket histogram -> hmat[blk][bucket] ----

__global__ __launch_bounds__(S1THREADS) void hist_kernel(
    const int* __restrict__ dst, int* __restrict__ hmat, int e, int nbuck)
{
    __shared__ int hist[BSIZE];
    const int tid = threadIdx.x;
    const int c0  = blockIdx.x * PASS1_CHUNK;
    for (int i = tid; i < nbuck; i += S1THREADS) hist[i] = 0;
    __syncthreads();
    for (int i = tid; i < PASS1_CHUNK; i += S1THREADS) {
        int idx = c0 + i;
        if (idx < e) atomicAdd(&hist[dst[idx] >> BSHIFT], 1);
    }
    __syncthreads();
    for (int b = tid; b < nbuck; b += S1THREADS)
        hmat[blockIdx.x * nbuck + b] = hist[b];
}

// ---------------- phase 2: column scan of hmat -> bmat (relative), bcnt -------

__global__ __launch_bounds__(THREADS) void colscan_kernel(
    const int* __restrict__ hmat, int* __restrict__ bmat,
    int* __restrict__ bcnt, int nblk, int nbuck)
{
    __shared__ int s[THREADS];
    const int b = blockIdx.x, tid = threadIdx.x;
    int run = 0;
    for (int t0 = 0; t0 < nblk; t0 += THREADS) {
        int idx = t0 + tid;
        int v = (idx < nblk) ? hmat[idx * nbuck + b] : 0;
        s[tid] = v;
        __syncthreads();
        for (int off = 1; off < THREADS; off <<= 1) {
            int t = (tid >= off) ? s[tid - off] : 0;
            __syncthreads();
            s[tid] += t;
            __syncthreads();
        }
        if (idx < nblk) bmat[idx * nbuck + b] = run + s[tid] - v;
        run += s[THREADS - 1];
        __syncthreads();
    }
    if (tid == 0) bcnt[b] = run;
}

// ---------------- phase 3: scan bucket totals -> bbase; rowptr[n]=e -----------

__global__ __launch_bounds__(1024) void bscan_kernel(const int* __restrict__ bcnt,
                                                     int* __restrict__ bbase,
                                                     int* __restrict__ rowptr,
                                                     int nbuck, int n, int e) {
    __shared__ int s[1024];
    int v = (threadIdx.x < nbuck) ? bcnt[threadIdx.x] : 0;
    s[threadIdx.x] = v;
    __syncthreads();
    for (int off = 1; off < 1024; off <<= 1) {
        int t = (threadIdx.x >= off) ? s[threadIdx.x - off] : 0;
        __syncthreads();
        s[threadIdx.x] += t;
        __syncthreads();
    }
    if (threadIdx.x < nbuck) bbase[threadIdx.x] = s[threadIdx.x] - v;
    if (threadIdx.x == 0) rowptr[n] = e;
}

// ---------------- phase 4: scatter packed (ld<<17|src) into bucket regions ----

__global__ __launch_bounds__(S1THREADS) void scatter_kernel(
    const int* __restrict__ src, const int* __restrict__ dst,
    const int* __restrict__ bmat, const int* __restrict__ bbase,
    u32* __restrict__ pairs, int e, int nbuck)
{
    __shared__ int base_s[BSIZE], cur[BSIZE];
    const int tid = threadIdx.x;
    const int c0  = blockIdx.x * PASS1_CHUNK;
    for (int b = tid; b < nbuck; b += S1THREADS) {
        base_s[b] = bbase[b] + bmat[blockIdx.x * nbuck + b];
        cur[b] = 0;
    }
    __syncthreads();
    for (int i = tid; i < PASS1_CHUNK; i += S1THREADS) {
        int idx = c0 + i;
        if (idx < e) {
            int d = dst[idx];
            int b = d >> BSHIFT;
            int off = atomicAdd(&cur[b], 1);
            pairs[base_s[b] + off] = ((u32)(d & (BSIZE - 1)) << SRC_BITS) | (u32)src[idx];
        }
    }
}

// ---------------- sort pass 2: degree count + rowptr + dis + csr scatter ------

__global__ __launch_bounds__(S1THREADS) void sort2_kernel(
    const int* __restrict__ bbase, const u32* __restrict__ pairs,
    int* __restrict__ rowptr, float* __restrict__ dis,
    int* __restrict__ csr, int n, int e)
{
    __shared__ int cnt[BSIZE];
    __shared__ int cur[BSIZE];
    __shared__ int s2[S1THREADS];
    __shared__ u32 pst[S2CAP];

    const int b  = blockIdx.x;
    const int d0 = b << BSHIFT;
    const int nd = min(BSIZE, n - d0);
    const int p0 = bbase[b];
    const int p1 = (d0 + nd >= n) ? e : bbase[b + 1];
    const int sz = p1 - p0;
    const int tid = threadIdx.x;

    for (int i = tid; i < BSIZE; i += S1THREADS) cnt[i] = 0;
    __syncthreads();

    for (int j = tid; j < sz; j += S1THREADS) {
        u32 pr = pairs[p0 + j];
        if (j < S2CAP) pst[j] = pr;
        atomicAdd(&cnt[pr >> SRC_BITS], 1);
    }
    __syncthreads();

    int v = cnt[tid];
    s2[tid] = v;
    __syncthreads();
    for (int off = 1; off < S1THREADS; off <<= 1) {
        int t = (tid >= off) ? s2[tid - off] : 0;
        __syncthreads();
        s2[tid] += t;
        __syncthreads();
    }
    cur[tid] = p0 + s2[tid] - v;
    __syncthreads();

    for (int i = tid; i < nd; i += S1THREADS) {
        rowptr[d0 + i] = cur[i];
        dis[d0 + i] = rsqrtf((float)(cnt[i] + 1));   // +1 self-loop
    }
    __syncthreads();

    for (int j = tid; j < sz; j += S1THREADS) {
        u32 pr = (j < S2CAP) ? pst[j] : pairs[p0 + j];
        int pos = atomicAdd(&cur[pr >> SRC_BITS], 1);
        csr[pos] = (int)(pr & ((1u << SRC_BITS) - 1));
    }
}

// ---------------- MFMA GEMM (layer 1: fp32 input, no pre-activation) ----------
// hs[r] = bf16( (bf16(Xf[r]) @ W) * dis[r] )
template <int KTOT, int OUT, int SOUT>
__global__ __launch_bounds__(THREADS) void mfma_gemm_kernel(
    const float* __restrict__ Xf, const float* __restrict__ W,
    const float* __restrict__ dis, u16* __restrict__ hs, int n)
{
    constexpr int NCG = (OUT + 15) / 16;
    constexpr int CC  = NCG * 16;
    constexpr int NKK = KTOT / 32;
    constexpr int WS  = KTOT + 8;

    __shared__ u16 WT[CC][WS];                // B^T bf16

    const int tid = threadIdx.x;
    for (int idx = tid; idx < KTOT * CC; idx += THREADS) {
        int k = idx / CC;
        int c = idx - k * CC;
        float v = (c < OUT) ? W[k * OUT + c] : 0.f;
        WT[c][k] = f2bf(v);
    }
    __syncthreads();

    const int lane  = tid & 63;
    const int rlane = lane & 15;
    const int kgrp  = lane >> 4;
    const int rbase = blockIdx.x * 64 + (tid >> 6) * 16;
    const int arow = min(rbase + rlane, n - 1);

    float4v acc[NCG];
#pragma unroll
    for (int g = 0; g < NCG; ++g) acc[g] = (float4v)(0.f);

#pragma unroll
    for (int kk = 0; kk < NKK; ++kk) {
        const int kb = kk * 32 + kgrp * 8;
        short8v a;
        float4 f0 = *(const float4*)(Xf + (size_t)arow * KTOT + kb);
        float4 f1 = *(const float4*)(Xf + (size_t)arow * KTOT + kb + 4);
        a[0] = (short)f2bf(f0.x); a[1] = (short)f2bf(f0.y);
        a[2] = (short)f2bf(f0.z); a[3] = (short)f2bf(f0.w);
        a[4] = (short)f2bf(f1.x); a[5] = (short)f2bf(f1.y);
        a[6] = (short)f2bf(f1.z); a[7] = (short)f2bf(f1.w);
#pragma unroll
        for (int g = 0; g < NCG; ++g) {
            short8v b = *(const short8v*)&WT[g * 16 + rlane][kb];
            acc[g] = __builtin_amdgcn_mfma_f32_16x16x32_bf16(a, b, acc[g], 0, 0, 0);
        }
    }

#pragma unroll
    for (int j = 0; j < 4; ++j) {
        int row = rbase + kgrp * 4 + j;
        if (row < n) {
            float dd = dis[row];
#pragma unroll
            for (int g = 0; g < NCG; ++g) {
                int col = g * 16 + rlane;
                if (OUT == CC || col < OUT)
                    hs[(size_t)row * SOUT + col] = f2bf(acc[g][j] * dd);
            }
        }
    }
}

// ---------------- fused gather-aggregate + swish + MFMA GEMM ------------------
// Phase 1: per 64-row tile, aggregate agg[d] = hs[d] + sum_src hs[src] (64-col
//   bf16 source), apply swish(agg*dis + bin), store bf16 A-tile in LDS.
// Phase 2: MFMA  hsout[r] = bf16( (A @ W) * dis[r] ),  A from LDS.
template <int OUT, int SOUT>
__global__ __launch_bounds__(THREADS) void fused_agg_gemm_kernel(
    const int* __restrict__ rowptr, const int* __restrict__ csr,
    const u16* __restrict__ hs, const float* __restrict__ W,
    const float* __restrict__ bin, const float* __restrict__ dis,
    u16* __restrict__ hsout, int n)
{
    constexpr int KTOT = 64;
    constexpr int NCG = (OUT + 15) / 16;
    constexpr int CC  = NCG * 16;
    constexpr int WS  = KTOT + 8;

    __shared__ u16 WT[CC][WS];                // B^T bf16
    __shared__ u16 As[64][WS];                // aggregated+activated A tile

    const int tid = threadIdx.x;
    for (int idx = tid; idx < KTOT * CC; idx += THREADS) {
        int k = idx / CC;
        int c = idx - k * CC;
        float v = (c < OUT) ? W[k * OUT + c] : 0.f;
        WT[c][k] = f2bf(v);
    }

    const int lane = tid & 63;
    const int wid  = tid >> 6;
    const int sub  = lane >> 3;               // subgroup 0..7 (one row each)
    const int gl   = lane & 7;
    const int c8   = gl * 8;
    const int row0 = blockIdx.x * 64;

    // ---- phase 1: gather-aggregate 64 rows (2 halves x 32 rows) ----
#pragma unroll
    for (int half = 0; half < 2; ++half) {
        const int lr = half * 32 + wid * 8 + sub;   // local row 0..63
        const int d  = row0 + lr;
        if (d < n) {
            const int beg = rowptr[d], end = rowptr[d + 1];
            float acc[8];
            {
                uint4 u = *(const uint4*)(hs + (size_t)d * 64 + c8);  // self-loop
                acc[0] = bf_lo(u.x); acc[1] = bf_hi(u.x);
                acc[2] = bf_lo(u.y); acc[3] = bf_hi(u.y);
                acc[4] = bf_lo(u.z); acc[5] = bf_hi(u.z);
                acc[6] = bf_lo(u.w); acc[7] = bf_hi(u.w);
            }
            int eidx = (beg + gl < end) ? csr[beg + gl] : 0;
            for (int t = beg; t < end; t += 8) {
                const int m = end - t;
                uint4 ub[8];
#pragma unroll
                for (int q = 0; q < 8; ++q) {
                    int s = __shfl(eidx, (sub << 3) + q);
                    if (q < m) ub[q] = *(const uint4*)(hs + (size_t)s * 64 + c8);
                }
                int eidx_n = (t + 8 + gl < end) ? csr[t + 8 + gl] : 0;
#pragma unroll
                for (int q = 0; q < 8; ++q) {
                    if (q < m) {
                        acc[0] += bf_lo(ub[q].x); acc[1] += bf_hi(ub[q].x);
                        acc[2] += bf_lo(ub[q].y); acc[3] += bf_hi(ub[q].y);
                        acc[4] += bf_lo(ub[q].z); acc[5] += bf_hi(ub[q].z);
                        acc[6] += bf_lo(ub[q].w); acc[7] += bf_hi(ub[q].w);
                    }
                }
                eidx = eidx_n;
            }
            // swish(agg*dis + b) -> bf16 A row
            float dd = dis[d];
            u16 o[8];
#pragma unroll
            for (int q = 0; q < 8; ++q) {
                float h = acc[q] * dd + bin[c8 + q];
                o[q] = f2bf(h / (1.f + __expf(-h)));
            }
            ushort4 o0 = {o[0], o[1], o[2], o[3]};
            ushort4 o1 = {o[4], o[5], o[6], o[7]};
            *(ushort4*)&As[lr][c8]     = o0;
            *(ushort4*)&As[lr][c8 + 4] = o1;
        }
    }
    __syncthreads();

    // ---- phase 2: MFMA from LDS ----
    const int rlane = lane & 15;
    const int kgrp  = lane >> 4;
    const int rbase = row0 + wid * 16;

    float4v acc[NCG];
#pragma unroll
    for (int g = 0; g < NCG; ++g) acc[g] = (float4v)(0.f);

#pragma unroll
    for (int kk = 0; kk < 2; ++kk) {
        const int kb = kk * 32 + kgrp * 8;
        short8v a = *(const short8v*)&As[wid * 16 + rlane][kb];
#pragma unroll
        for (int g = 0; g < NCG; ++g) {
            short8v b = *(const short8v*)&WT[g * 16 + rlane][kb];
            acc[g] = __builtin_amdgcn_mfma_f32_16x16x32_bf16(a, b, acc[g], 0, 0, 0);
        }
    }

#pragma unroll
    for (int j = 0; j < 4; ++j) {
        int row = rbase + kgrp * 4 + j;
        if (row < n) {
            float dd = dis[row];
#pragma unroll
            for (int g = 0; g < NCG; ++g) {
                int col = g * 16 + rlane;
                if (OUT == CC || col < OUT)
                    hsout[(size_t)row * SOUT + col] = f2bf(acc[g][j] * dd);
            }
        }
    }
}

// ---------------- layer-3 aggregate + bias + log_softmax ----------------------
// hs3 rows: 40 bf16 at stride 48 (96B). One 8-lane subgroup per row.
__global__ __launch_bounds__(THREADS) void agg40_lsm_kernel(
    const int* __restrict__ rowptr, const int* __restrict__ csr,
    const u16* __restrict__ hs, const float* __restrict__ dis,
    const float* __restrict__ b3, float* __restrict__ out, int n)
{
    constexpr int S = 48;
    const int lane = threadIdx.x & 63;
    const int sub  = lane >> 3;
    const int gl   = lane & 7;
    const int d = (blockIdx.x * 4 + (threadIdx.x >> 6)) * 8 + sub;
    if (d >= n) return;
    const bool act = (gl < 5);
    const int c8 = gl * 8;

    const int beg = rowptr[d], end = rowptr[d + 1];
    float acc[8] = {0.f,0.f,0.f,0.f,0.f,0.f,0.f,0.f};
    if (act) {
        uint4 u = *(const uint4*)(hs + (size_t)d * S + c8);
        acc[0] = bf_lo(u.x); acc[1] = bf_hi(u.x);
        acc[2] = bf_lo(u.y); acc[3] = bf_hi(u.y);
        acc[4] = bf_lo(u.z); acc[5] = bf_hi(u.z);
        acc[6] = bf_lo(u.w); acc[7] = bf_hi(u.w);
    }

    int eidx = (beg + gl < end) ? csr[beg + gl] : 0;
    for (int t = beg; t < end; t += 8) {
        const int m = end - t;
        uint4 ub[8];
#pragma unroll
        for (int q = 0; q < 8; ++q) {
            int s = __shfl(eidx, (sub << 3) + q);
            if (q < m && act) ub[q] = *(const uint4*)(hs + (size_t)s * S + c8);
        }
        int eidx_n = (t + 8 + gl < end) ? csr[t + 8 + gl] : 0;
#pragma unroll
        for (int q = 0; q < 8; ++q) {
            if (q < m && act) {
                acc[0] += bf_lo(ub[q].x); acc[1] += bf_hi(ub[q].x);
                acc[2] += bf_lo(ub[q].y); acc[3] += bf_hi(ub[q].y);
                acc[4] += bf_lo(ub[q].z); acc[5] += bf_hi(ub[q].z);
                acc[6] += bf_lo(ub[q].w); acc[7] += bf_hi(ub[q].w);
            }
        }
        eidx = eidx_n;
    }

    float val[8];
    float mx = -1e30f;
    if (act) {
        float dd = dis[d];
#pragma unroll
        for (int q = 0; q < 8; ++q) {
            val[q] = acc[q] * dd + b3[c8 + q];
            mx = fmaxf(mx, val[q]);
        }
    }
#pragma unroll
    for (int off = 4; off > 0; off >>= 1) mx = fmaxf(mx, __shfl_xor(mx, off));
    float es = 0.f;
    if (act) {
#pragma unroll
        for (int q = 0; q < 8; ++q) es += __expf(val[q] - mx);
    }
#pragma unroll
    for (int off = 4; off > 0; off >>= 1) es += __shfl_xor(es, off);
    float lse = mx + __logf(es);
    if (act) {
        float4 o0 = make_float4(val[0]-lse, val[1]-lse, val[2]-lse, val[3]-lse);
        float4 o1 = make_float4(val[4]-lse, val[5]-lse, val[6]-lse, val[7]-lse);
        *(float4*)(out + (size_t)d * 40 + c8)     = o0;
        *(float4*)(out + (size_t)d * 40 + c8 + 4) = o1;
    }
}

// ---------------- launch ----------------
static inline size_t align_up(size_t v, size_t a) { return (v + a - 1) & ~(a - 1); }

extern "C" void kernel_launch(void* const* d_in, const int* in_sizes, int n_in,
                              void* d_out, int out_size, void* d_ws, size_t ws_size,
                              hipStream_t stream) {
    const float* x  = (const float*)d_in[0];
    const int*   ei = (const int*)d_in[1];
    const float* W1 = (const float*)d_in[2];
    const float* b1 = (const float*)d_in[3];
    const float* W2 = (const float*)d_in[4];
    const float* b2 = (const float*)d_in[5];
    const float* W3 = (const float*)d_in[6];
    const float* b3 = (const float*)d_in[7];
    float* out = (float*)d_out;

    const int n = in_sizes[0] / 128;
    const int e = in_sizes[1] / 2;
    const int* src = ei;
    const int* dst = ei + e;

    const int nbuck = (n + BSIZE - 1) >> BSHIFT;            // 196 for n=100k
    const int nblk  = (e + PASS1_CHUNK - 1) / PASS1_CHUNK;  // 391

    // workspace: dis[n] | rowptr[n+1] | bcnt[1k] | bbase[1k+1] |
    //            hmat[nblk*nbuck] | bmat[nblk*nbuck] | csr[e] |
    //            hsb (n*64 u16) | hs2b (n*64 u16)
    // pairs u32[e] aliases hsb (consumed in sort2 before gemm1 writes hsb).
    char* base = (char*)d_ws;
    size_t off = 0;
    float* dis = (float*)(base + off);    off = align_up(off + (size_t)n * 4, 256);
    int* rowptr = (int*)(base + off);     off = align_up(off + (size_t)(n + 1) * 4, 256);
    int* bcnt = (int*)(base + off);       off = align_up(off + 1024 * 4, 256);
    int* bbase = (int*)(base + off);      off = align_up(off + 1025 * 4, 256);
    int* hmat = (int*)(base + off);       off = align_up(off + (size_t)nblk * nbuck * 4, 256);
    int* bmat = (int*)(base + off);       off = align_up(off + (size_t)nblk * nbuck * 4, 256);
    int* csr = (int*)(base + off);        off = align_up(off + (size_t)e * 4, 256);
    u16* hsb = (u16*)(base + off);        off = align_up(off + (size_t)n * 64 * 2, 256);
    u16* hs2b = (u16*)(base + off);       off = align_up(off + (size_t)n * 64 * 2, 256);
    u32* pairs = (u32*)hsb;

    const int gb_rows = (n + 63) / 64;
    const int gb_agg  = (n + 31) / 32;

    // CSR build (deterministic, no global atomics)
    hist_kernel<<<nblk, S1THREADS, 0, stream>>>(dst, hmat, e, nbuck);
    colscan_kernel<<<nbuck, THREADS, 0, stream>>>(hmat, bmat, bcnt, nblk, nbuck);
    bscan_kernel<<<1, 1024, 0, stream>>>(bcnt, bbase, rowptr, nbuck, n, e);
    scatter_kernel<<<nblk, S1THREADS, 0, stream>>>(src, dst, bmat, bbase, pairs, e, nbuck);
    sort2_kernel<<<nbuck, S1THREADS, 0, stream>>>(bbase, pairs, rowptr, dis, csr, n, e);

    // layer 1: x @ W1 -> hsb (hs1, bf16)
    mfma_gemm_kernel<128, 64, 64><<<gb_rows, THREADS, 0, stream>>>(x, W1, dis, hsb, n);

    // layer 2 fused: gather-agg(hs1) + swish(+b1) + @W2 -> hs2b (hs2)
    fused_agg_gemm_kernel<64, 64><<<gb_rows, THREADS, 0, stream>>>(
        rowptr, csr, hsb, W2, b1, dis, hs2b, n);

    // layer 3 fused: gather-agg(hs2) + swish(+b2) + @W3 -> hsb (hs3, stride 48)
    fused_agg_gemm_kernel<40, 48><<<gb_rows, THREADS, 0, stream>>>(
        rowptr, csr, hs2b, W3, b2, dis, hsb, n);

    // final: gather-agg(hs3) + bias + log_softmax -> out
    agg40_lsm_kernel<<<gb_agg, THREADS, 0, stream>>>(rowptr, csr, hsb, dis, b3, out, n);
}

// Round 13
// 170.868 us; speedup vs baseline: 6.7258x; 1.0300x over previous
//
#include <hip/hip_runtime.h>
#include <math.h>

#define THREADS 256
#define S1THREADS 512
#define BSHIFT 9              // 512 dsts per bucket
#define BSIZE (1 << BSHIFT)
#define PASS1_CHUNK 4096
#define SRC_BITS 17           // n < 131072
#define S2CAP 12288           // sort2 LDS pair-stage capacity (48KB)

typedef unsigned int u32;
typedef unsigned short u16;
typedef __attribute__((ext_vector_type(8))) short short8v;   // 8 bf16 (4 VGPR)
typedef __attribute__((ext_vector_type(4))) float float4v;   // MFMA acc

__device__ __forceinline__ u16 f2bf(float f) {      // RNE fp32 -> bf16
    u32 u = __float_as_uint(f);
    u = (u + 0x7fffu + ((u >> 16) & 1u)) >> 16;
    return (u16)u;
}
__device__ __forceinline__ float bf_lo(u32 u) { return __uint_as_float(u << 16); }
__device__ __forceinline__ float bf_hi(u32 u) { return __uint_as_float(u & 0xffff0000u); }

// ---------------- phase 1: per-block bucket histogram -> hmat[blk][bucket] ----

__global__ __launch_bounds__(S1THREADS) void hist_kernel(
    const int* __restrict__ dst, int* __restrict__ hmat, int e, int nbuck, int valn)
{
    __shared__ int hist[BSIZE];
    const int tid = threadIdx.x;
    const int c0  = blockIdx.x * PASS1_CHUNK;
    for (int i = tid; i < nbuck; i += S1THREADS) hist[i] = 0;
    __syncthreads();
    if (valn) {   // 16B-aligned dst, 4 edges per iter
        for (int i = tid * 4; i < PASS1_CHUNK; i += S1THREADS * 4) {
            int idx = c0 + i;
            if (idx + 3 < e) {
                int4 dv = *(const int4*)(dst + idx);
                atomicAdd(&hist[dv.x >> BSHIFT], 1);
                atomicAdd(&hist[dv.y >> BSHIFT], 1);
                atomicAdd(&hist[dv.z >> BSHIFT], 1);
                atomicAdd(&hist[dv.w >> BSHIFT], 1);
            } else {
                for (int k = 0; k < 4; ++k)
                    if (idx + k < e) atomicAdd(&hist[dst[idx + k] >> BSHIFT], 1);
            }
        }
    } else {
        for (int i = tid; i < PASS1_CHUNK; i += S1THREADS) {
            int idx = c0 + i;
            if (idx < e) atomicAdd(&hist[dst[idx] >> BSHIFT], 1);
        }
    }
    __syncthreads();
    for (int b = tid; b < nbuck; b += S1THREADS)
        hmat[blockIdx.x * nbuck + b] = hist[b];
}

// ---------------- phase 2: column scan of hmat -> bmat (relative), bcnt -------

__global__ __launch_bounds__(THREADS) void colscan_kernel(
    const int* __restrict__ hmat, int* __restrict__ bmat,
    int* __restrict__ bcnt, int nblk, int nbuck)
{
    __shared__ int s[THREADS];
    const int b = blockIdx.x, tid = threadIdx.x;
    int run = 0;
    for (int t0 = 0; t0 < nblk; t0 += THREADS) {
        int idx = t0 + tid;
        int v = (idx < nblk) ? hmat[idx * nbuck + b] : 0;
        s[tid] = v;
        __syncthreads();
        for (int off = 1; off < THREADS; off <<= 1) {
            int t = (tid >= off) ? s[tid - off] : 0;
            __syncthreads();
            s[tid] += t;
            __syncthreads();
        }
        if (idx < nblk) bmat[idx * nbuck + b] = run + s[tid] - v;
        run += s[THREADS - 1];
        __syncthreads();
    }
    if (tid == 0) bcnt[b] = run;
}

// ---------------- phase 3: scatter packed (ld<<17|src) into bucket regions ----
// bbase derived locally from bcnt (scan of <=512 values); no global atomics.

__global__ __launch_bounds__(S1THREADS) void scatter_kernel(
    const int* __restrict__ src, const int* __restrict__ dst,
    const int* __restrict__ bmat, const int* __restrict__ bcnt,
    u32* __restrict__ pairs, int e, int nbuck, int valn)
{
    __shared__ int base_s[BSIZE], cur[BSIZE], s2[S1THREADS];
    const int tid = threadIdx.x;
    const int c0  = blockIdx.x * PASS1_CHUNK;

    // local exclusive scan of bcnt -> bbase
    int v = (tid < nbuck) ? bcnt[tid] : 0;
    s2[tid] = v;
    __syncthreads();
    for (int off = 1; off < S1THREADS; off <<= 1) {
        int t = (tid >= off) ? s2[tid - off] : 0;
        __syncthreads();
        s2[tid] += t;
        __syncthreads();
    }
    if (tid < nbuck) {
        base_s[tid] = (s2[tid] - v) + bmat[blockIdx.x * nbuck + tid];
        cur[tid] = 0;
    }
    __syncthreads();

    if (valn) {
        for (int i = tid * 4; i < PASS1_CHUNK; i += S1THREADS * 4) {
            int idx = c0 + i;
            if (idx + 3 < e) {
                int4 dv = *(const int4*)(dst + idx);
                int4 sv = *(const int4*)(src + idx);
                int dd[4] = {dv.x, dv.y, dv.z, dv.w};
                int ss[4] = {sv.x, sv.y, sv.z, sv.w};
#pragma unroll
                for (int k = 0; k < 4; ++k) {
                    int b = dd[k] >> BSHIFT;
                    int off = atomicAdd(&cur[b], 1);
                    pairs[base_s[b] + off] =
                        ((u32)(dd[k] & (BSIZE - 1)) << SRC_BITS) | (u32)ss[k];
                }
            } else {
                for (int k = 0; k < 4; ++k) {
                    if (idx + k < e) {
                        int d = dst[idx + k];
                        int b = d >> BSHIFT;
                        int off = atomicAdd(&cur[b], 1);
                        pairs[base_s[b] + off] =
                            ((u32)(d & (BSIZE - 1)) << SRC_BITS) | (u32)src[idx + k];
                    }
                }
            }
        }
    } else {
        for (int i = tid; i < PASS1_CHUNK; i += S1THREADS) {
            int idx = c0 + i;
            if (idx < e) {
                int d = dst[idx];
                int b = d >> BSHIFT;
                int off = atomicAdd(&cur[b], 1);
                pairs[base_s[b] + off] = ((u32)(d & (BSIZE - 1)) << SRC_BITS) | (u32)src[idx];
            }
        }
    }
}

// ---------------- sort pass 2: degree count + rowptr + dis + csr scatter ------
// bbase derived locally from bcnt; one block per bucket; pairs staged in LDS.

__global__ __launch_bounds__(S1THREADS) void sort2_kernel(
    const int* __restrict__ bcnt, const u32* __restrict__ pairs,
    int* __restrict__ rowptr, float* __restrict__ dis,
    int* __restrict__ csr, int n, int e, int nbuck)
{
    __shared__ int cnt[BSIZE];
    __shared__ int cur[BSIZE];
    __shared__ int s2[S1THREADS];
    __shared__ u32 pst[S2CAP];
    __shared__ int p0s, p1s;

    const int b  = blockIdx.x;
    const int d0 = b << BSHIFT;
    const int nd = min(BSIZE, n - d0);
    const int tid = threadIdx.x;

    // local scan of bcnt: p0 = exclusive[b], p1 = inclusive[b]
    int v = (tid < nbuck) ? bcnt[tid] : 0;
    s2[tid] = v;
    __syncthreads();
    for (int off = 1; off < S1THREADS; off <<= 1) {
        int t = (tid >= off) ? s2[tid - off] : 0;
        __syncthreads();
        s2[tid] += t;
        __syncthreads();
    }
    if (tid == b) { p0s = s2[tid] - v; p1s = s2[tid]; }
    __syncthreads();
    const int p0 = p0s, p1 = p1s;
    const int sz = p1 - p0;

    for (int i = tid; i < BSIZE; i += S1THREADS) cnt[i] = 0;
    __syncthreads();

    for (int j = tid; j < sz; j += S1THREADS) {
        u32 pr = pairs[p0 + j];
        if (j < S2CAP) pst[j] = pr;
        atomicAdd(&cnt[pr >> SRC_BITS], 1);
    }
    __syncthreads();

    int cv = cnt[tid];
    s2[tid] = cv;
    __syncthreads();
    for (int off = 1; off < S1THREADS; off <<= 1) {
        int t = (tid >= off) ? s2[tid - off] : 0;
        __syncthreads();
        s2[tid] += t;
        __syncthreads();
    }
    cur[tid] = p0 + s2[tid] - cv;
    __syncthreads();

    for (int i = tid; i < nd; i += S1THREADS) {
        rowptr[d0 + i] = cur[i];
        dis[d0 + i] = rsqrtf((float)(cnt[i] + 1));   // +1 self-loop
    }
    if (b == nbuck - 1 && tid == 0) rowptr[n] = e;
    __syncthreads();

    for (int j = tid; j < sz; j += S1THREADS) {
        u32 pr = (j < S2CAP) ? pst[j] : pairs[p0 + j];
        int pos = atomicAdd(&cur[pr >> SRC_BITS], 1);
        csr[pos] = (int)(pr & ((1u << SRC_BITS) - 1));
    }
}

// ---------------- MFMA GEMM (layer 1: fp32 input, no pre-activation) ----------
// hs[r] = bf16( (bf16(Xf[r]) @ W) * dis[r] )
template <int KTOT, int OUT, int SOUT>
__global__ __launch_bounds__(THREADS) void mfma_gemm_kernel(
    const float* __restrict__ Xf, const float* __restrict__ W,
    const float* __restrict__ dis, u16* __restrict__ hs, int n)
{
    constexpr int NCG = (OUT + 15) / 16;
    constexpr int CC  = NCG * 16;
    constexpr int NKK = KTOT / 32;
    constexpr int WS  = KTOT + 8;

    __shared__ u16 WT[CC][WS];                // B^T bf16

    const int tid = threadIdx.x;
    for (int idx = tid; idx < KTOT * CC; idx += THREADS) {
        int k = idx / CC;
        int c = idx - k * CC;
        float v = (c < OUT) ? W[k * OUT + c] : 0.f;
        WT[c][k] = f2bf(v);
    }
    __syncthreads();

    const int lane  = tid & 63;
    const int rlane = lane & 15;
    const int kgrp  = lane >> 4;
    const int rbase = blockIdx.x * 64 + (tid >> 6) * 16;
    const int arow = min(rbase + rlane, n - 1);

    float4v acc[NCG];
#pragma unroll
    for (int g = 0; g < NCG; ++g) acc[g] = (float4v)(0.f);

#pragma unroll
    for (int kk = 0; kk < NKK; ++kk) {
        const int kb = kk * 32 + kgrp * 8;
        short8v a;
        float4 f0 = *(const float4*)(Xf + (size_t)arow * KTOT + kb);
        float4 f1 = *(const float4*)(Xf + (size_t)arow * KTOT + kb + 4);
        a[0] = (short)f2bf(f0.x); a[1] = (short)f2bf(f0.y);
        a[2] = (short)f2bf(f0.z); a[3] = (short)f2bf(f0.w);
        a[4] = (short)f2bf(f1.x); a[5] = (short)f2bf(f1.y);
        a[6] = (short)f2bf(f1.z); a[7] = (short)f2bf(f1.w);
#pragma unroll
        for (int g = 0; g < NCG; ++g) {
            short8v b = *(const short8v*)&WT[g * 16 + rlane][kb];
            acc[g] = __builtin_amdgcn_mfma_f32_16x16x32_bf16(a, b, acc[g], 0, 0, 0);
        }
    }

#pragma unroll
    for (int j = 0; j < 4; ++j) {
        int row = rbase + kgrp * 4 + j;
        if (row < n) {
            float dd = dis[row];
#pragma unroll
            for (int g = 0; g < NCG; ++g) {
                int col = g * 16 + rlane;
                if (OUT == CC || col < OUT)
                    hs[(size_t)row * SOUT + col] = f2bf(acc[g][j] * dd);
            }
        }
    }
}

// ---------------- fused gather-aggregate + swish + MFMA GEMM ------------------
template <int OUT, int SOUT>
__global__ __launch_bounds__(THREADS) void fused_agg_gemm_kernel(
    const int* __restrict__ rowptr, const int* __restrict__ csr,
    const u16* __restrict__ hs, const float* __restrict__ W,
    const float* __restrict__ bin, const float* __restrict__ dis,
    u16* __restrict__ hsout, int n)
{
    constexpr int KTOT = 64;
    constexpr int NCG = (OUT + 15) / 16;
    constexpr int CC  = NCG * 16;
    constexpr int WS  = KTOT + 8;

    __shared__ u16 WT[CC][WS];                // B^T bf16
    __shared__ u16 As[64][WS];                // aggregated+activated A tile

    const int tid = threadIdx.x;
    for (int idx = tid; idx < KTOT * CC; idx += THREADS) {
        int k = idx / CC;
        int c = idx - k * CC;
        float v = (c < OUT) ? W[k * OUT + c] : 0.f;
        WT[c][k] = f2bf(v);
    }

    const int lane = tid & 63;
    const int wid  = tid >> 6;
    const int sub  = lane >> 3;               // subgroup 0..7 (one row each)
    const int gl   = lane & 7;
    const int c8   = gl * 8;
    const int row0 = blockIdx.x * 64;

    // ---- phase 1: gather-aggregate 64 rows (2 halves x 32 rows) ----
#pragma unroll
    for (int half = 0; half < 2; ++half) {
        const int lr = half * 32 + wid * 8 + sub;   // local row 0..63
        const int d  = row0 + lr;
        if (d < n) {
            const int beg = rowptr[d], end = rowptr[d + 1];
            float acc[8];
            {
                uint4 u = *(const uint4*)(hs + (size_t)d * 64 + c8);  // self-loop
                acc[0] = bf_lo(u.x); acc[1] = bf_hi(u.x);
                acc[2] = bf_lo(u.y); acc[3] = bf_hi(u.y);
                acc[4] = bf_lo(u.z); acc[5] = bf_hi(u.z);
                acc[6] = bf_lo(u.w); acc[7] = bf_hi(u.w);
            }
            int eidx = (beg + gl < end) ? csr[beg + gl] : 0;
            for (int t = beg; t < end; t += 8) {
                const int m = end - t;
                uint4 ub[8];
#pragma unroll
                for (int q = 0; q < 8; ++q) {
                    int s = __shfl(eidx, (sub << 3) + q);
                    if (q < m) ub[q] = *(const uint4*)(hs + (size_t)s * 64 + c8);
                }
                int eidx_n = (t + 8 + gl < end) ? csr[t + 8 + gl] : 0;
#pragma unroll
                for (int q = 0; q < 8; ++q) {
                    if (q < m) {
                        acc[0] += bf_lo(ub[q].x); acc[1] += bf_hi(ub[q].x);
                        acc[2] += bf_lo(ub[q].y); acc[3] += bf_hi(ub[q].y);
                        acc[4] += bf_lo(ub[q].z); acc[5] += bf_hi(ub[q].z);
                        acc[6] += bf_lo(ub[q].w); acc[7] += bf_hi(ub[q].w);
                    }
                }
                eidx = eidx_n;
            }
            // swish(agg*dis + b) -> bf16 A row
            float dd = dis[d];
            u16 o[8];
#pragma unroll
            for (int q = 0; q < 8; ++q) {
                float h = acc[q] * dd + bin[c8 + q];
                o[q] = f2bf(h / (1.f + __expf(-h)));
            }
            ushort4 o0 = {o[0], o[1], o[2], o[3]};
            ushort4 o1 = {o[4], o[5], o[6], o[7]};
            *(ushort4*)&As[lr][c8]     = o0;
            *(ushort4*)&As[lr][c8 + 4] = o1;
        }
    }
    __syncthreads();

    // ---- phase 2: MFMA from LDS ----
    const int rlane = lane & 15;
    const int kgrp  = lane >> 4;
    const int rbase = row0 + wid * 16;

    float4v acc[NCG];
#pragma unroll
    for (int g = 0; g < NCG; ++g) acc[g] = (float4v)(0.f);

#pragma unroll
    for (int kk = 0; kk < 2; ++kk) {
        const int kb = kk * 32 + kgrp * 8;
        short8v a = *(const short8v*)&As[wid * 16 + rlane][kb];
#pragma unroll
        for (int g = 0; g < NCG; ++g) {
            short8v b = *(const short8v*)&WT[g * 16 + rlane][kb];
            acc[g] = __builtin_amdgcn_mfma_f32_16x16x32_bf16(a, b, acc[g], 0, 0, 0);
        }
    }

#pragma unroll
    for (int j = 0; j < 4; ++j) {
        int row = rbase + kgrp * 4 + j;
        if (row < n) {
            float dd = dis[row];
#pragma unroll
            for (int g = 0; g < NCG; ++g) {
                int col = g * 16 + rlane;
                if (OUT == CC || col < OUT)
                    hsout[(size_t)row * SOUT + col] = f2bf(acc[g][j] * dd);
            }
        }
    }
}

// ---------------- layer-3 aggregate + bias + log_softmax ----------------------
// hs3 rows: 40 bf16 at stride 40 (80B, 16B-aligned). One 8-lane subgroup per
// row; lanes gl<5 carry features.
__global__ __launch_bounds__(THREADS) void agg40_lsm_kernel(
    const int* __restrict__ rowptr, const int* __restrict__ csr,
    const u16* __restrict__ hs, const float* __restrict__ dis,
    const float* __restrict__ b3, float* __restrict__ out, int n)
{
    constexpr int S = 40;
    const int lane = threadIdx.x & 63;
    const int sub  = lane >> 3;
    const int gl   = lane & 7;
    const int d = (blockIdx.x * 4 + (threadIdx.x >> 6)) * 8 + sub;
    if (d >= n) return;
    const bool act = (gl < 5);
    const int c8 = gl * 8;

    const int beg = rowptr[d], end = rowptr[d + 1];
    float acc[8] = {0.f,0.f,0.f,0.f,0.f,0.f,0.f,0.f};
    if (act) {
        uint4 u = *(const uint4*)(hs + (size_t)d * S + c8);
        acc[0] = bf_lo(u.x); acc[1] = bf_hi(u.x);
        acc[2] = bf_lo(u.y); acc[3] = bf_hi(u.y);
        acc[4] = bf_lo(u.z); acc[5] = bf_hi(u.z);
        acc[6] = bf_lo(u.w); acc[7] = bf_hi(u.w);
    }

    int eidx = (beg + gl < end) ? csr[beg + gl] : 0;
    for (int t = beg; t < end; t += 8) {
        const int m = end - t;
        uint4 ub[8];
#pragma unroll
        for (int q = 0; q < 8; ++q) {
            int s = __shfl(eidx, (sub << 3) + q);
            if (q < m && act) ub[q] = *(const uint4*)(hs + (size_t)s * S + c8);
        }
        int eidx_n = (t + 8 + gl < end) ? csr[t + 8 + gl] : 0;
#pragma unroll
        for (int q = 0; q < 8; ++q) {
            if (q < m && act) {
                acc[0] += bf_lo(ub[q].x); acc[1] += bf_hi(ub[q].x);
                acc[2] += bf_lo(ub[q].y); acc[3] += bf_hi(ub[q].y);
                acc[4] += bf_lo(ub[q].z); acc[5] += bf_hi(ub[q].z);
                acc[6] += bf_lo(ub[q].w); acc[7] += bf_hi(ub[q].w);
            }
        }
        eidx = eidx_n;
    }

    float val[8];
    float mx = -1e30f;
    if (act) {
        float dd = dis[d];
#pragma unroll
        for (int q = 0; q < 8; ++q) {
            val[q] = acc[q] * dd + b3[c8 + q];
            mx = fmaxf(mx, val[q]);
        }
    }
#pragma unroll
    for (int off = 4; off > 0; off >>= 1) mx = fmaxf(mx, __shfl_xor(mx, off));
    float es = 0.f;
    if (act) {
#pragma unroll
        for (int q = 0; q < 8; ++q) es += __expf(val[q] - mx);
    }
#pragma unroll
    for (int off = 4; off > 0; off >>= 1) es += __shfl_xor(es, off);
    float lse = mx + __logf(es);
    if (act) {
        float4 o0 = make_float4(val[0]-lse, val[1]-lse, val[2]-lse, val[3]-lse);
        float4 o1 = make_float4(val[4]-lse, val[5]-lse, val[6]-lse, val[7]-lse);
        *(float4*)(out + (size_t)d * 40 + c8)     = o0;
        *(float4*)(out + (size_t)d * 40 + c8 + 4) = o1;
    }
}

// ---------------- launch ----------------
static inline size_t align_up(size_t v, size_t a) { return (v + a - 1) & ~(a - 1); }

extern "C" void kernel_launch(void* const* d_in, const int* in_sizes, int n_in,
                              void* d_out, int out_size, void* d_ws, size_t ws_size,
                              hipStream_t stream) {
    const float* x  = (const float*)d_in[0];
    const int*   ei = (const int*)d_in[1];
    const float* W1 = (const float*)d_in[2];
    const float* b1 = (const float*)d_in[3];
    const float* W2 = (const float*)d_in[4];
    const float* b2 = (const float*)d_in[5];
    const float* W3 = (const float*)d_in[6];
    const float* b3 = (const float*)d_in[7];
    float* out = (float*)d_out;

    const int n = in_sizes[0] / 128;
    const int e = in_sizes[1] / 2;
    const int* src = ei;
    const int* dst = ei + e;
    const int valn = (((uintptr_t)src & 15) == 0 && ((uintptr_t)dst & 15) == 0) ? 1 : 0;

    const int nbuck = (n + BSIZE - 1) >> BSHIFT;            // 196 for n=100k
    const int nblk  = (e + PASS1_CHUNK - 1) / PASS1_CHUNK;  // 391

    // workspace: dis[n] | rowptr[n+1] | bcnt[1k] |
    //            hmat[nblk*nbuck] | bmat[nblk*nbuck] | csr[e] |
    //            hsb (n*64 u16) | hs2b (n*64 u16)
    // pairs u32[e] aliases hsb (consumed in sort2 before gemm1 writes hsb).
    char* base = (char*)d_ws;
    size_t off = 0;
    float* dis = (float*)(base + off);    off = align_up(off + (size_t)n * 4, 256);
    int* rowptr = (int*)(base + off);     off = align_up(off + (size_t)(n + 1) * 4, 256);
    int* bcnt = (int*)(base + off);       off = align_up(off + 1024 * 4, 256);
    int* hmat = (int*)(base + off);       off = align_up(off + (size_t)nblk * nbuck * 4, 256);
    int* bmat = (int*)(base + off);       off = align_up(off + (size_t)nblk * nbuck * 4, 256);
    int* csr = (int*)(base + off);        off = align_up(off + (size_t)e * 4, 256);
    u16* hsb = (u16*)(base + off);        off = align_up(off + (size_t)n * 64 * 2, 256);
    u16* hs2b = (u16*)(base + off);       off = align_up(off + (size_t)n * 64 * 2, 256);
    u32* pairs = (u32*)hsb;

    const int gb_rows = (n + 63) / 64;
    const int gb_agg  = (n + 31) / 32;

    // CSR build (deterministic, no global atomics; 4 kernels)
    hist_kernel<<<nblk, S1THREADS, 0, stream>>>(dst, hmat, e, nbuck, valn);
    colscan_kernel<<<nbuck, THREADS, 0, stream>>>(hmat, bmat, bcnt, nblk, nbuck);
    scatter_kernel<<<nblk, S1THREADS, 0, stream>>>(src, dst, bmat, bcnt, pairs, e, nbuck, valn);
    sort2_kernel<<<nbuck, S1THREADS, 0, stream>>>(bcnt, pairs, rowptr, dis, csr, n, e, nbuck);

    // layer 1: x @ W1 -> hsb (hs1, bf16)
    mfma_gemm_kernel<128, 64, 64><<<gb_rows, THREADS, 0, stream>>>(x, W1, dis, hsb, n);

    // layer 2 fused: gather-agg(hs1) + swish(+b1) + @W2 -> hs2b (hs2)
    fused_agg_gemm_kernel<64, 64><<<gb_rows, THREADS, 0, stream>>>(
        rowptr, csr, hsb, W2, b1, dis, hs2b, n);

    // layer 3 fused: gather-agg(hs2) + swish(+b2) + @W3 -> hsb (hs3, stride 40)
    fused_agg_gemm_kernel<40, 40><<<gb_rows, THREADS, 0, stream>>>(
        rowptr, csr, hs2b, W3, b2, dis, hsb, n);

    // final: gather-agg(hs3) + bias + log_softmax -> out
    agg40_lsm_kernel<<<gb_agg, THREADS, 0, stream>>>(rowptr, csr, hsb, dis, b3, out, n);
}